// Round 2
// baseline (743.184 us; speedup 1.0000x reference)
//
#include <hip/hip_runtime.h>
#include <math.h>

static constexpr int Bz = 8;
static constexpr int Lz = 2048;
static constexpr int Cz = 512;
static constexpr int CRz = 128;
static constexpr int DHz = 256;
static constexpr int MT = Bz * Lz;           // 16384 rows
static constexpr float EPSz = 1e-5f;

// ---------------------------------------------------------------------------
// P: fold BN params (alpha/beta) for pw + dw branches; compute Q const vector
// ---------------------------------------------------------------------------
__global__ __launch_bounds__(256) void prep_kernel(
    const float* __restrict__ pw_b, const float* __restrict__ pw_g,
    const float* __restrict__ pw_bb, const float* __restrict__ pw_m,
    const float* __restrict__ pw_v,
    const float* __restrict__ dw_b, const float* __restrict__ dw_g,
    const float* __restrict__ dw_bb, const float* __restrict__ dw_m,
    const float* __restrict__ dw_v,
    const float* __restrict__ df_ln_b, const float* __restrict__ wq,
    const float* __restrict__ bq,
    float* __restrict__ pwA, float* __restrict__ pwB,
    float* __restrict__ dwA, float* __restrict__ dwB,
    float* __restrict__ qc) {
  const int blk = blockIdx.x;
  const int t = threadIdx.x;
  if (blk == 0) {
    for (int c = t; c < Cz; c += 256) {
      float inv = rsqrtf(pw_v[c] + EPSz);
      float a = pw_g[c] * inv;
      float bb = pw_bb[c] - pw_m[c] * a;
      pwA[c] = a;
      pwB[c] = pw_b[c] * a + bb;
    }
  } else if (blk <= 4) {
    const int i = blk - 1;
    for (int c = t; c < Cz; c += 256) {
      int idx = i * Cz + c;
      float inv = rsqrtf(dw_v[idx] + EPSz);
      float a = dw_g[idx] * inv;
      float bb = dw_bb[idx] - dw_m[idx] * a;
      dwA[idx] = a;
      dwB[idx] = dw_b[idx] * a + bb;
    }
  } else {
    // Q = df_ln_b @ wq.T + bq  (D == df_ln_b analytically: diff_feat is
    // channel-constant so its LayerNorm collapses to the bias)
    if (t < DHz) {
      float s = bq[t];
      const float* w = wq + (size_t)t * Cz;
      for (int c = 0; c < Cz; c++) s += df_ln_b[c] * w[c];
      qc[t] = s;
    }
  }
}

// ---------------------------------------------------------------------------
// A: pointwise conv GEMM  xpw[b,o,l] = relu(alpha[o]*sum_c W[o,c]x[b,l,c]+beta[o])
// grid (L/64, C/64, B), 256 thr, 64x64 tile, 4x4 per thread
// ---------------------------------------------------------------------------
__global__ __launch_bounds__(256) void pw_gemm_kernel(
    const float* __restrict__ x, const float* __restrict__ W,
    const float* __restrict__ alpha, const float* __restrict__ beta,
    float* __restrict__ xpw) {
  __shared__ float sW[16][68];
  __shared__ float sX[16][68];
  const int l0 = blockIdx.x * 64;
  const int o0 = blockIdx.y * 64;
  const int b = blockIdx.z;
  const int t = threadIdx.x;
  const int tn = t & 15, tm = t >> 4;
  const int lrow = t >> 2, lk = (t & 3) * 4;
  float acc[4][4] = {};
  const float* wp = W + (size_t)(o0 + lrow) * Cz + lk;
  const float* xp = x + ((size_t)b * Lz + l0 + lrow) * Cz + lk;
  for (int k0 = 0; k0 < Cz; k0 += 16) {
    float4 w4 = *(const float4*)(wp + k0);
    float4 x4 = *(const float4*)(xp + k0);
    __syncthreads();
    sW[lk + 0][lrow] = w4.x; sW[lk + 1][lrow] = w4.y;
    sW[lk + 2][lrow] = w4.z; sW[lk + 3][lrow] = w4.w;
    sX[lk + 0][lrow] = x4.x; sX[lk + 1][lrow] = x4.y;
    sX[lk + 2][lrow] = x4.z; sX[lk + 3][lrow] = x4.w;
    __syncthreads();
#pragma unroll
    for (int k = 0; k < 16; k++) {
      float a[4], bb[4];
      *(float4*)a = *(const float4*)&sW[k][tm * 4];
      *(float4*)bb = *(const float4*)&sX[k][tn * 4];
#pragma unroll
      for (int m = 0; m < 4; m++)
#pragma unroll
        for (int n = 0; n < 4; n++) acc[m][n] += a[m] * bb[n];
    }
  }
#pragma unroll
  for (int m = 0; m < 4; m++) {
    const int o = o0 + tm * 4 + m;
    const float av = alpha[o], bt = beta[o];
    float4 r;
    r.x = fmaxf(acc[m][0] * av + bt, 0.f);
    r.y = fmaxf(acc[m][1] * av + bt, 0.f);
    r.z = fmaxf(acc[m][2] * av + bt, 0.f);
    r.w = fmaxf(acc[m][3] * av + bt, 0.f);
    *(float4*)(xpw + ((size_t)(b * Cz + o)) * Lz + l0 + tn * 4) = r;
  }
}

// ---------------------------------------------------------------------------
// B: depthwise conv (4 branches) + bias/BN/ReLU folded + per-row sum
// grid 4*B*C blocks, 256 thr; block = one (branch,b,c) row of length L
// ---------------------------------------------------------------------------
__global__ __launch_bounds__(256) void dw_conv_kernel(
    const float* __restrict__ xpw,
    const float* __restrict__ w0, const float* __restrict__ w1,
    const float* __restrict__ w2, const float* __restrict__ w3,
    const float* __restrict__ dwA, const float* __restrict__ dwB,
    float* __restrict__ y, float* __restrict__ ysum) {
  __shared__ float row[Lz];
  __shared__ float wts[20];
  __shared__ float wsum[4];
  const int bx = blockIdx.x;
  const int i = bx >> 12;            // /(B*C)=4096
  const int rem = bx & 4095;
  const int b = rem >> 9;
  const int c = rem & 511;
  const int ks[4] = {3, 7, 15, 20};
  const int k = ks[i];
  const int p = (k - 1) >> 1;
  const int valid = (i == 3) ? (Lz - 1) : Lz;
  const float* w = (i == 0 ? w0 : i == 1 ? w1 : i == 2 ? w2 : w3) + c * k;
  const int t = threadIdx.x;
  const float* src = xpw + ((size_t)(b * Cz + c)) * Lz;
  for (int idx = t; idx < Lz / 4; idx += 256)
    ((float4*)row)[idx] = ((const float4*)src)[idx];
  if (t < k) wts[t] = w[t];
  __syncthreads();
  const float a = dwA[i * Cz + c], bb = dwB[i * Cz + c];
  float* dst = y + ((size_t)((i * Bz + b) * Cz + c)) * Lz;
  float psum = 0.f;
  for (int s = 0; s < 8; s++) {
    const int l = t + s * 256;
    float acc = 0.f;
    for (int j = 0; j < k; j++) {
      const int xi = l + j - p;
      if (xi >= 0 && xi < Lz) acc += wts[j] * row[xi];
    }
    float v = fmaxf(acc * a + bb, 0.f);
    if (l >= valid) v = 0.f;
    dst[l] = v;
    psum += v;
  }
  for (int off = 32; off > 0; off >>= 1) psum += __shfl_down(psum, off, 64);
  if ((t & 63) == 0) wsum[t >> 6] = psum;
  __syncthreads();
  if (t == 0) ysum[(i * Bz + b) * Cz + c] = wsum[0] + wsum[1] + wsum[2] + wsum[3];
}

// ---------------------------------------------------------------------------
// C: squeeze-excite; sc = 1 + sigmoid(relu(ym@w1.T+b1)@w2.T+b2)
// grid 32 = (i,b), 128 thr
// ---------------------------------------------------------------------------
__global__ __launch_bounds__(128) void se_kernel(
    const float* __restrict__ ysum,
    const float* __restrict__ se_w1, const float* __restrict__ se_b1,
    const float* __restrict__ se_w2, const float* __restrict__ se_b2,
    float* __restrict__ sc) {
  const int i = blockIdx.x >> 3;
  const int b = blockIdx.x & 7;
  __shared__ float ym[Cz];
  __shared__ float h[CRz];
  const int t = threadIdx.x;
  const float* ys = ysum + (i * Bz + b) * Cz;
  for (int cc = t; cc < Cz; cc += 128) ym[cc] = ys[cc] * (1.f / Lz);
  __syncthreads();
  {
    const float* w1 = se_w1 + (size_t)i * CRz * Cz + (size_t)t * Cz;
    float s = se_b1[i * CRz + t];
    for (int cc = 0; cc < Cz; cc++) s += ym[cc] * w1[cc];
    h[t] = fmaxf(s, 0.f);
  }
  __syncthreads();
  for (int cc = t; cc < Cz; cc += 128) {
    const float* w2 = se_w2 + ((size_t)i * Cz + cc) * CRz;
    float s = se_b2[i * Cz + cc];
    for (int r = 0; r < CRz; r++) s += h[r] * w2[r];
    float wt = 1.f / (1.f + expf(-s));
    sc[(i * Bz + b) * Cz + cc] = 1.f + wt;
  }
}

// ---------------------------------------------------------------------------
// D: enhanced = LN_c( y[b,c,l]*sc[b,c] ), transposing (B,C,L)->(B,L,C)
// grid (L/16, B) per branch, 256 thr
// ---------------------------------------------------------------------------
__global__ __launch_bounds__(256) void ln_transpose_kernel(
    const float* __restrict__ ysrc, const float* __restrict__ sc,
    const float* __restrict__ g, const float* __restrict__ bb,
    float* __restrict__ edst) {
  __shared__ float tile[16][Cz + 1];
  const int l0 = blockIdx.x * 16;
  const int b = blockIdx.y;
  const int t = threadIdx.x;
  const float* yb = ysrc + (size_t)b * Cz * Lz;
  const float* scb = sc + b * Cz;
  for (int s = 0; s < 8; s++) {
    const int idx = s * 256 + t;
    const int c = idx >> 2;
    const int l4 = (idx & 3) * 4;
    float4 v = *(const float4*)(yb + (size_t)c * Lz + l0 + l4);
    const float scale = scb[c];
    tile[l4 + 0][c] = v.x * scale;
    tile[l4 + 1][c] = v.y * scale;
    tile[l4 + 2][c] = v.z * scale;
    tile[l4 + 3][c] = v.w * scale;
  }
  __syncthreads();
  const int wave = t >> 6, lane = t & 63;
  float* eb = edst + ((size_t)b * Lz + l0) * Cz;
  for (int r = wave; r < 16; r += 4) {
    float vals[8];
    float s1 = 0.f, s2 = 0.f;
#pragma unroll
    for (int j = 0; j < 8; j++) {
      float v = tile[r][lane + j * 64];
      vals[j] = v; s1 += v; s2 += v * v;
    }
    for (int off = 32; off > 0; off >>= 1) {
      s1 += __shfl_xor(s1, off, 64);
      s2 += __shfl_xor(s2, off, 64);
    }
    const float m = s1 * (1.f / Cz);
    const float var = s2 * (1.f / Cz) - m * m;
    const float inv = rsqrtf(var + EPSz);
#pragma unroll
    for (int j = 0; j < 8; j++) {
      const int cc = lane + j * 64;
      eb[(size_t)r * Cz + cc] = (vals[j] - m) * inv * g[cc] + bb[cc];
    }
  }
}

// ---------------------------------------------------------------------------
// E: score GEMM: Vi = e_i @ wv.T + bv; score_i = sum_d tanh(qc*Vi)*wg + bg
// grid (MT/64, 4), 256 thr; 64 rows x full DH=256
// ---------------------------------------------------------------------------
__global__ __launch_bounds__(256) void score_gemm_kernel(
    const float* __restrict__ e0, const float* __restrict__ e1,
    const float* __restrict__ e2, const float* __restrict__ e3,
    const float* __restrict__ wv, const float* __restrict__ bv,
    const float* __restrict__ qc, const float* __restrict__ wg,
    const float* __restrict__ bg, float* __restrict__ scores) {
  __shared__ float sA[16][68];
  __shared__ float sW[16][260];
  const int i = blockIdx.y;
  const float* E = (i == 0) ? e0 : (i == 1) ? e1 : (i == 2) ? e2 : e3;
  const int r0 = blockIdx.x * 64;
  const int t = threadIdx.x;
  const int tn = t & 15, tm = t >> 4;
  const int lrow = t >> 2, lk = (t & 3) * 4;
  float acc[4][16] = {};
  const float* ep = E + (size_t)(r0 + lrow) * Cz + lk;
  const float* wp = wv + (size_t)lrow * Cz + lk;
  for (int k0 = 0; k0 < Cz; k0 += 16) {
    float4 a4 = *(const float4*)(ep + k0);
    float4 q0 = *(const float4*)(wp + k0);
    float4 q1 = *(const float4*)(wp + (size_t)64 * Cz + k0);
    float4 q2 = *(const float4*)(wp + (size_t)128 * Cz + k0);
    float4 q3 = *(const float4*)(wp + (size_t)192 * Cz + k0);
    __syncthreads();
    sA[lk + 0][lrow] = a4.x; sA[lk + 1][lrow] = a4.y;
    sA[lk + 2][lrow] = a4.z; sA[lk + 3][lrow] = a4.w;
    sW[lk + 0][lrow] = q0.x; sW[lk + 1][lrow] = q0.y;
    sW[lk + 2][lrow] = q0.z; sW[lk + 3][lrow] = q0.w;
    sW[lk + 0][lrow + 64] = q1.x; sW[lk + 1][lrow + 64] = q1.y;
    sW[lk + 2][lrow + 64] = q1.z; sW[lk + 3][lrow + 64] = q1.w;
    sW[lk + 0][lrow + 128] = q2.x; sW[lk + 1][lrow + 128] = q2.y;
    sW[lk + 2][lrow + 128] = q2.z; sW[lk + 3][lrow + 128] = q2.w;
    sW[lk + 0][lrow + 192] = q3.x; sW[lk + 1][lrow + 192] = q3.y;
    sW[lk + 2][lrow + 192] = q3.z; sW[lk + 3][lrow + 192] = q3.w;
    __syncthreads();
#pragma unroll
    for (int k = 0; k < 16; k++) {
      float a[4];
      *(float4*)a = *(const float4*)&sA[k][tm * 4];
#pragma unroll
      for (int q = 0; q < 4; q++) {
        float w[4];
        *(float4*)w = *(const float4*)&sW[k][tn * 4 + q * 64];
#pragma unroll
        for (int m = 0; m < 4; m++)
#pragma unroll
          for (int r = 0; r < 4; r++) acc[m][q * 4 + r] += a[m] * w[r];
      }
    }
  }
  float part[4] = {0.f, 0.f, 0.f, 0.f};
#pragma unroll
  for (int q = 0; q < 4; q++) {
    const int n = tn * 4 + q * 64;
    float bv4[4], qc4[4], wg4[4];
    *(float4*)bv4 = *(const float4*)(bv + n);
    *(float4*)qc4 = *(const float4*)(qc + n);
    *(float4*)wg4 = *(const float4*)(wg + n);
#pragma unroll
    for (int r = 0; r < 4; r++)
#pragma unroll
      for (int m = 0; m < 4; m++)
        part[m] += tanhf(qc4[r] * (acc[m][q * 4 + r] + bv4[r])) * wg4[r];
  }
#pragma unroll
  for (int off = 1; off < 16; off <<= 1) {
#pragma unroll
    for (int m = 0; m < 4; m++) part[m] += __shfl_xor(part[m], off, 64);
  }
  if (tn == 0) {
    const float bgv = bg[0];
#pragma unroll
    for (int m = 0; m < 4; m++)
      scores[(size_t)i * MT + r0 + tm * 4 + m] = part[m] + bgv;
  }
}

// ---------------------------------------------------------------------------
// F: softmax over 4 branch scores + weighted combine of enhanced
// grid MT, 128 thr (4 floats each)
// ---------------------------------------------------------------------------
__global__ __launch_bounds__(128) void fuse_kernel(
    const float* __restrict__ e0, const float* __restrict__ e1,
    const float* __restrict__ e2, const float* __restrict__ e3,
    const float* __restrict__ scores, float* __restrict__ fused) {
  const int r = blockIdx.x;
  float s0 = scores[r], s1 = scores[MT + r], s2 = scores[2 * MT + r],
        s3 = scores[3 * MT + r];
  float mx = fmaxf(fmaxf(s0, s1), fmaxf(s2, s3));
  float x0 = expf(s0 - mx), x1 = expf(s1 - mx), x2 = expf(s2 - mx),
        x3 = expf(s3 - mx);
  float inv = 1.f / (x0 + x1 + x2 + x3);
  x0 *= inv; x1 *= inv; x2 *= inv; x3 *= inv;
  const int t = threadIdx.x;
  const size_t base = (size_t)r * Cz;
  float4 v0 = ((const float4*)(e0 + base))[t];
  float4 v1 = ((const float4*)(e1 + base))[t];
  float4 v2 = ((const float4*)(e2 + base))[t];
  float4 v3 = ((const float4*)(e3 + base))[t];
  float4 o;
  o.x = x0 * v0.x + x1 * v1.x + x2 * v2.x + x3 * v3.x;
  o.y = x0 * v0.y + x1 * v1.y + x2 * v2.y + x3 * v3.y;
  o.z = x0 * v0.z + x1 * v1.z + x2 * v2.z + x3 * v3.z;
  o.w = x0 * v0.w + x1 * v1.w + x2 * v2.w + x3 * v3.w;
  ((float4*)(fused + base))[t] = o;
}

// ---------------------------------------------------------------------------
// G: out = LN( LN(fused@op_w.T + op_b) + x )
// grid MT/32, 256 thr; block = 32 rows x full C=512
// ---------------------------------------------------------------------------
__global__ __launch_bounds__(256) void op_ln_kernel(
    const float* __restrict__ fusedp, const float* __restrict__ opw,
    const float* __restrict__ opb, const float* __restrict__ g1,
    const float* __restrict__ b1, const float* __restrict__ x,
    const float* __restrict__ g2, const float* __restrict__ b2,
    float* __restrict__ out) {
  __shared__ float sA[16][36];
  __shared__ float sW[16][516];
  const int r0 = blockIdx.x * 32;
  const int t = threadIdx.x;
  const int tn = t & 15, tm = t >> 4;
  const int lrow = t >> 2, lk = (t & 3) * 4;
  float acc[2][32] = {};
  const float* wp = opw + (size_t)lrow * Cz + lk;
  for (int k0 = 0; k0 < Cz; k0 += 16) {
    float4 a4 = make_float4(0.f, 0.f, 0.f, 0.f);
    if (t < 128)
      a4 = *(const float4*)(fusedp + (size_t)(r0 + (t >> 2)) * Cz + k0 +
                            (t & 3) * 4);
    float4 w4[8];
#pragma unroll
    for (int s = 0; s < 8; s++)
      w4[s] = *(const float4*)(wp + (size_t)s * 64 * Cz + k0);
    __syncthreads();
    if (t < 128) {
      sA[lk + 0][lrow] = a4.x; sA[lk + 1][lrow] = a4.y;
      sA[lk + 2][lrow] = a4.z; sA[lk + 3][lrow] = a4.w;
    }
#pragma unroll
    for (int s = 0; s < 8; s++) {
      sW[lk + 0][lrow + s * 64] = w4[s].x;
      sW[lk + 1][lrow + s * 64] = w4[s].y;
      sW[lk + 2][lrow + s * 64] = w4[s].z;
      sW[lk + 3][lrow + s * 64] = w4[s].w;
    }
    __syncthreads();
#pragma unroll
    for (int k = 0; k < 16; k++) {
      const float a0 = sA[k][tm * 2], a1 = sA[k][tm * 2 + 1];
#pragma unroll
      for (int q = 0; q < 8; q++) {
        float w[4];
        *(float4*)w = *(const float4*)&sW[k][tn * 4 + q * 64];
#pragma unroll
        for (int r = 0; r < 4; r++) {
          acc[0][q * 4 + r] += a0 * w[r];
          acc[1][q * 4 + r] += a1 * w[r];
        }
      }
    }
  }
#pragma unroll
  for (int j = 0; j < 2; j++) {
    const int row = r0 + tm * 2 + j;
    float s1 = 0.f, s2 = 0.f;
#pragma unroll
    for (int q = 0; q < 8; q++) {
      const int n = tn * 4 + q * 64;
      float ob[4];
      *(float4*)ob = *(const float4*)(opb + n);
#pragma unroll
      for (int r = 0; r < 4; r++) {
        float z = acc[j][q * 4 + r] + ob[r];
        acc[j][q * 4 + r] = z;
        s1 += z; s2 += z * z;
      }
    }
#pragma unroll
    for (int off = 1; off < 16; off <<= 1) {
      s1 += __shfl_xor(s1, off, 64);
      s2 += __shfl_xor(s2, off, 64);
    }
    const float m1 = s1 * (1.f / Cz);
    const float iv1 = rsqrtf(s2 * (1.f / Cz) - m1 * m1 + EPSz);
    s1 = 0.f; s2 = 0.f;
#pragma unroll
    for (int q = 0; q < 8; q++) {
      const int n = tn * 4 + q * 64;
      float gg[4], bb[4], xv[4];
      *(float4*)gg = *(const float4*)(g1 + n);
      *(float4*)bb = *(const float4*)(b1 + n);
      *(float4*)xv = *(const float4*)(x + (size_t)row * Cz + n);
#pragma unroll
      for (int r = 0; r < 4; r++) {
        float tt = (acc[j][q * 4 + r] - m1) * iv1 * gg[r] + bb[r] + xv[r];
        acc[j][q * 4 + r] = tt;
        s1 += tt; s2 += tt * tt;
      }
    }
#pragma unroll
    for (int off = 1; off < 16; off <<= 1) {
      s1 += __shfl_xor(s1, off, 64);
      s2 += __shfl_xor(s2, off, 64);
    }
    const float m2 = s1 * (1.f / Cz);
    const float iv2 = rsqrtf(s2 * (1.f / Cz) - m2 * m2 + EPSz);
#pragma unroll
    for (int q = 0; q < 8; q++) {
      const int n = tn * 4 + q * 64;
      float gg[4], bb[4];
      *(float4*)gg = *(const float4*)(g2 + n);
      *(float4*)bb = *(const float4*)(b2 + n);
      float4 o;
      o.x = (acc[j][q * 4 + 0] - m2) * iv2 * gg[0] + bb[0];
      o.y = (acc[j][q * 4 + 1] - m2) * iv2 * gg[1] + bb[1];
      o.z = (acc[j][q * 4 + 2] - m2) * iv2 * gg[2] + bb[2];
      o.w = (acc[j][q * 4 + 3] - m2) * iv2 * gg[3] + bb[3];
      *(float4*)(out + (size_t)row * Cz + n) = o;
    }
  }
}

// ---------------------------------------------------------------------------
extern "C" void kernel_launch(void* const* d_in, const int* in_sizes, int n_in,
                              void* d_out, int out_size, void* d_ws,
                              size_t ws_size, hipStream_t stream) {
  const float* x = (const float*)d_in[0];
  const float* pw_w = (const float*)d_in[1];
  const float* pw_b = (const float*)d_in[2];
  const float* pw_bn_g = (const float*)d_in[3];
  const float* pw_bn_b = (const float*)d_in[4];
  const float* pw_bn_m = (const float*)d_in[5];
  const float* pw_bn_v = (const float*)d_in[6];
  const float* dw_w0 = (const float*)d_in[7];
  const float* dw_w1 = (const float*)d_in[8];
  const float* dw_w2 = (const float*)d_in[9];
  const float* dw_w3 = (const float*)d_in[10];
  const float* dw_b = (const float*)d_in[11];
  const float* dw_bn_g = (const float*)d_in[12];
  const float* dw_bn_b = (const float*)d_in[13];
  const float* dw_bn_m = (const float*)d_in[14];
  const float* dw_bn_v = (const float*)d_in[15];
  const float* se_w1 = (const float*)d_in[16];
  const float* se_b1 = (const float*)d_in[17];
  const float* se_w2 = (const float*)d_in[18];
  const float* se_b2 = (const float*)d_in[19];
  const float* se_ln_g = (const float*)d_in[20];
  const float* se_ln_b = (const float*)d_in[21];
  // d_in[22] = df_ln_g (unused: LN of channel-constant rows -> bias only)
  const float* df_ln_b = (const float*)d_in[23];
  const float* wq = (const float*)d_in[24];
  const float* bq = (const float*)d_in[25];
  const float* wv = (const float*)d_in[26];
  const float* bv = (const float*)d_in[27];
  const float* wg = (const float*)d_in[28];
  const float* bg = (const float*)d_in[29];
  const float* op_w = (const float*)d_in[30];
  const float* op_b = (const float*)d_in[31];
  const float* op_ln_g = (const float*)d_in[32];
  const float* op_ln_b = (const float*)d_in[33];
  const float* fn_g = (const float*)d_in[34];
  const float* fn_b = (const float*)d_in[35];
  float* out = (float*)d_out;

  float* ws = (float*)d_ws;
  const size_t NBL = (size_t)Bz * Cz * Lz;  // 8388608 floats
  float* xpw = ws;                          // [NBL]; reused as `fused` later
  float* y = ws + NBL;                      // [4*NBL]
  float* spare = ws + 5 * NBL;              // [NBL]
  // enhanced buffers: reuse dead y slots (sequential branch processing)
  float* e[4] = {spare, y, y + NBL, y + 2 * NBL};
  float* smallb = ws + 6 * NBL;
  float* ysum = smallb;                 // 16384
  float* scv = smallb + 16384;          // 16384
  float* scores = smallb + 32768;       // 65536
  float* pwA = smallb + 98304;          // 512
  float* pwB = pwA + 512;               // 512
  float* dwA = pwB + 512;               // 2048
  float* dwB = dwA + 2048;              // 2048
  float* qc = dwB + 2048;               // 256

  prep_kernel<<<6, 256, 0, stream>>>(pw_b, pw_bn_g, pw_bn_b, pw_bn_m, pw_bn_v,
                                     dw_b, dw_bn_g, dw_bn_b, dw_bn_m, dw_bn_v,
                                     df_ln_b, wq, bq, pwA, pwB, dwA, dwB, qc);

  pw_gemm_kernel<<<dim3(Lz / 64, Cz / 64, Bz), 256, 0, stream>>>(
      x, pw_w, pwA, pwB, xpw);

  dw_conv_kernel<<<4 * Bz * Cz, 256, 0, stream>>>(xpw, dw_w0, dw_w1, dw_w2,
                                                  dw_w3, dwA, dwB, y, ysum);

  se_kernel<<<32, 128, 0, stream>>>(ysum, se_w1, se_b1, se_w2, se_b2, scv);

  for (int i = 0; i < 4; i++) {
    ln_transpose_kernel<<<dim3(Lz / 16, Bz), 256, 0, stream>>>(
        y + (size_t)i * NBL, scv + (size_t)i * Bz * Cz, se_ln_g + i * Cz,
        se_ln_b + i * Cz, e[i]);
  }

  score_gemm_kernel<<<dim3(MT / 64, 4), 256, 0, stream>>>(
      e[0], e[1], e[2], e[3], wv, bv, qc, wg, bg, scores);

  fuse_kernel<<<MT, 128, 0, stream>>>(e[0], e[1], e[2], e[3], scores, xpw);

  op_ln_kernel<<<MT / 32, 256, 0, stream>>>(xpw, op_w, op_b, op_ln_g, op_ln_b,
                                            x, fn_g, fn_b, out);
}

// Round 3
// 740.364 us; speedup vs baseline: 1.0038x; 1.0038x over previous
//
#include <hip/hip_runtime.h>
#include <math.h>

static constexpr int Bz = 8;
static constexpr int Lz = 2048;
static constexpr int Cz = 512;
static constexpr int CRz = 128;
static constexpr int DHz = 256;
static constexpr int MT = Bz * Lz;           // 16384 rows
static constexpr float EPSz = 1e-5f;

// ---------------------------------------------------------------------------
// P: fold BN params (alpha/beta) for pw + dw branches; compute Q const vector
// ---------------------------------------------------------------------------
__global__ __launch_bounds__(256) void prep_kernel(
    const float* __restrict__ pw_b, const float* __restrict__ pw_g,
    const float* __restrict__ pw_bb, const float* __restrict__ pw_m,
    const float* __restrict__ pw_v,
    const float* __restrict__ dw_b, const float* __restrict__ dw_g,
    const float* __restrict__ dw_bb, const float* __restrict__ dw_m,
    const float* __restrict__ dw_v,
    const float* __restrict__ df_ln_b, const float* __restrict__ wq,
    const float* __restrict__ bq,
    float* __restrict__ pwA, float* __restrict__ pwB,
    float* __restrict__ dwA, float* __restrict__ dwB,
    float* __restrict__ qc) {
  const int blk = blockIdx.x;
  const int t = threadIdx.x;
  if (blk == 0) {
    for (int c = t; c < Cz; c += 256) {
      float inv = rsqrtf(pw_v[c] + EPSz);
      float a = pw_g[c] * inv;
      float bb = pw_bb[c] - pw_m[c] * a;
      pwA[c] = a;
      pwB[c] = pw_b[c] * a + bb;
    }
  } else if (blk <= 4) {
    const int i = blk - 1;
    for (int c = t; c < Cz; c += 256) {
      int idx = i * Cz + c;
      float inv = rsqrtf(dw_v[idx] + EPSz);
      float a = dw_g[idx] * inv;
      float bb = dw_bb[idx] - dw_m[idx] * a;
      dwA[idx] = a;
      dwB[idx] = dw_b[idx] * a + bb;
    }
  } else {
    // Q = df_ln_b @ wq.T + bq  (D == df_ln_b analytically: diff_feat is
    // channel-constant so its LayerNorm collapses to the bias)
    if (t < DHz) {
      float s = bq[t];
      const float* w = wq + (size_t)t * Cz;
      for (int c = 0; c < Cz; c++) s += df_ln_b[c] * w[c];
      qc[t] = s;
    }
  }
}

// ---------------------------------------------------------------------------
// A: pointwise conv GEMM  xpw[b,o,l] = relu(alpha[o]*sum_c W[o,c]x[b,l,c]+beta[o])
// grid (L/64, C/64, B), 256 thr, 64x64 tile, 4x4 per thread
// ---------------------------------------------------------------------------
__global__ __launch_bounds__(256) void pw_gemm_kernel(
    const float* __restrict__ x, const float* __restrict__ W,
    const float* __restrict__ alpha, const float* __restrict__ beta,
    float* __restrict__ xpw) {
  __shared__ float sW[16][68];
  __shared__ float sX[16][68];
  const int l0 = blockIdx.x * 64;
  const int o0 = blockIdx.y * 64;
  const int b = blockIdx.z;
  const int t = threadIdx.x;
  const int tn = t & 15, tm = t >> 4;
  const int lrow = t >> 2, lk = (t & 3) * 4;
  float acc[4][4] = {};
  const float* wp = W + (size_t)(o0 + lrow) * Cz + lk;
  const float* xp = x + ((size_t)b * Lz + l0 + lrow) * Cz + lk;
  for (int k0 = 0; k0 < Cz; k0 += 16) {
    float4 w4 = *(const float4*)(wp + k0);
    float4 x4 = *(const float4*)(xp + k0);
    __syncthreads();
    sW[lk + 0][lrow] = w4.x; sW[lk + 1][lrow] = w4.y;
    sW[lk + 2][lrow] = w4.z; sW[lk + 3][lrow] = w4.w;
    sX[lk + 0][lrow] = x4.x; sX[lk + 1][lrow] = x4.y;
    sX[lk + 2][lrow] = x4.z; sX[lk + 3][lrow] = x4.w;
    __syncthreads();
#pragma unroll
    for (int k = 0; k < 16; k++) {
      float a[4], bb[4];
      *(float4*)a = *(const float4*)&sW[k][tm * 4];
      *(float4*)bb = *(const float4*)&sX[k][tn * 4];
#pragma unroll
      for (int m = 0; m < 4; m++)
#pragma unroll
        for (int n = 0; n < 4; n++) acc[m][n] += a[m] * bb[n];
    }
  }
#pragma unroll
  for (int m = 0; m < 4; m++) {
    const int o = o0 + tm * 4 + m;
    const float av = alpha[o], bt = beta[o];
    float4 r;
    r.x = fmaxf(acc[m][0] * av + bt, 0.f);
    r.y = fmaxf(acc[m][1] * av + bt, 0.f);
    r.z = fmaxf(acc[m][2] * av + bt, 0.f);
    r.w = fmaxf(acc[m][3] * av + bt, 0.f);
    *(float4*)(xpw + ((size_t)(b * Cz + o)) * Lz + l0 + tn * 4) = r;
  }
}

// ---------------------------------------------------------------------------
// B: depthwise conv (4 branches) + bias/BN/ReLU folded + per-row sum
// grid 4*B*C blocks, 256 thr; block = one (branch,b,c) row of length L
// ---------------------------------------------------------------------------
__global__ __launch_bounds__(256) void dw_conv_kernel(
    const float* __restrict__ xpw,
    const float* __restrict__ w0, const float* __restrict__ w1,
    const float* __restrict__ w2, const float* __restrict__ w3,
    const float* __restrict__ dwA, const float* __restrict__ dwB,
    float* __restrict__ y, float* __restrict__ ysum) {
  __shared__ float row[Lz];
  __shared__ float wts[20];
  __shared__ float wsum[4];
  const int bx = blockIdx.x;
  const int i = bx >> 12;            // /(B*C)=4096
  const int rem = bx & 4095;
  const int b = rem >> 9;
  const int c = rem & 511;
  const int ks[4] = {3, 7, 15, 20};
  const int k = ks[i];
  const int p = (k - 1) >> 1;
  const int valid = (i == 3) ? (Lz - 1) : Lz;
  const float* w = (i == 0 ? w0 : i == 1 ? w1 : i == 2 ? w2 : w3) + c * k;
  const int t = threadIdx.x;
  const float* src = xpw + ((size_t)(b * Cz + c)) * Lz;
  for (int idx = t; idx < Lz / 4; idx += 256)
    ((float4*)row)[idx] = ((const float4*)src)[idx];
  if (t < k) wts[t] = w[t];
  __syncthreads();
  const float a = dwA[i * Cz + c], bb = dwB[i * Cz + c];
  float* dst = y + ((size_t)((i * Bz + b) * Cz + c)) * Lz;
  float psum = 0.f;
  for (int s = 0; s < 8; s++) {
    const int l = t + s * 256;
    float acc = 0.f;
    for (int j = 0; j < k; j++) {
      const int xi = l + j - p;
      if (xi >= 0 && xi < Lz) acc += wts[j] * row[xi];
    }
    float v = fmaxf(acc * a + bb, 0.f);
    if (l >= valid) v = 0.f;
    dst[l] = v;
    psum += v;
  }
  for (int off = 32; off > 0; off >>= 1) psum += __shfl_down(psum, off, 64);
  if ((t & 63) == 0) wsum[t >> 6] = psum;
  __syncthreads();
  if (t == 0) ysum[(i * Bz + b) * Cz + c] = wsum[0] + wsum[1] + wsum[2] + wsum[3];
}

// ---------------------------------------------------------------------------
// C: squeeze-excite; sc = 1 + sigmoid(relu(ym@w1.T+b1)@w2.T+b2)
// grid 32 = (i,b), 128 thr
// ---------------------------------------------------------------------------
__global__ __launch_bounds__(128) void se_kernel(
    const float* __restrict__ ysum,
    const float* __restrict__ se_w1, const float* __restrict__ se_b1,
    const float* __restrict__ se_w2, const float* __restrict__ se_b2,
    float* __restrict__ sc) {
  const int i = blockIdx.x >> 3;
  const int b = blockIdx.x & 7;
  __shared__ float ym[Cz];
  __shared__ float h[CRz];
  const int t = threadIdx.x;
  const float* ys = ysum + (i * Bz + b) * Cz;
  for (int cc = t; cc < Cz; cc += 128) ym[cc] = ys[cc] * (1.f / Lz);
  __syncthreads();
  {
    const float* w1 = se_w1 + (size_t)i * CRz * Cz + (size_t)t * Cz;
    float s = se_b1[i * CRz + t];
    for (int cc = 0; cc < Cz; cc++) s += ym[cc] * w1[cc];
    h[t] = fmaxf(s, 0.f);
  }
  __syncthreads();
  for (int cc = t; cc < Cz; cc += 128) {
    const float* w2 = se_w2 + ((size_t)i * Cz + cc) * CRz;
    float s = se_b2[i * Cz + cc];
    for (int r = 0; r < CRz; r++) s += h[r] * w2[r];
    float wt = 1.f / (1.f + expf(-s));
    sc[(i * Bz + b) * Cz + cc] = 1.f + wt;
  }
}

// ---------------------------------------------------------------------------
// D: enhanced = LN_c( y[b,c,l]*sc[b,c] ), transposing (B,C,L)->(B,L,C)
// grid (L/16, B) per branch, 256 thr
// ---------------------------------------------------------------------------
__global__ __launch_bounds__(256) void ln_transpose_kernel(
    const float* __restrict__ ysrc, const float* __restrict__ sc,
    const float* __restrict__ g, const float* __restrict__ bb,
    float* __restrict__ edst) {
  __shared__ float tile[16][Cz + 1];
  const int l0 = blockIdx.x * 16;
  const int b = blockIdx.y;
  const int t = threadIdx.x;
  const float* yb = ysrc + (size_t)b * Cz * Lz;
  const float* scb = sc + b * Cz;
  for (int s = 0; s < 8; s++) {
    const int idx = s * 256 + t;
    const int c = idx >> 2;
    const int l4 = (idx & 3) * 4;
    float4 v = *(const float4*)(yb + (size_t)c * Lz + l0 + l4);
    const float scale = scb[c];
    tile[l4 + 0][c] = v.x * scale;
    tile[l4 + 1][c] = v.y * scale;
    tile[l4 + 2][c] = v.z * scale;
    tile[l4 + 3][c] = v.w * scale;
  }
  __syncthreads();
  const int wave = t >> 6, lane = t & 63;
  float* eb = edst + ((size_t)b * Lz + l0) * Cz;
  for (int r = wave; r < 16; r += 4) {
    float vals[8];
    float s1 = 0.f, s2 = 0.f;
#pragma unroll
    for (int j = 0; j < 8; j++) {
      float v = tile[r][lane + j * 64];
      vals[j] = v; s1 += v; s2 += v * v;
    }
    for (int off = 32; off > 0; off >>= 1) {
      s1 += __shfl_xor(s1, off, 64);
      s2 += __shfl_xor(s2, off, 64);
    }
    const float m = s1 * (1.f / Cz);
    const float var = s2 * (1.f / Cz) - m * m;
    const float inv = rsqrtf(var + EPSz);
#pragma unroll
    for (int j = 0; j < 8; j++) {
      const int cc = lane + j * 64;
      eb[(size_t)r * Cz + cc] = (vals[j] - m) * inv * g[cc] + bb[cc];
    }
  }
}

// ---------------------------------------------------------------------------
// E: score GEMM: Vi = e_i @ wv.T + bv; score_i = sum_d tanh(qc*Vi)*wg + bg
// grid (MT/64, 4), 256 thr; 64 rows x full DH=256
// ---------------------------------------------------------------------------
__global__ __launch_bounds__(256) void score_gemm_kernel(
    const float* __restrict__ e0, const float* __restrict__ e1,
    const float* __restrict__ e2, const float* __restrict__ e3,
    const float* __restrict__ wv, const float* __restrict__ bv,
    const float* __restrict__ qc, const float* __restrict__ wg,
    const float* __restrict__ bg, float* __restrict__ scores) {
  __shared__ float sA[16][68];
  __shared__ float sW[16][260];
  const int i = blockIdx.y;
  const float* E = (i == 0) ? e0 : (i == 1) ? e1 : (i == 2) ? e2 : e3;
  const int r0 = blockIdx.x * 64;
  const int t = threadIdx.x;
  const int tn = t & 15, tm = t >> 4;
  const int lrow = t >> 2, lk = (t & 3) * 4;
  float acc[4][16] = {};
  const float* ep = E + (size_t)(r0 + lrow) * Cz + lk;
  const float* wp = wv + (size_t)lrow * Cz + lk;
  for (int k0 = 0; k0 < Cz; k0 += 16) {
    float4 a4 = *(const float4*)(ep + k0);
    float4 q0 = *(const float4*)(wp + k0);
    float4 q1 = *(const float4*)(wp + (size_t)64 * Cz + k0);
    float4 q2 = *(const float4*)(wp + (size_t)128 * Cz + k0);
    float4 q3 = *(const float4*)(wp + (size_t)192 * Cz + k0);
    __syncthreads();
    sA[lk + 0][lrow] = a4.x; sA[lk + 1][lrow] = a4.y;
    sA[lk + 2][lrow] = a4.z; sA[lk + 3][lrow] = a4.w;
    sW[lk + 0][lrow] = q0.x; sW[lk + 1][lrow] = q0.y;
    sW[lk + 2][lrow] = q0.z; sW[lk + 3][lrow] = q0.w;
    sW[lk + 0][lrow + 64] = q1.x; sW[lk + 1][lrow + 64] = q1.y;
    sW[lk + 2][lrow + 64] = q1.z; sW[lk + 3][lrow + 64] = q1.w;
    sW[lk + 0][lrow + 128] = q2.x; sW[lk + 1][lrow + 128] = q2.y;
    sW[lk + 2][lrow + 128] = q2.z; sW[lk + 3][lrow + 128] = q2.w;
    sW[lk + 0][lrow + 192] = q3.x; sW[lk + 1][lrow + 192] = q3.y;
    sW[lk + 2][lrow + 192] = q3.z; sW[lk + 3][lrow + 192] = q3.w;
    __syncthreads();
#pragma unroll
    for (int k = 0; k < 16; k++) {
      float a[4];
      *(float4*)a = *(const float4*)&sA[k][tm * 4];
#pragma unroll
      for (int q = 0; q < 4; q++) {
        float w[4];
        *(float4*)w = *(const float4*)&sW[k][tn * 4 + q * 64];
#pragma unroll
        for (int m = 0; m < 4; m++)
#pragma unroll
          for (int r = 0; r < 4; r++) acc[m][q * 4 + r] += a[m] * w[r];
      }
    }
  }
  float part[4] = {0.f, 0.f, 0.f, 0.f};
#pragma unroll
  for (int q = 0; q < 4; q++) {
    const int n = tn * 4 + q * 64;
    float bv4[4], qc4[4], wg4[4];
    *(float4*)bv4 = *(const float4*)(bv + n);
    *(float4*)qc4 = *(const float4*)(qc + n);
    *(float4*)wg4 = *(const float4*)(wg + n);
#pragma unroll
    for (int r = 0; r < 4; r++)
#pragma unroll
      for (int m = 0; m < 4; m++)
        part[m] += tanhf(qc4[r] * (acc[m][q * 4 + r] + bv4[r])) * wg4[r];
  }
#pragma unroll
  for (int off = 1; off < 16; off <<= 1) {
#pragma unroll
    for (int m = 0; m < 4; m++) part[m] += __shfl_xor(part[m], off, 64);
  }
  if (tn == 0) {
    const float bgv = bg[0];
#pragma unroll
    for (int m = 0; m < 4; m++)
      scores[(size_t)i * MT + r0 + tm * 4 + m] = part[m] + bgv;
  }
}

// ---------------------------------------------------------------------------
// F: softmax over 4 branch scores + weighted combine of enhanced
// grid MT, 128 thr (4 floats each)
// ---------------------------------------------------------------------------
__global__ __launch_bounds__(128) void fuse_kernel(
    const float* __restrict__ e0, const float* __restrict__ e1,
    const float* __restrict__ e2, const float* __restrict__ e3,
    const float* __restrict__ scores, float* __restrict__ fused) {
  const int r = blockIdx.x;
  float s0 = scores[r], s1 = scores[MT + r], s2 = scores[2 * MT + r],
        s3 = scores[3 * MT + r];
  float mx = fmaxf(fmaxf(s0, s1), fmaxf(s2, s3));
  float x0 = expf(s0 - mx), x1 = expf(s1 - mx), x2 = expf(s2 - mx),
        x3 = expf(s3 - mx);
  float inv = 1.f / (x0 + x1 + x2 + x3);
  x0 *= inv; x1 *= inv; x2 *= inv; x3 *= inv;
  const int t = threadIdx.x;
  const size_t base = (size_t)r * Cz;
  float4 v0 = ((const float4*)(e0 + base))[t];
  float4 v1 = ((const float4*)(e1 + base))[t];
  float4 v2 = ((const float4*)(e2 + base))[t];
  float4 v3 = ((const float4*)(e3 + base))[t];
  float4 o;
  o.x = x0 * v0.x + x1 * v1.x + x2 * v2.x + x3 * v3.x;
  o.y = x0 * v0.y + x1 * v1.y + x2 * v2.y + x3 * v3.y;
  o.z = x0 * v0.z + x1 * v1.z + x2 * v2.z + x3 * v3.z;
  o.w = x0 * v0.w + x1 * v1.w + x2 * v2.w + x3 * v3.w;
  ((float4*)(fused + base))[t] = o;
}

// ---------------------------------------------------------------------------
// G: out = LN( LN(fused@op_w.T + op_b) + x )
// grid MT/32, 256 thr; block = 32 rows x full C=512
// ---------------------------------------------------------------------------
__global__ __launch_bounds__(256) void op_ln_kernel(
    const float* __restrict__ fusedp, const float* __restrict__ opw,
    const float* __restrict__ opb, const float* __restrict__ g1,
    const float* __restrict__ b1, const float* __restrict__ x,
    const float* __restrict__ g2, const float* __restrict__ b2,
    float* __restrict__ out) {
  __shared__ float sA[16][36];
  __shared__ float sW[16][516];
  const int r0 = blockIdx.x * 32;
  const int t = threadIdx.x;
  const int tn = t & 15, tm = t >> 4;
  const int lrow = t >> 2, lk = (t & 3) * 4;
  float acc[2][32] = {};
  const float* wp = opw + (size_t)lrow * Cz + lk;
  for (int k0 = 0; k0 < Cz; k0 += 16) {
    float4 a4 = make_float4(0.f, 0.f, 0.f, 0.f);
    if (t < 128)
      a4 = *(const float4*)(fusedp + (size_t)(r0 + (t >> 2)) * Cz + k0 +
                            (t & 3) * 4);
    float4 w4[8];
#pragma unroll
    for (int s = 0; s < 8; s++)
      w4[s] = *(const float4*)(wp + (size_t)s * 64 * Cz + k0);
    __syncthreads();
    if (t < 128) {
      sA[lk + 0][lrow] = a4.x; sA[lk + 1][lrow] = a4.y;
      sA[lk + 2][lrow] = a4.z; sA[lk + 3][lrow] = a4.w;
    }
#pragma unroll
    for (int s = 0; s < 8; s++) {
      sW[lk + 0][lrow + s * 64] = w4[s].x;
      sW[lk + 1][lrow + s * 64] = w4[s].y;
      sW[lk + 2][lrow + s * 64] = w4[s].z;
      sW[lk + 3][lrow + s * 64] = w4[s].w;
    }
    __syncthreads();
#pragma unroll
    for (int k = 0; k < 16; k++) {
      const float a0 = sA[k][tm * 2], a1 = sA[k][tm * 2 + 1];
#pragma unroll
      for (int q = 0; q < 8; q++) {
        float w[4];
        *(float4*)w = *(const float4*)&sW[k][tn * 4 + q * 64];
#pragma unroll
        for (int r = 0; r < 4; r++) {
          acc[0][q * 4 + r] += a0 * w[r];
          acc[1][q * 4 + r] += a1 * w[r];
        }
      }
    }
  }
#pragma unroll
  for (int j = 0; j < 2; j++) {
    const int row = r0 + tm * 2 + j;
    float s1 = 0.f, s2 = 0.f;
#pragma unroll
    for (int q = 0; q < 8; q++) {
      const int n = tn * 4 + q * 64;
      float ob[4];
      *(float4*)ob = *(const float4*)(opb + n);
#pragma unroll
      for (int r = 0; r < 4; r++) {
        float z = acc[j][q * 4 + r] + ob[r];
        acc[j][q * 4 + r] = z;
        s1 += z; s2 += z * z;
      }
    }
#pragma unroll
    for (int off = 1; off < 16; off <<= 1) {
      s1 += __shfl_xor(s1, off, 64);
      s2 += __shfl_xor(s2, off, 64);
    }
    const float m1 = s1 * (1.f / Cz);
    const float iv1 = rsqrtf(s2 * (1.f / Cz) - m1 * m1 + EPSz);
    s1 = 0.f; s2 = 0.f;
#pragma unroll
    for (int q = 0; q < 8; q++) {
      const int n = tn * 4 + q * 64;
      float gg[4], bb[4], xv[4];
      *(float4*)gg = *(const float4*)(g1 + n);
      *(float4*)bb = *(const float4*)(b1 + n);
      *(float4*)xv = *(const float4*)(x + (size_t)row * Cz + n);
#pragma unroll
      for (int r = 0; r < 4; r++) {
        float tt = (acc[j][q * 4 + r] - m1) * iv1 * gg[r] + bb[r] + xv[r];
        acc[j][q * 4 + r] = tt;
        s1 += tt; s2 += tt * tt;
      }
    }
#pragma unroll
    for (int off = 1; off < 16; off <<= 1) {
      s1 += __shfl_xor(s1, off, 64);
      s2 += __shfl_xor(s2, off, 64);
    }
    const float m2 = s1 * (1.f / Cz);
    const float iv2 = rsqrtf(s2 * (1.f / Cz) - m2 * m2 + EPSz);
#pragma unroll
    for (int q = 0; q < 8; q++) {
      const int n = tn * 4 + q * 64;
      float gg[4], bb[4];
      *(float4*)gg = *(const float4*)(g2 + n);
      *(float4*)bb = *(const float4*)(b2 + n);
      float4 o;
      o.x = (acc[j][q * 4 + 0] - m2) * iv2 * gg[0] + bb[0];
      o.y = (acc[j][q * 4 + 1] - m2) * iv2 * gg[1] + bb[1];
      o.z = (acc[j][q * 4 + 2] - m2) * iv2 * gg[2] + bb[2];
      o.w = (acc[j][q * 4 + 3] - m2) * iv2 * gg[3] + bb[3];
      *(float4*)(out + (size_t)row * Cz + n) = o;
    }
  }
}

// ---------------------------------------------------------------------------
extern "C" void kernel_launch(void* const* d_in, const int* in_sizes, int n_in,
                              void* d_out, int out_size, void* d_ws,
                              size_t ws_size, hipStream_t stream) {
  const float* x = (const float*)d_in[0];
  const float* pw_w = (const float*)d_in[1];
  const float* pw_b = (const float*)d_in[2];
  const float* pw_bn_g = (const float*)d_in[3];
  const float* pw_bn_b = (const float*)d_in[4];
  const float* pw_bn_m = (const float*)d_in[5];
  const float* pw_bn_v = (const float*)d_in[6];
  const float* dw_w0 = (const float*)d_in[7];
  const float* dw_w1 = (const float*)d_in[8];
  const float* dw_w2 = (const float*)d_in[9];
  const float* dw_w3 = (const float*)d_in[10];
  const float* dw_b = (const float*)d_in[11];
  const float* dw_bn_g = (const float*)d_in[12];
  const float* dw_bn_b = (const float*)d_in[13];
  const float* dw_bn_m = (const float*)d_in[14];
  const float* dw_bn_v = (const float*)d_in[15];
  const float* se_w1 = (const float*)d_in[16];
  const float* se_b1 = (const float*)d_in[17];
  const float* se_w2 = (const float*)d_in[18];
  const float* se_b2 = (const float*)d_in[19];
  const float* se_ln_g = (const float*)d_in[20];
  const float* se_ln_b = (const float*)d_in[21];
  // d_in[22] = df_ln_g (unused: LN of channel-constant rows -> bias only)
  const float* df_ln_b = (const float*)d_in[23];
  const float* wq = (const float*)d_in[24];
  const float* bq = (const float*)d_in[25];
  const float* wv = (const float*)d_in[26];
  const float* bv = (const float*)d_in[27];
  const float* wg = (const float*)d_in[28];
  const float* bg = (const float*)d_in[29];
  const float* op_w = (const float*)d_in[30];
  const float* op_b = (const float*)d_in[31];
  const float* op_ln_g = (const float*)d_in[32];
  const float* op_ln_b = (const float*)d_in[33];
  const float* fn_g = (const float*)d_in[34];
  const float* fn_b = (const float*)d_in[35];
  float* out = (float*)d_out;

  float* ws = (float*)d_ws;
  const size_t NBL = (size_t)Bz * Cz * Lz;  // 8388608 floats
  float* xpw = ws;                          // [NBL]; reused as `fused` later
  float* y = ws + NBL;                      // [4*NBL]
  float* spare = ws + 5 * NBL;              // [NBL]
  // enhanced buffers: reuse dead y slots (sequential branch processing)
  float* e[4] = {spare, y, y + NBL, y + 2 * NBL};
  float* smallb = ws + 6 * NBL;
  float* ysum = smallb;                 // 16384
  float* scv = smallb + 16384;          // 16384
  float* scores = smallb + 32768;       // 65536
  float* pwA = smallb + 98304;          // 512
  float* pwB = pwA + 512;               // 512
  float* dwA = pwB + 512;               // 2048
  float* dwB = dwA + 2048;              // 2048
  float* qc = dwB + 2048;               // 256

  prep_kernel<<<6, 256, 0, stream>>>(pw_b, pw_bn_g, pw_bn_b, pw_bn_m, pw_bn_v,
                                     dw_b, dw_bn_g, dw_bn_b, dw_bn_m, dw_bn_v,
                                     df_ln_b, wq, bq, pwA, pwB, dwA, dwB, qc);

  pw_gemm_kernel<<<dim3(Lz / 64, Cz / 64, Bz), 256, 0, stream>>>(
      x, pw_w, pwA, pwB, xpw);

  dw_conv_kernel<<<4 * Bz * Cz, 256, 0, stream>>>(xpw, dw_w0, dw_w1, dw_w2,
                                                  dw_w3, dwA, dwB, y, ysum);

  se_kernel<<<32, 128, 0, stream>>>(ysum, se_w1, se_b1, se_w2, se_b2, scv);

  for (int i = 0; i < 4; i++) {
    ln_transpose_kernel<<<dim3(Lz / 16, Bz), 256, 0, stream>>>(
        y + (size_t)i * NBL, scv + (size_t)i * Bz * Cz, se_ln_g + i * Cz,
        se_ln_b + i * Cz, e[i]);
  }

  score_gemm_kernel<<<dim3(MT / 64, 4), 256, 0, stream>>>(
      e[0], e[1], e[2], e[3], wv, bv, qc, wg, bg, scores);

  fuse_kernel<<<MT, 128, 0, stream>>>(e[0], e[1], e[2], e[3], scores, xpw);

  op_ln_kernel<<<MT / 32, 256, 0, stream>>>(xpw, op_w, op_b, op_ln_g, op_ln_b,
                                            x, fn_g, fn_b, out);
}

// Round 4
// 332.060 us; speedup vs baseline: 2.2381x; 2.2296x over previous
//
#include <hip/hip_runtime.h>
#include <math.h>

static constexpr int Bz = 8;
static constexpr int Lz = 2048;
static constexpr int Cz = 512;
static constexpr int CRz = 128;
static constexpr int DHz = 256;
static constexpr int MT = Bz * Lz;           // 16384 rows
static constexpr float EPSz = 1e-5f;

typedef unsigned short u16;
typedef __bf16 bf16x8 __attribute__((ext_vector_type(8)));
typedef float f32x4 __attribute__((ext_vector_type(4)));
typedef unsigned short u16x8 __attribute__((ext_vector_type(8)));

__device__ __forceinline__ float bf2f(u16 u) {
  unsigned int v = ((unsigned int)u) << 16;
  return __builtin_bit_cast(float, v);
}
__device__ __forceinline__ u16 f2bf(float f) {
  unsigned int b = __builtin_bit_cast(unsigned int, f);
  b += 0x7FFFu + ((b >> 16) & 1u);
  return (u16)(b >> 16);
}
__device__ __forceinline__ f32x4 mfma16(bf16x8 a, bf16x8 b, f32x4 c) {
  return __builtin_amdgcn_mfma_f32_16x16x32_bf16(a, b, c, 0, 0, 0);
}

// ---------------------------------------------------------------------------
// cvt: fp32 -> bf16 (8 elems/thread)
// ---------------------------------------------------------------------------
__global__ __launch_bounds__(256) void cvt_bf16_kernel(
    const float* __restrict__ src, u16* __restrict__ dst, int n8) {
  int i = blockIdx.x * 256 + threadIdx.x;
  if (i >= n8) return;
  const float4* s = (const float4*)src;
  float4 a = s[i * 2], b = s[i * 2 + 1];
  u16x8 o;
  o[0] = f2bf(a.x); o[1] = f2bf(a.y); o[2] = f2bf(a.z); o[3] = f2bf(a.w);
  o[4] = f2bf(b.x); o[5] = f2bf(b.y); o[6] = f2bf(b.z); o[7] = f2bf(b.w);
  ((u16x8*)dst)[i] = o;
}

// ---------------------------------------------------------------------------
// P: fold BN params; compute Q const vector (diff-path LN collapses to bias)
// ---------------------------------------------------------------------------
__global__ __launch_bounds__(256) void prep_kernel(
    const float* __restrict__ pw_b, const float* __restrict__ pw_g,
    const float* __restrict__ pw_bb, const float* __restrict__ pw_m,
    const float* __restrict__ pw_v,
    const float* __restrict__ dw_b, const float* __restrict__ dw_g,
    const float* __restrict__ dw_bb, const float* __restrict__ dw_m,
    const float* __restrict__ dw_v,
    const float* __restrict__ df_ln_b, const float* __restrict__ wq,
    const float* __restrict__ bq,
    float* __restrict__ pwA, float* __restrict__ pwB,
    float* __restrict__ dwA, float* __restrict__ dwB,
    float* __restrict__ qc) {
  const int blk = blockIdx.x;
  const int t = threadIdx.x;
  if (blk == 0) {
    for (int c = t; c < Cz; c += 256) {
      float inv = rsqrtf(pw_v[c] + EPSz);
      float a = pw_g[c] * inv;
      float bb = pw_bb[c] - pw_m[c] * a;
      pwA[c] = a;
      pwB[c] = pw_b[c] * a + bb;
    }
  } else if (blk <= 4) {
    const int i = blk - 1;
    for (int c = t; c < Cz; c += 256) {
      int idx = i * Cz + c;
      float inv = rsqrtf(dw_v[idx] + EPSz);
      float a = dw_g[idx] * inv;
      float bb = dw_bb[idx] - dw_m[idx] * a;
      dwA[idx] = a;
      dwB[idx] = dw_b[idx] * a + bb;
    }
  } else {
    if (t < DHz) {
      float s = bq[t];
      const float* w = wq + (size_t)t * Cz;
      for (int c = 0; c < Cz; c++) s += df_ln_b[c] * w[c];
      qc[t] = s;
    }
  }
}

// ---------------------------------------------------------------------------
// A: pointwise conv via MFMA. C[o][l] = W(o,c) @ x[b](l,c)^T, per batch.
// A = pw_w bf16 (512x512), B^T = xbf[b] (2048x512). Epilogue relu(a*v+b) bf16.
// grid (L/64, C/64, B), 256 thr, 64x64 tile, 4 waves 2x2.
// ---------------------------------------------------------------------------
__global__ __launch_bounds__(256) void pw_mfma_kernel(
    const u16* __restrict__ Wbf, const u16* __restrict__ xbf,
    const float* __restrict__ alpha, const float* __restrict__ beta,
    u16* __restrict__ xpw) {
  __shared__ u16 sA[64][40];
  __shared__ u16 sB[64][40];
  __shared__ u16 sC[64][64];
  const int n0 = blockIdx.x * 64;   // l
  const int m0 = blockIdx.y * 64;   // o
  const int bat = blockIdx.z;
  const int t = threadIdx.x;
  const int lane = t & 63, w = t >> 6;
  const int wm = w >> 1, wn = w & 1;
  const int srow = t >> 2, skoff = (t & 3) * 8;
  f32x4 acc[2][2];
#pragma unroll
  for (int m = 0; m < 2; m++)
#pragma unroll
    for (int n = 0; n < 2; n++)
#pragma unroll
      for (int r = 0; r < 4; r++) acc[m][n][r] = 0.f;
  const u16* ap = Wbf + (size_t)(m0 + srow) * Cz + skoff;
  const u16* bp = xbf + ((size_t)bat * Lz + n0 + srow) * Cz + skoff;
  const int fr = lane & 15, fk = (lane >> 4) * 8;
  for (int k0 = 0; k0 < Cz; k0 += 32) {
    u16x8 av = *(const u16x8*)(ap + k0);
    u16x8 bv = *(const u16x8*)(bp + k0);
    __syncthreads();
    *(u16x8*)&sA[srow][skoff] = av;
    *(u16x8*)&sB[srow][skoff] = bv;
    __syncthreads();
    bf16x8 a0 = *(const bf16x8*)&sA[wm * 32 + fr][fk];
    bf16x8 a1 = *(const bf16x8*)&sA[wm * 32 + 16 + fr][fk];
    bf16x8 b0 = *(const bf16x8*)&sB[wn * 32 + fr][fk];
    bf16x8 b1 = *(const bf16x8*)&sB[wn * 32 + 16 + fr][fk];
    acc[0][0] = mfma16(a0, b0, acc[0][0]);
    acc[0][1] = mfma16(a0, b1, acc[0][1]);
    acc[1][0] = mfma16(a1, b0, acc[1][0]);
    acc[1][1] = mfma16(a1, b1, acc[1][1]);
  }
#pragma unroll
  for (int mf = 0; mf < 2; mf++) {
#pragma unroll
    for (int r = 0; r < 4; r++) {
      const int row = wm * 32 + mf * 16 + ((lane >> 4) << 2) + r;
      const float al = alpha[m0 + row], be = beta[m0 + row];
#pragma unroll
      for (int nf = 0; nf < 2; nf++) {
        const int col = wn * 32 + nf * 16 + (lane & 15);
        float v = fmaxf(acc[mf][nf][r] * al + be, 0.f);
        sC[row][col] = f2bf(v);
      }
    }
  }
  __syncthreads();
  const int row = t >> 2, c0 = (t & 3) * 16;
  u16x8 v0 = *(const u16x8*)&sC[row][c0];
  u16x8 v1 = *(const u16x8*)&sC[row][c0 + 8];
  u16* dst = xpw + ((size_t)(bat * Cz + m0 + row)) * Lz + n0 + c0;
  *(u16x8*)dst = v0;
  *(u16x8*)(dst + 8) = v1;
}

// ---------------------------------------------------------------------------
// B: depthwise conv (4 branches) + BN/ReLU folded + per-row sum. bf16 io.
// grid 4*B*C, 256 thr; block = one (branch,b,c) row of length L
// ---------------------------------------------------------------------------
__global__ __launch_bounds__(256) void dw_conv_kernel(
    const u16* __restrict__ xpw,
    const float* __restrict__ w0, const float* __restrict__ w1,
    const float* __restrict__ w2, const float* __restrict__ w3,
    const float* __restrict__ dwA, const float* __restrict__ dwB,
    u16* __restrict__ y, float* __restrict__ ysum) {
  __shared__ float row[Lz];
  __shared__ float wts[20];
  __shared__ float wsum[4];
  const int bx = blockIdx.x;
  const int i = bx >> 12;
  const int rem = bx & 4095;
  const int b = rem >> 9;
  const int c = rem & 511;
  const int ks[4] = {3, 7, 15, 20};
  const int k = ks[i];
  const int p = (k - 1) >> 1;
  const int valid = (i == 3) ? (Lz - 1) : Lz;
  const float* w = (i == 0 ? w0 : i == 1 ? w1 : i == 2 ? w2 : w3) + c * k;
  const int t = threadIdx.x;
  const u16* src = xpw + ((size_t)(b * Cz + c)) * Lz;
  {
    u16x8 v = ((const u16x8*)src)[t];
#pragma unroll
    for (int j = 0; j < 8; j++) row[t * 8 + j] = bf2f(v[j]);
  }
  if (t < k) wts[t] = w[t];
  __syncthreads();
  const float a = dwA[i * Cz + c], bb = dwB[i * Cz + c];
  u16* dst = y + ((size_t)((i * Bz + b) * Cz + c)) * Lz;
  float psum = 0.f;
  for (int s = 0; s < 8; s++) {
    const int l = t + s * 256;
    float acc = 0.f;
    for (int j = 0; j < k; j++) {
      const int xi = l + j - p;
      if (xi >= 0 && xi < Lz) acc += wts[j] * row[xi];
    }
    float v = fmaxf(acc * a + bb, 0.f);
    if (l >= valid) v = 0.f;
    dst[l] = f2bf(v);
    psum += v;
  }
  for (int off = 32; off > 0; off >>= 1) psum += __shfl_down(psum, off, 64);
  if ((t & 63) == 0) wsum[t >> 6] = psum;
  __syncthreads();
  if (t == 0) ysum[(i * Bz + b) * Cz + c] = wsum[0] + wsum[1] + wsum[2] + wsum[3];
}

// ---------------------------------------------------------------------------
// C: squeeze-excite; sc = 1 + sigmoid(relu(ym@w1.T+b1)@w2.T+b2)
// ---------------------------------------------------------------------------
__global__ __launch_bounds__(128) void se_kernel(
    const float* __restrict__ ysum,
    const float* __restrict__ se_w1, const float* __restrict__ se_b1,
    const float* __restrict__ se_w2, const float* __restrict__ se_b2,
    float* __restrict__ sc) {
  const int i = blockIdx.x >> 3;
  const int b = blockIdx.x & 7;
  __shared__ float ym[Cz];
  __shared__ float h[CRz];
  const int t = threadIdx.x;
  const float* ys = ysum + (i * Bz + b) * Cz;
  for (int cc = t; cc < Cz; cc += 128) ym[cc] = ys[cc] * (1.f / Lz);
  __syncthreads();
  {
    const float* w1 = se_w1 + (size_t)i * CRz * Cz + (size_t)t * Cz;
    float s = se_b1[i * CRz + t];
    for (int cc = 0; cc < Cz; cc++) s += ym[cc] * w1[cc];
    h[t] = fmaxf(s, 0.f);
  }
  __syncthreads();
  for (int cc = t; cc < Cz; cc += 128) {
    const float* w2 = se_w2 + ((size_t)i * Cz + cc) * CRz;
    float s = se_b2[i * Cz + cc];
    for (int r = 0; r < CRz; r++) s += h[r] * w2[r];
    float wt = 1.f / (1.f + expf(-s));
    sc[(i * Bz + b) * Cz + cc] = 1.f + wt;
  }
}

// ---------------------------------------------------------------------------
// D: enhanced = LN_c( y[b,c,l]*sc[b,c] ), transpose (B,C,L)->(B,L,C), bf16 io
// grid (L/16, B) per branch, 256 thr
// ---------------------------------------------------------------------------
__global__ __launch_bounds__(256) void ln_transpose_kernel(
    const u16* __restrict__ ysrc, const float* __restrict__ sc,
    const float* __restrict__ g, const float* __restrict__ bb,
    u16* __restrict__ edst) {
  __shared__ float tile[16][Cz + 1];
  const int l0 = blockIdx.x * 16;
  const int b = blockIdx.y;
  const int t = threadIdx.x;
  const u16* yb = ysrc + (size_t)b * Cz * Lz;
  const float* scb = sc + b * Cz;
#pragma unroll
  for (int s = 0; s < 4; s++) {
    const int idx = s * 256 + t;
    const int c = idx >> 1;
    const int l8 = (idx & 1) * 8;
    u16x8 v = *(const u16x8*)(yb + (size_t)c * Lz + l0 + l8);
    const float scale = scb[c];
#pragma unroll
    for (int j = 0; j < 8; j++) tile[l8 + j][c] = bf2f(v[j]) * scale;
  }
  __syncthreads();
  const int wave = t >> 6, lane = t & 63;
  u16* eb = edst + ((size_t)b * Lz + l0) * Cz;
  for (int r = wave; r < 16; r += 4) {
    float vals[8];
    float s1 = 0.f, s2 = 0.f;
#pragma unroll
    for (int j = 0; j < 8; j++) {
      float v = tile[r][lane + j * 64];
      vals[j] = v; s1 += v; s2 += v * v;
    }
    for (int off = 32; off > 0; off >>= 1) {
      s1 += __shfl_xor(s1, off, 64);
      s2 += __shfl_xor(s2, off, 64);
    }
    const float m = s1 * (1.f / Cz);
    const float var = s2 * (1.f / Cz) - m * m;
    const float inv = rsqrtf(var + EPSz);
#pragma unroll
    for (int j = 0; j < 8; j++) {
      const int cc = lane + j * 64;
      eb[(size_t)r * Cz + cc] = f2bf((vals[j] - m) * inv * g[cc] + bb[cc]);
    }
  }
}

// ---------------------------------------------------------------------------
// E: score via MFMA. Per branch: V = e @ wv^T + bv; score = sum tanh(qc*V)*wg.
// grid (MT/64, 4), 256 thr; wave w owns rows w*16..+16; nt loops 4x64 cols.
// ---------------------------------------------------------------------------
__global__ __launch_bounds__(256) void score_mfma_kernel(
    const u16* __restrict__ e0, const u16* __restrict__ e1,
    const u16* __restrict__ e2, const u16* __restrict__ e3,
    const u16* __restrict__ wvbf, const float* __restrict__ bv,
    const float* __restrict__ qc, const float* __restrict__ wg,
    const float* __restrict__ bg, float* __restrict__ scores) {
  __shared__ u16 sA[64][40];
  __shared__ u16 sB[64][40];
  const int i = blockIdx.y;
  const u16* E = (i == 0) ? e0 : (i == 1) ? e1 : (i == 2) ? e2 : e3;
  const int r0 = blockIdx.x * 64;
  const int t = threadIdx.x;
  const int lane = t & 63, w = t >> 6;
  const int srow = t >> 2, skoff = (t & 3) * 8;
  const int fr = lane & 15, fk = (lane >> 4) * 8;
  const u16* ap = E + (size_t)(r0 + srow) * Cz + skoff;
  float part[4] = {0.f, 0.f, 0.f, 0.f};
  for (int nt = 0; nt < 4; nt++) {
    const u16* bp = wvbf + (size_t)(nt * 64 + srow) * Cz + skoff;
    f32x4 acc[4];
#pragma unroll
    for (int nf = 0; nf < 4; nf++)
#pragma unroll
      for (int r = 0; r < 4; r++) acc[nf][r] = 0.f;
    for (int k0 = 0; k0 < Cz; k0 += 32) {
      u16x8 av = *(const u16x8*)(ap + k0);
      u16x8 bv8 = *(const u16x8*)(bp + k0);
      __syncthreads();
      *(u16x8*)&sA[srow][skoff] = av;
      *(u16x8*)&sB[srow][skoff] = bv8;
      __syncthreads();
      bf16x8 a = *(const bf16x8*)&sA[w * 16 + fr][fk];
#pragma unroll
      for (int nf = 0; nf < 4; nf++) {
        bf16x8 bfr = *(const bf16x8*)&sB[nf * 16 + fr][fk];
        acc[nf] = mfma16(a, bfr, acc[nf]);
      }
    }
#pragma unroll
    for (int nf = 0; nf < 4; nf++) {
      const int n = nt * 64 + nf * 16 + (lane & 15);
      const float bvn = bv[n], qcn = qc[n], wgn = wg[n];
#pragma unroll
      for (int r = 0; r < 4; r++)
        part[r] += tanhf(qcn * (acc[nf][r] + bvn)) * wgn;
    }
  }
#pragma unroll
  for (int off = 1; off < 16; off <<= 1) {
#pragma unroll
    for (int r = 0; r < 4; r++) part[r] += __shfl_xor(part[r], off, 64);
  }
  if ((lane & 15) == 0) {
    const float bgv = bg[0];
#pragma unroll
    for (int r = 0; r < 4; r++)
      scores[(size_t)i * MT + r0 + w * 16 + ((lane >> 4) << 2) + r] =
          part[r] + bgv;
  }
}

// ---------------------------------------------------------------------------
// F: softmax over 4 branch scores + weighted combine (bf16 io)
// grid MT/4, 256 thr
// ---------------------------------------------------------------------------
__global__ __launch_bounds__(256) void fuse_kernel(
    const u16* __restrict__ e0, const u16* __restrict__ e1,
    const u16* __restrict__ e2, const u16* __restrict__ e3,
    const float* __restrict__ scores, u16* __restrict__ fused) {
  const int t = threadIdx.x;
  const int r = blockIdx.x * 4 + (t >> 6);
  const int lane = t & 63;
  float s0 = scores[r], s1 = scores[MT + r], s2 = scores[2 * MT + r],
        s3 = scores[3 * MT + r];
  float mx = fmaxf(fmaxf(s0, s1), fmaxf(s2, s3));
  float x0 = expf(s0 - mx), x1 = expf(s1 - mx), x2 = expf(s2 - mx),
        x3 = expf(s3 - mx);
  float inv = 1.f / (x0 + x1 + x2 + x3);
  x0 *= inv; x1 *= inv; x2 *= inv; x3 *= inv;
  const size_t base = (size_t)r * Cz + lane * 8;
  u16x8 v0 = *(const u16x8*)(e0 + base);
  u16x8 v1 = *(const u16x8*)(e1 + base);
  u16x8 v2 = *(const u16x8*)(e2 + base);
  u16x8 v3 = *(const u16x8*)(e3 + base);
  u16x8 o;
#pragma unroll
  for (int j = 0; j < 8; j++)
    o[j] = f2bf(x0 * bf2f(v0[j]) + x1 * bf2f(v1[j]) + x2 * bf2f(v2[j]) +
                x3 * bf2f(v3[j]));
  *(u16x8*)(fused + base) = o;
}

// ---------------------------------------------------------------------------
// G: op GEMM via MFMA: oproj = fused @ op_w^T + op_b (fp32 out)
// grid (MT/64, C/64), 256 thr, 64x64 tile
// ---------------------------------------------------------------------------
__global__ __launch_bounds__(256) void op_mfma_kernel(
    const u16* __restrict__ fusedbf, const u16* __restrict__ opwbf,
    const float* __restrict__ opb, float* __restrict__ oproj) {
  __shared__ u16 sA[64][40];
  __shared__ u16 sB[64][40];
  __shared__ float sCf[64][68];
  const int m0 = blockIdx.x * 64;
  const int n0 = blockIdx.y * 64;
  const int t = threadIdx.x;
  const int lane = t & 63, w = t >> 6;
  const int wm = w >> 1, wn = w & 1;
  const int srow = t >> 2, skoff = (t & 3) * 8;
  const int fr = lane & 15, fk = (lane >> 4) * 8;
  f32x4 acc[2][2];
#pragma unroll
  for (int m = 0; m < 2; m++)
#pragma unroll
    for (int n = 0; n < 2; n++)
#pragma unroll
      for (int r = 0; r < 4; r++) acc[m][n][r] = 0.f;
  const u16* ap = fusedbf + (size_t)(m0 + srow) * Cz + skoff;
  const u16* bp = opwbf + (size_t)(n0 + srow) * Cz + skoff;
  for (int k0 = 0; k0 < Cz; k0 += 32) {
    u16x8 av = *(const u16x8*)(ap + k0);
    u16x8 bv = *(const u16x8*)(bp + k0);
    __syncthreads();
    *(u16x8*)&sA[srow][skoff] = av;
    *(u16x8*)&sB[srow][skoff] = bv;
    __syncthreads();
    bf16x8 a0 = *(const bf16x8*)&sA[wm * 32 + fr][fk];
    bf16x8 a1 = *(const bf16x8*)&sA[wm * 32 + 16 + fr][fk];
    bf16x8 b0 = *(const bf16x8*)&sB[wn * 32 + fr][fk];
    bf16x8 b1 = *(const bf16x8*)&sB[wn * 32 + 16 + fr][fk];
    acc[0][0] = mfma16(a0, b0, acc[0][0]);
    acc[0][1] = mfma16(a0, b1, acc[0][1]);
    acc[1][0] = mfma16(a1, b0, acc[1][0]);
    acc[1][1] = mfma16(a1, b1, acc[1][1]);
  }
#pragma unroll
  for (int nf = 0; nf < 2; nf++) {
    const int col = wn * 32 + nf * 16 + (lane & 15);
    const float ob = opb[n0 + col];
#pragma unroll
    for (int mf = 0; mf < 2; mf++)
#pragma unroll
      for (int r = 0; r < 4; r++) {
        const int row = wm * 32 + mf * 16 + ((lane >> 4) << 2) + r;
        sCf[row][col] = acc[mf][nf][r] + ob;
      }
  }
  __syncthreads();
  const int row = t >> 2, c0 = (t & 3) * 16;
  float4* d = (float4*)(oproj + ((size_t)(m0 + row)) * Cz + n0 + c0);
  const float4* s = (const float4*)&sCf[row][c0];
  d[0] = s[0]; d[1] = s[1]; d[2] = s[2]; d[3] = s[3];
}

// ---------------------------------------------------------------------------
// H: out = LN2( LN1(oproj)*g1+b1 + x )  (rowwise double LN, fp32)
// grid MT/4, 256 thr; one wave per row
// ---------------------------------------------------------------------------
__global__ __launch_bounds__(256) void final_ln_kernel(
    const float* __restrict__ oproj, const float* __restrict__ g1,
    const float* __restrict__ b1, const float* __restrict__ x,
    const float* __restrict__ g2, const float* __restrict__ b2,
    float* __restrict__ out) {
  const int t = threadIdx.x;
  const int row = blockIdx.x * 4 + (t >> 6);
  const int lane = t & 63;
  const float* pr = oproj + (size_t)row * Cz;
  float4 a = ((const float4*)pr)[lane];
  float4 c = ((const float4*)pr)[lane + 64];
  float s1 = a.x + a.y + a.z + a.w + c.x + c.y + c.z + c.w;
  float s2 = a.x * a.x + a.y * a.y + a.z * a.z + a.w * a.w + c.x * c.x +
             c.y * c.y + c.z * c.z + c.w * c.w;
  for (int off = 1; off < 64; off <<= 1) {
    s1 += __shfl_xor(s1, off, 64);
    s2 += __shfl_xor(s2, off, 64);
  }
  const float m1 = s1 * (1.f / Cz);
  const float iv1 = rsqrtf(s2 * (1.f / Cz) - m1 * m1 + EPSz);
  float4 g1a = ((const float4*)g1)[lane], g1b = ((const float4*)g1)[lane + 64];
  float4 b1a = ((const float4*)b1)[lane], b1b = ((const float4*)b1)[lane + 64];
  const float* xr = x + (size_t)row * Cz;
  float4 xa = ((const float4*)xr)[lane], xb = ((const float4*)xr)[lane + 64];
  float4 ta, tb;
  ta.x = (a.x - m1) * iv1 * g1a.x + b1a.x + xa.x;
  ta.y = (a.y - m1) * iv1 * g1a.y + b1a.y + xa.y;
  ta.z = (a.z - m1) * iv1 * g1a.z + b1a.z + xa.z;
  ta.w = (a.w - m1) * iv1 * g1a.w + b1a.w + xa.w;
  tb.x = (c.x - m1) * iv1 * g1b.x + b1b.x + xb.x;
  tb.y = (c.y - m1) * iv1 * g1b.y + b1b.y + xb.y;
  tb.z = (c.z - m1) * iv1 * g1b.z + b1b.z + xb.z;
  tb.w = (c.w - m1) * iv1 * g1b.w + b1b.w + xb.w;
  s1 = ta.x + ta.y + ta.z + ta.w + tb.x + tb.y + tb.z + tb.w;
  s2 = ta.x * ta.x + ta.y * ta.y + ta.z * ta.z + ta.w * ta.w + tb.x * tb.x +
       tb.y * tb.y + tb.z * tb.z + tb.w * tb.w;
  for (int off = 1; off < 64; off <<= 1) {
    s1 += __shfl_xor(s1, off, 64);
    s2 += __shfl_xor(s2, off, 64);
  }
  const float m2 = s1 * (1.f / Cz);
  const float iv2 = rsqrtf(s2 * (1.f / Cz) - m2 * m2 + EPSz);
  float4 g2a = ((const float4*)g2)[lane], g2b = ((const float4*)g2)[lane + 64];
  float4 b2a = ((const float4*)b2)[lane], b2b = ((const float4*)b2)[lane + 64];
  float4 oa, ob;
  oa.x = (ta.x - m2) * iv2 * g2a.x + b2a.x;
  oa.y = (ta.y - m2) * iv2 * g2a.y + b2a.y;
  oa.z = (ta.z - m2) * iv2 * g2a.z + b2a.z;
  oa.w = (ta.w - m2) * iv2 * g2a.w + b2a.w;
  ob.x = (tb.x - m2) * iv2 * g2b.x + b2b.x;
  ob.y = (tb.y - m2) * iv2 * g2b.y + b2b.y;
  ob.z = (tb.z - m2) * iv2 * g2b.z + b2b.z;
  ob.w = (tb.w - m2) * iv2 * g2b.w + b2b.w;
  float* orow = out + (size_t)row * Cz;
  ((float4*)orow)[lane] = oa;
  ((float4*)orow)[lane + 64] = ob;
}

// ---------------------------------------------------------------------------
extern "C" void kernel_launch(void* const* d_in, const int* in_sizes, int n_in,
                              void* d_out, int out_size, void* d_ws,
                              size_t ws_size, hipStream_t stream) {
  const float* x = (const float*)d_in[0];
  const float* pw_w = (const float*)d_in[1];
  const float* pw_b = (const float*)d_in[2];
  const float* pw_bn_g = (const float*)d_in[3];
  const float* pw_bn_b = (const float*)d_in[4];
  const float* pw_bn_m = (const float*)d_in[5];
  const float* pw_bn_v = (const float*)d_in[6];
  const float* dw_w0 = (const float*)d_in[7];
  const float* dw_w1 = (const float*)d_in[8];
  const float* dw_w2 = (const float*)d_in[9];
  const float* dw_w3 = (const float*)d_in[10];
  const float* dw_b = (const float*)d_in[11];
  const float* dw_bn_g = (const float*)d_in[12];
  const float* dw_bn_b = (const float*)d_in[13];
  const float* dw_bn_m = (const float*)d_in[14];
  const float* dw_bn_v = (const float*)d_in[15];
  const float* se_w1 = (const float*)d_in[16];
  const float* se_b1 = (const float*)d_in[17];
  const float* se_w2 = (const float*)d_in[18];
  const float* se_b2 = (const float*)d_in[19];
  const float* se_ln_g = (const float*)d_in[20];
  const float* se_ln_b = (const float*)d_in[21];
  // d_in[22] = df_ln_g (unused: LN of channel-constant rows -> bias only)
  const float* df_ln_b = (const float*)d_in[23];
  const float* wq = (const float*)d_in[24];
  const float* bq = (const float*)d_in[25];
  const float* wv = (const float*)d_in[26];
  const float* bv = (const float*)d_in[27];
  const float* wg = (const float*)d_in[28];
  const float* bg = (const float*)d_in[29];
  const float* op_w = (const float*)d_in[30];
  const float* op_b = (const float*)d_in[31];
  const float* op_ln_g = (const float*)d_in[32];
  const float* op_ln_b = (const float*)d_in[33];
  const float* fn_g = (const float*)d_in[34];
  const float* fn_b = (const float*)d_in[35];
  float* out = (float*)d_out;

  const size_t NBL = (size_t)Bz * Cz * Lz;  // 8388608 elems
  char* p = (char*)d_ws;
  u16* xbf = (u16*)p; p += NBL * 2;          // 16MB; reused as `fused` later
  u16* xpw = (u16*)p; p += NBL * 2;          // 16MB
  u16* ybuf = (u16*)p; p += 4 * NBL * 2;     // 64MB; reused as oproj (32MB)
  u16* ebuf = (u16*)p; p += 4 * NBL * 2;     // 64MB
  u16* pwwbf = (u16*)p; p += (size_t)Cz * Cz * 2;    // 512KB
  u16* wvbf = (u16*)p; p += (size_t)DHz * Cz * 2;    // 256KB
  u16* opwbf = (u16*)p; p += (size_t)Cz * Cz * 2;    // 512KB
  float* fbuf = (float*)p;
  float* ysum = fbuf;                  // 16384
  float* scv = fbuf + 16384;           // 16384
  float* scores = fbuf + 32768;        // 65536
  float* pwA = fbuf + 98304;           // 512
  float* pwB = pwA + 512;              // 512
  float* dwA = pwB + 512;              // 2048
  float* dwB = dwA + 2048;             // 2048
  float* qc = dwB + 2048;              // 256
  u16* fusedbf = xbf;                  // alias (xbf dead after pw_mfma)
  float* oproj = (float*)ybuf;         // alias (y dead after ln loop)

  cvt_bf16_kernel<<<(int)(NBL / 8 / 256), 256, 0, stream>>>(x, xbf,
                                                            (int)(NBL / 8));
  cvt_bf16_kernel<<<Cz * Cz / 8 / 256, 256, 0, stream>>>(pw_w, pwwbf,
                                                         Cz * Cz / 8);
  cvt_bf16_kernel<<<DHz * Cz / 8 / 256, 256, 0, stream>>>(wv, wvbf,
                                                          DHz * Cz / 8);
  cvt_bf16_kernel<<<Cz * Cz / 8 / 256, 256, 0, stream>>>(op_w, opwbf,
                                                         Cz * Cz / 8);

  prep_kernel<<<6, 256, 0, stream>>>(pw_b, pw_bn_g, pw_bn_b, pw_bn_m, pw_bn_v,
                                     dw_b, dw_bn_g, dw_bn_b, dw_bn_m, dw_bn_v,
                                     df_ln_b, wq, bq, pwA, pwB, dwA, dwB, qc);

  pw_mfma_kernel<<<dim3(Lz / 64, Cz / 64, Bz), 256, 0, stream>>>(
      pwwbf, xbf, pwA, pwB, xpw);

  dw_conv_kernel<<<4 * Bz * Cz, 256, 0, stream>>>(xpw, dw_w0, dw_w1, dw_w2,
                                                  dw_w3, dwA, dwB, ybuf, ysum);

  se_kernel<<<32, 128, 0, stream>>>(ysum, se_w1, se_b1, se_w2, se_b2, scv);

  for (int i = 0; i < 4; i++) {
    ln_transpose_kernel<<<dim3(Lz / 16, Bz), 256, 0, stream>>>(
        ybuf + (size_t)i * NBL, scv + (size_t)i * Bz * Cz, se_ln_g + i * Cz,
        se_ln_b + i * Cz, ebuf + (size_t)i * NBL);
  }

  score_mfma_kernel<<<dim3(MT / 64, 4), 256, 0, stream>>>(
      ebuf, ebuf + NBL, ebuf + 2 * NBL, ebuf + 3 * NBL, wvbf, bv, qc, wg, bg,
      scores);

  fuse_kernel<<<MT / 4, 256, 0, stream>>>(ebuf, ebuf + NBL, ebuf + 2 * NBL,
                                          ebuf + 3 * NBL, scores, fusedbf);

  op_mfma_kernel<<<dim3(MT / 64, Cz / 64), 256, 0, stream>>>(fusedbf, opwbf,
                                                             op_b, oproj);

  final_ln_kernel<<<MT / 4, 256, 0, stream>>>(oproj, op_ln_g, op_ln_b, x, fn_g,
                                              fn_b, out);
}

// Round 5
// 315.024 us; speedup vs baseline: 2.3591x; 1.0541x over previous
//
#include <hip/hip_runtime.h>
#include <math.h>

static constexpr int Bz = 8;
static constexpr int Lz = 2048;
static constexpr int Cz = 512;
static constexpr int CRz = 128;
static constexpr int DHz = 256;
static constexpr int MT = Bz * Lz;           // 16384 rows
static constexpr float EPSz = 1e-5f;

typedef unsigned short u16;
typedef __bf16 bf16x8 __attribute__((ext_vector_type(8)));
typedef float f32x4 __attribute__((ext_vector_type(4)));
typedef unsigned short u16x8 __attribute__((ext_vector_type(8)));

__device__ __forceinline__ float bf2f(u16 u) {
  unsigned int v = ((unsigned int)u) << 16;
  return __builtin_bit_cast(float, v);
}
__device__ __forceinline__ u16 f2bf(float f) {
  unsigned int b = __builtin_bit_cast(unsigned int, f);
  b += 0x7FFFu + ((b >> 16) & 1u);
  return (u16)(b >> 16);
}
__device__ __forceinline__ f32x4 mfma16(bf16x8 a, bf16x8 b, f32x4 c) {
  return __builtin_amdgcn_mfma_f32_16x16x32_bf16(a, b, c, 0, 0, 0);
}

// ---------------------------------------------------------------------------
// cvt: fp32 -> bf16 (8 elems/thread)
// ---------------------------------------------------------------------------
__global__ __launch_bounds__(256) void cvt_bf16_kernel(
    const float* __restrict__ src, u16* __restrict__ dst, int n8) {
  int i = blockIdx.x * 256 + threadIdx.x;
  if (i >= n8) return;
  const float4* s = (const float4*)src;
  float4 a = s[i * 2], b = s[i * 2 + 1];
  u16x8 o;
  o[0] = f2bf(a.x); o[1] = f2bf(a.y); o[2] = f2bf(a.z); o[3] = f2bf(a.w);
  o[4] = f2bf(b.x); o[5] = f2bf(b.y); o[6] = f2bf(b.z); o[7] = f2bf(b.w);
  ((u16x8*)dst)[i] = o;
}

// ---------------------------------------------------------------------------
// P: fold BN params; compute Q const vector (diff-path LN collapses to bias)
// ---------------------------------------------------------------------------
__global__ __launch_bounds__(256) void prep_kernel(
    const float* __restrict__ pw_b, const float* __restrict__ pw_g,
    const float* __restrict__ pw_bb, const float* __restrict__ pw_m,
    const float* __restrict__ pw_v,
    const float* __restrict__ dw_b, const float* __restrict__ dw_g,
    const float* __restrict__ dw_bb, const float* __restrict__ dw_m,
    const float* __restrict__ dw_v,
    const float* __restrict__ df_ln_b, const float* __restrict__ wq,
    const float* __restrict__ bq,
    float* __restrict__ pwA, float* __restrict__ pwB,
    float* __restrict__ dwA, float* __restrict__ dwB,
    float* __restrict__ qc) {
  const int blk = blockIdx.x;
  const int t = threadIdx.x;
  if (blk == 0) {
    for (int c = t; c < Cz; c += 256) {
      float inv = rsqrtf(pw_v[c] + EPSz);
      float a = pw_g[c] * inv;
      float bb = pw_bb[c] - pw_m[c] * a;
      pwA[c] = a;
      pwB[c] = pw_b[c] * a + bb;
    }
  } else if (blk <= 4) {
    const int i = blk - 1;
    for (int c = t; c < Cz; c += 256) {
      int idx = i * Cz + c;
      float inv = rsqrtf(dw_v[idx] + EPSz);
      float a = dw_g[idx] * inv;
      float bb = dw_bb[idx] - dw_m[idx] * a;
      dwA[idx] = a;
      dwB[idx] = dw_b[idx] * a + bb;
    }
  } else {
    if (t < DHz) {
      float s = bq[t];
      const float* w = wq + (size_t)t * Cz;
      for (int c = 0; c < Cz; c++) s += df_ln_b[c] * w[c];
      qc[t] = s;
    }
  }
}

// ---------------------------------------------------------------------------
// A: pointwise conv via MFMA (unchanged structure)
// ---------------------------------------------------------------------------
__global__ __launch_bounds__(256) void pw_mfma_kernel(
    const u16* __restrict__ Wbf, const u16* __restrict__ xbf,
    const float* __restrict__ alpha, const float* __restrict__ beta,
    u16* __restrict__ xpw) {
  __shared__ u16 sA[64][40];
  __shared__ u16 sB[64][40];
  __shared__ u16 sC[64][64];
  const int n0 = blockIdx.x * 64;   // l
  const int m0 = blockIdx.y * 64;   // o
  const int bat = blockIdx.z;
  const int t = threadIdx.x;
  const int lane = t & 63, w = t >> 6;
  const int wm = w >> 1, wn = w & 1;
  const int srow = t >> 2, skoff = (t & 3) * 8;
  f32x4 acc[2][2];
#pragma unroll
  for (int m = 0; m < 2; m++)
#pragma unroll
    for (int n = 0; n < 2; n++)
#pragma unroll
      for (int r = 0; r < 4; r++) acc[m][n][r] = 0.f;
  const u16* ap = Wbf + (size_t)(m0 + srow) * Cz + skoff;
  const u16* bp = xbf + ((size_t)bat * Lz + n0 + srow) * Cz + skoff;
  const int fr = lane & 15, fk = (lane >> 4) * 8;
  for (int k0 = 0; k0 < Cz; k0 += 32) {
    u16x8 av = *(const u16x8*)(ap + k0);
    u16x8 bv = *(const u16x8*)(bp + k0);
    __syncthreads();
    *(u16x8*)&sA[srow][skoff] = av;
    *(u16x8*)&sB[srow][skoff] = bv;
    __syncthreads();
    bf16x8 a0 = *(const bf16x8*)&sA[wm * 32 + fr][fk];
    bf16x8 a1 = *(const bf16x8*)&sA[wm * 32 + 16 + fr][fk];
    bf16x8 b0 = *(const bf16x8*)&sB[wn * 32 + fr][fk];
    bf16x8 b1 = *(const bf16x8*)&sB[wn * 32 + 16 + fr][fk];
    acc[0][0] = mfma16(a0, b0, acc[0][0]);
    acc[0][1] = mfma16(a0, b1, acc[0][1]);
    acc[1][0] = mfma16(a1, b0, acc[1][0]);
    acc[1][1] = mfma16(a1, b1, acc[1][1]);
  }
#pragma unroll
  for (int mf = 0; mf < 2; mf++) {
#pragma unroll
    for (int r = 0; r < 4; r++) {
      const int row = wm * 32 + mf * 16 + ((lane >> 4) << 2) + r;
      const float al = alpha[m0 + row], be = beta[m0 + row];
#pragma unroll
      for (int nf = 0; nf < 2; nf++) {
        const int col = wn * 32 + nf * 16 + (lane & 15);
        float v = fmaxf(acc[mf][nf][r] * al + be, 0.f);
        sC[row][col] = f2bf(v);
      }
    }
  }
  __syncthreads();
  const int row = t >> 2, c0 = (t & 3) * 16;
  u16x8 v0 = *(const u16x8*)&sC[row][c0];
  u16x8 v1 = *(const u16x8*)&sC[row][c0 + 8];
  u16* dst = xpw + ((size_t)(bat * Cz + m0 + row)) * Lz + n0 + c0;
  *(u16x8*)dst = v0;
  *(u16x8*)(dst + 8) = v1;
}

// ---------------------------------------------------------------------------
// B: depthwise conv, register sliding window: thread owns 8 contiguous outputs
// ---------------------------------------------------------------------------
template <int K>
__device__ __forceinline__ void dw_body(const float* __restrict__ row,
                                        const float* __restrict__ w,
                                        float a, float bb, int valid, int t,
                                        u16* __restrict__ dst, float& psum) {
  constexpr int P = (K - 1) / 2;
  constexpr int W = 8 + K - 1;
  float wreg[K];
#pragma unroll
  for (int j = 0; j < K; j++) wreg[j] = w[j];
  const int base = t * 8 - P;
  float win[W];
  if (base >= 0 && base + W <= Lz) {
#pragma unroll
    for (int j = 0; j < W; j++) win[j] = row[base + j];
  } else {
#pragma unroll
    for (int j = 0; j < W; j++) {
      int xi = base + j;
      win[j] = (xi >= 0 && xi < Lz) ? row[xi] : 0.f;
    }
  }
  float acc[8] = {};
#pragma unroll
  for (int jj = 0; jj < K; jj++)
#pragma unroll
    for (int o = 0; o < 8; o++) acc[o] = fmaf(wreg[jj], win[jj + o], acc[o]);
  u16x8 ov;
#pragma unroll
  for (int o = 0; o < 8; o++) {
    float v = fmaxf(acc[o] * a + bb, 0.f);
    if (t * 8 + o >= valid) v = 0.f;
    ov[o] = f2bf(v);
    psum += v;
  }
  *(u16x8*)(dst + t * 8) = ov;
}

__global__ __launch_bounds__(256) void dw_conv_kernel(
    const u16* __restrict__ xpw,
    const float* __restrict__ w0, const float* __restrict__ w1,
    const float* __restrict__ w2, const float* __restrict__ w3,
    const float* __restrict__ dwA, const float* __restrict__ dwB,
    u16* __restrict__ y, float* __restrict__ ysum) {
  __shared__ float row[Lz];
  __shared__ float wsum[4];
  const int bx = blockIdx.x;
  const int i = bx >> 12;
  const int rem = bx & 4095;
  const int b = rem >> 9;
  const int c = rem & 511;
  const int t = threadIdx.x;
  const u16* src = xpw + ((size_t)(b * Cz + c)) * Lz;
  {
    u16x8 v = ((const u16x8*)src)[t];
#pragma unroll
    for (int j = 0; j < 8; j++) row[t * 8 + j] = bf2f(v[j]);
  }
  __syncthreads();
  const float a = dwA[i * Cz + c], bb = dwB[i * Cz + c];
  u16* dst = y + ((size_t)((i * Bz + b) * Cz + c)) * Lz;
  float psum = 0.f;
  if (i == 0) {
    dw_body<3>(row, w0 + c * 3, a, bb, Lz, t, dst, psum);
  } else if (i == 1) {
    dw_body<7>(row, w1 + c * 7, a, bb, Lz, t, dst, psum);
  } else if (i == 2) {
    dw_body<15>(row, w2 + c * 15, a, bb, Lz, t, dst, psum);
  } else {
    dw_body<20>(row, w3 + c * 20, a, bb, Lz - 1, t, dst, psum);
  }
  for (int off = 32; off > 0; off >>= 1) psum += __shfl_down(psum, off, 64);
  if ((t & 63) == 0) wsum[t >> 6] = psum;
  __syncthreads();
  if (t == 0) ysum[(i * Bz + b) * Cz + c] = wsum[0] + wsum[1] + wsum[2] + wsum[3];
}

// ---------------------------------------------------------------------------
// C: squeeze-excite (unchanged)
// ---------------------------------------------------------------------------
__global__ __launch_bounds__(128) void se_kernel(
    const float* __restrict__ ysum,
    const float* __restrict__ se_w1, const float* __restrict__ se_b1,
    const float* __restrict__ se_w2, const float* __restrict__ se_b2,
    float* __restrict__ sc) {
  const int i = blockIdx.x >> 3;
  const int b = blockIdx.x & 7;
  __shared__ float ym[Cz];
  __shared__ float h[CRz];
  const int t = threadIdx.x;
  const float* ys = ysum + (i * Bz + b) * Cz;
  for (int cc = t; cc < Cz; cc += 128) ym[cc] = ys[cc] * (1.f / Lz);
  __syncthreads();
  {
    const float* w1 = se_w1 + (size_t)i * CRz * Cz + (size_t)t * Cz;
    float s = se_b1[i * CRz + t];
    for (int cc = 0; cc < Cz; cc++) s += ym[cc] * w1[cc];
    h[t] = fmaxf(s, 0.f);
  }
  __syncthreads();
  for (int cc = t; cc < Cz; cc += 128) {
    const float* w2 = se_w2 + ((size_t)i * Cz + cc) * CRz;
    float s = se_b2[i * Cz + cc];
    for (int r = 0; r < CRz; r++) s += h[r] * w2[r];
    float wt = 1.f / (1.f + expf(-s));
    sc[(i * Bz + b) * Cz + cc] = 1.f + wt;
  }
}

// ---------------------------------------------------------------------------
// D: enhanced = LN_c( y[b,c,l]*sc[b,c] ), 32-l tiles, one launch for all
// grid (L/32, 4*B), 256 thr
// ---------------------------------------------------------------------------
__global__ __launch_bounds__(256) void ln_transpose_kernel(
    const u16* __restrict__ ybuf, const float* __restrict__ scv,
    const float* __restrict__ se_ln_g, const float* __restrict__ se_ln_b,
    u16* __restrict__ ebuf) {
  __shared__ float tile[32][Cz + 1];
  const size_t NBL = (size_t)Bz * Cz * Lz;
  const int i = blockIdx.y >> 3;
  const int b = blockIdx.y & 7;
  const int l0 = blockIdx.x * 32;
  const int t = threadIdx.x;
  const u16* yb = ybuf + (size_t)i * NBL + (size_t)b * Cz * Lz;
  const float* scb = scv + (i * Bz + b) * Cz;
  const float* g = se_ln_g + i * Cz;
  const float* bb = se_ln_b + i * Cz;
#pragma unroll
  for (int rep = 0; rep < 8; rep++) {
    const int idx = rep * 256 + t;
    const int c = idx >> 2;
    const int l8 = (idx & 3) * 8;
    u16x8 v = *(const u16x8*)(yb + (size_t)c * Lz + l0 + l8);
    const float scale = scb[c];
#pragma unroll
    for (int j = 0; j < 8; j++) tile[l8 + j][c] = bf2f(v[j]) * scale;
  }
  __syncthreads();
  const int wave = t >> 6, lane = t & 63;
  u16* eb = ebuf + (size_t)i * NBL + ((size_t)b * Lz + l0) * Cz;
  for (int r = wave; r < 32; r += 4) {
    float vals[8];
    float s1 = 0.f, s2 = 0.f;
#pragma unroll
    for (int j = 0; j < 8; j++) {
      float v = tile[r][lane + j * 64];
      vals[j] = v; s1 += v; s2 += v * v;
    }
    for (int off = 32; off > 0; off >>= 1) {
      s1 += __shfl_xor(s1, off, 64);
      s2 += __shfl_xor(s2, off, 64);
    }
    const float m = s1 * (1.f / Cz);
    const float var = s2 * (1.f / Cz) - m * m;
    const float inv = rsqrtf(var + EPSz);
#pragma unroll
    for (int j = 0; j < 8; j++) {
      const int cc = lane + j * 64;
      eb[(size_t)r * Cz + cc] = f2bf((vals[j] - m) * inv * g[cc] + bb[cc]);
    }
  }
}

// ---------------------------------------------------------------------------
// E: score via MFMA, k0-outer: stage A(64x32) + full B(256x32) per k-step.
// Wave w owns dh cols [w*64, w*64+64), all 64 rows. grid (MT/64, 4), 256 thr.
// ---------------------------------------------------------------------------
__global__ __launch_bounds__(256) void score_mfma_kernel(
    const u16* __restrict__ e0, const u16* __restrict__ e1,
    const u16* __restrict__ e2, const u16* __restrict__ e3,
    const u16* __restrict__ wvbf, const float* __restrict__ bv,
    const float* __restrict__ qc, const float* __restrict__ wg,
    const float* __restrict__ bg, float* __restrict__ scores) {
  __shared__ u16 sA[64][40];
  __shared__ u16 sB[256][40];
  __shared__ float sP[4][64];
  const int i = blockIdx.y;
  const u16* E = (i == 0) ? e0 : (i == 1) ? e1 : (i == 2) ? e2 : e3;
  const int r0 = blockIdx.x * 64;
  const int t = threadIdx.x;
  const int lane = t & 63, w = t >> 6;
  const int srow = t >> 2, skoff = (t & 3) * 8;
  const int fr = lane & 15, fk = (lane >> 4) * 8;
  const u16* ap = E + (size_t)(r0 + srow) * Cz + skoff;
  const u16* bp = wvbf + (size_t)srow * Cz + skoff;
  f32x4 acc[4][4];
#pragma unroll
  for (int m = 0; m < 4; m++)
#pragma unroll
    for (int j = 0; j < 4; j++)
#pragma unroll
      for (int r = 0; r < 4; r++) acc[m][j][r] = 0.f;
  for (int k0 = 0; k0 < Cz; k0 += 32) {
    u16x8 av = *(const u16x8*)(ap + k0);
    u16x8 bq0 = *(const u16x8*)(bp + k0);
    u16x8 bq1 = *(const u16x8*)(bp + (size_t)64 * Cz + k0);
    u16x8 bq2 = *(const u16x8*)(bp + (size_t)128 * Cz + k0);
    u16x8 bq3 = *(const u16x8*)(bp + (size_t)192 * Cz + k0);
    __syncthreads();
    *(u16x8*)&sA[srow][skoff] = av;
    *(u16x8*)&sB[srow][skoff] = bq0;
    *(u16x8*)&sB[srow + 64][skoff] = bq1;
    *(u16x8*)&sB[srow + 128][skoff] = bq2;
    *(u16x8*)&sB[srow + 192][skoff] = bq3;
    __syncthreads();
    bf16x8 am[4], bj[4];
#pragma unroll
    for (int m = 0; m < 4; m++) am[m] = *(const bf16x8*)&sA[m * 16 + fr][fk];
#pragma unroll
    for (int j = 0; j < 4; j++)
      bj[j] = *(const bf16x8*)&sB[(w * 4 + j) * 16 + fr][fk];
#pragma unroll
    for (int m = 0; m < 4; m++)
#pragma unroll
      for (int j = 0; j < 4; j++)
        acc[m][j] = mfma16(am[m], bj[j], acc[m][j]);
  }
  float part[4][4];
#pragma unroll
  for (int m = 0; m < 4; m++)
#pragma unroll
    for (int r = 0; r < 4; r++) part[m][r] = 0.f;
#pragma unroll
  for (int j = 0; j < 4; j++) {
    const int dh = (w * 4 + j) * 16 + fr;
    const float bvn = bv[dh], qcn = qc[dh], wgn = wg[dh];
#pragma unroll
    for (int m = 0; m < 4; m++)
#pragma unroll
      for (int r = 0; r < 4; r++)
        part[m][r] += tanhf(qcn * (acc[m][j][r] + bvn)) * wgn;
  }
#pragma unroll
  for (int off = 1; off < 16; off <<= 1) {
#pragma unroll
    for (int m = 0; m < 4; m++)
#pragma unroll
      for (int r = 0; r < 4; r++)
        part[m][r] += __shfl_xor(part[m][r], off, 64);
  }
  if (fr == 0) {
#pragma unroll
    for (int m = 0; m < 4; m++)
#pragma unroll
      for (int r = 0; r < 4; r++)
        sP[w][m * 16 + ((lane >> 4) << 2) + r] = part[m][r];
  }
  __syncthreads();
  if (t < 64) {
    float s = sP[0][t] + sP[1][t] + sP[2][t] + sP[3][t] + bg[0];
    scores[(size_t)i * MT + r0 + t] = s;
  }
}

// ---------------------------------------------------------------------------
// G: fused softmax-combine + op GEMM: oproj = (sum sw_i*e_i) @ op_w^T + op_b
// Combined A staged full-K in LDS once. grid (C/64 n-fast, MT/64), 256 thr.
// Output bf16.
// ---------------------------------------------------------------------------
__global__ __launch_bounds__(256) void op_mfma_kernel(
    const u16* __restrict__ e0, const u16* __restrict__ e1,
    const u16* __restrict__ e2, const u16* __restrict__ e3,
    const float* __restrict__ scores, const u16* __restrict__ opwbf,
    const float* __restrict__ opb, u16* __restrict__ oproj) {
  __shared__ u16 sA[64][520];   // full-K combined A, 66.6KB
  __shared__ u16 sB[64][40];
  __shared__ float sw4[4][64];
  const int n0 = blockIdx.x * 64;
  const int m0 = blockIdx.y * 64;
  const int t = threadIdx.x;
  const int lane = t & 63, w = t >> 6;
  const int wm = w >> 1, wn = w & 1;
  const int srow = t >> 2, skoff = (t & 3) * 8;
  const int fr = lane & 15, fk = (lane >> 4) * 8;
  if (t < 64) {
    const int r = m0 + t;
    float s0 = scores[r], s1 = scores[MT + r], s2 = scores[2 * MT + r],
          s3 = scores[3 * MT + r];
    float mx = fmaxf(fmaxf(s0, s1), fmaxf(s2, s3));
    float x0 = expf(s0 - mx), x1 = expf(s1 - mx), x2 = expf(s2 - mx),
          x3 = expf(s3 - mx);
    float inv = 1.f / (x0 + x1 + x2 + x3);
    sw4[0][t] = x0 * inv; sw4[1][t] = x1 * inv;
    sw4[2][t] = x2 * inv; sw4[3][t] = x3 * inv;
  }
  __syncthreads();
#pragma unroll
  for (int rep = 0; rep < 16; rep++) {
    const int idx = rep * 256 + t;
    const int row = idx >> 6;
    const int col = (idx & 63) * 8;
    const size_t off = (size_t)(m0 + row) * Cz + col;
    u16x8 v0 = *(const u16x8*)(e0 + off);
    u16x8 v1 = *(const u16x8*)(e1 + off);
    u16x8 v2 = *(const u16x8*)(e2 + off);
    u16x8 v3 = *(const u16x8*)(e3 + off);
    const float x0 = sw4[0][row], x1 = sw4[1][row], x2 = sw4[2][row],
                x3 = sw4[3][row];
    u16x8 o;
#pragma unroll
    for (int j = 0; j < 8; j++)
      o[j] = f2bf(x0 * bf2f(v0[j]) + x1 * bf2f(v1[j]) + x2 * bf2f(v2[j]) +
                  x3 * bf2f(v3[j]));
    *(u16x8*)&sA[row][col] = o;
  }
  f32x4 acc[2][2];
#pragma unroll
  for (int m = 0; m < 2; m++)
#pragma unroll
    for (int n = 0; n < 2; n++)
#pragma unroll
      for (int r = 0; r < 4; r++) acc[m][n][r] = 0.f;
  const u16* bp = opwbf + (size_t)(n0 + srow) * Cz + skoff;
  for (int k0 = 0; k0 < Cz; k0 += 32) {
    u16x8 bv8 = *(const u16x8*)(bp + k0);
    __syncthreads();
    *(u16x8*)&sB[srow][skoff] = bv8;
    __syncthreads();
    bf16x8 a0 = *(const bf16x8*)&sA[wm * 32 + fr][k0 + fk];
    bf16x8 a1 = *(const bf16x8*)&sA[wm * 32 + 16 + fr][k0 + fk];
    bf16x8 b0 = *(const bf16x8*)&sB[wn * 32 + fr][fk];
    bf16x8 b1 = *(const bf16x8*)&sB[wn * 32 + 16 + fr][fk];
    acc[0][0] = mfma16(a0, b0, acc[0][0]);
    acc[0][1] = mfma16(a0, b1, acc[0][1]);
    acc[1][0] = mfma16(a1, b0, acc[1][0]);
    acc[1][1] = mfma16(a1, b1, acc[1][1]);
  }
  __syncthreads();  // sA reads done; reuse as sC
  u16* sC = (u16*)&sA[0][0];  // [64][72]
#pragma unroll
  for (int nf = 0; nf < 2; nf++) {
    const int col = wn * 32 + nf * 16 + fr;
    const float ob = opb[n0 + col];
#pragma unroll
    for (int mf = 0; mf < 2; mf++)
#pragma unroll
      for (int r = 0; r < 4; r++) {
        const int row = wm * 32 + mf * 16 + ((lane >> 4) << 2) + r;
        sC[row * 72 + col] = f2bf(acc[mf][nf][r] + ob);
      }
  }
  __syncthreads();
  const int row = t >> 2, c0 = (t & 3) * 16;
  u16x8 v0 = *(const u16x8*)&sC[row * 72 + c0];
  u16x8 v1 = *(const u16x8*)&sC[row * 72 + c0 + 8];
  u16* dst = oproj + (size_t)(m0 + row) * Cz + n0 + c0;
  *(u16x8*)dst = v0;
  *(u16x8*)(dst + 8) = v1;
}

// ---------------------------------------------------------------------------
// H: out = LN2( LN1(oproj)*g1+b1 + x )  oproj bf16, out fp32
// grid MT/4, 256 thr; one wave per row, 8 contiguous cols per lane
// ---------------------------------------------------------------------------
__global__ __launch_bounds__(256) void final_ln_kernel(
    const u16* __restrict__ oproj, const float* __restrict__ g1,
    const float* __restrict__ b1, const float* __restrict__ x,
    const float* __restrict__ g2, const float* __restrict__ b2,
    float* __restrict__ out) {
  const int t = threadIdx.x;
  const int row = blockIdx.x * 4 + (t >> 6);
  const int lane = t & 63;
  u16x8 av = ((const u16x8*)(oproj + (size_t)row * Cz))[lane];
  float v[8];
  float s1 = 0.f, s2 = 0.f;
#pragma unroll
  for (int j = 0; j < 8; j++) {
    v[j] = bf2f(av[j]);
    s1 += v[j]; s2 += v[j] * v[j];
  }
  for (int off = 1; off < 64; off <<= 1) {
    s1 += __shfl_xor(s1, off, 64);
    s2 += __shfl_xor(s2, off, 64);
  }
  const float m1 = s1 * (1.f / Cz);
  const float iv1 = rsqrtf(s2 * (1.f / Cz) - m1 * m1 + EPSz);
  float4 g1a = ((const float4*)g1)[lane * 2], g1b = ((const float4*)g1)[lane * 2 + 1];
  float4 b1a = ((const float4*)b1)[lane * 2], b1b = ((const float4*)b1)[lane * 2 + 1];
  const float* xr = x + (size_t)row * Cz;
  float4 xa = ((const float4*)xr)[lane * 2], xb = ((const float4*)xr)[lane * 2 + 1];
  float gv[8] = {g1a.x, g1a.y, g1a.z, g1a.w, g1b.x, g1b.y, g1b.z, g1b.w};
  float bvv[8] = {b1a.x, b1a.y, b1a.z, b1a.w, b1b.x, b1b.y, b1b.z, b1b.w};
  float xv[8] = {xa.x, xa.y, xa.z, xa.w, xb.x, xb.y, xb.z, xb.w};
  float tv[8];
  s1 = 0.f; s2 = 0.f;
#pragma unroll
  for (int j = 0; j < 8; j++) {
    tv[j] = (v[j] - m1) * iv1 * gv[j] + bvv[j] + xv[j];
    s1 += tv[j]; s2 += tv[j] * tv[j];
  }
  for (int off = 1; off < 64; off <<= 1) {
    s1 += __shfl_xor(s1, off, 64);
    s2 += __shfl_xor(s2, off, 64);
  }
  const float m2 = s1 * (1.f / Cz);
  const float iv2 = rsqrtf(s2 * (1.f / Cz) - m2 * m2 + EPSz);
  float4 g2a = ((const float4*)g2)[lane * 2], g2b = ((const float4*)g2)[lane * 2 + 1];
  float4 b2a = ((const float4*)b2)[lane * 2], b2b = ((const float4*)b2)[lane * 2 + 1];
  float g2v[8] = {g2a.x, g2a.y, g2a.z, g2a.w, g2b.x, g2b.y, g2b.z, g2b.w};
  float b2v[8] = {b2a.x, b2a.y, b2a.z, b2a.w, b2b.x, b2b.y, b2b.z, b2b.w};
  float4 oa, ob;
  oa.x = (tv[0] - m2) * iv2 * g2v[0] + b2v[0];
  oa.y = (tv[1] - m2) * iv2 * g2v[1] + b2v[1];
  oa.z = (tv[2] - m2) * iv2 * g2v[2] + b2v[2];
  oa.w = (tv[3] - m2) * iv2 * g2v[3] + b2v[3];
  ob.x = (tv[4] - m2) * iv2 * g2v[4] + b2v[4];
  ob.y = (tv[5] - m2) * iv2 * g2v[5] + b2v[5];
  ob.z = (tv[6] - m2) * iv2 * g2v[6] + b2v[6];
  ob.w = (tv[7] - m2) * iv2 * g2v[7] + b2v[7];
  float* orow = out + (size_t)row * Cz;
  ((float4*)orow)[lane * 2] = oa;
  ((float4*)orow)[lane * 2 + 1] = ob;
}

// ---------------------------------------------------------------------------
extern "C" void kernel_launch(void* const* d_in, const int* in_sizes, int n_in,
                              void* d_out, int out_size, void* d_ws,
                              size_t ws_size, hipStream_t stream) {
  const float* x = (const float*)d_in[0];
  const float* pw_w = (const float*)d_in[1];
  const float* pw_b = (const float*)d_in[2];
  const float* pw_bn_g = (const float*)d_in[3];
  const float* pw_bn_b = (const float*)d_in[4];
  const float* pw_bn_m = (const float*)d_in[5];
  const float* pw_bn_v = (const float*)d_in[6];
  const float* dw_w0 = (const float*)d_in[7];
  const float* dw_w1 = (const float*)d_in[8];
  const float* dw_w2 = (const float*)d_in[9];
  const float* dw_w3 = (const float*)d_in[10];
  const float* dw_b = (const float*)d_in[11];
  const float* dw_bn_g = (const float*)d_in[12];
  const float* dw_bn_b = (const float*)d_in[13];
  const float* dw_bn_m = (const float*)d_in[14];
  const float* dw_bn_v = (const float*)d_in[15];
  const float* se_w1 = (const float*)d_in[16];
  const float* se_b1 = (const float*)d_in[17];
  const float* se_w2 = (const float*)d_in[18];
  const float* se_b2 = (const float*)d_in[19];
  const float* se_ln_g = (const float*)d_in[20];
  const float* se_ln_b = (const float*)d_in[21];
  // d_in[22] = df_ln_g (unused: LN of channel-constant rows -> bias only)
  const float* df_ln_b = (const float*)d_in[23];
  const float* wq = (const float*)d_in[24];
  const float* bq = (const float*)d_in[25];
  const float* wv = (const float*)d_in[26];
  const float* bv = (const float*)d_in[27];
  const float* wg = (const float*)d_in[28];
  const float* bg = (const float*)d_in[29];
  const float* op_w = (const float*)d_in[30];
  const float* op_b = (const float*)d_in[31];
  const float* op_ln_g = (const float*)d_in[32];
  const float* op_ln_b = (const float*)d_in[33];
  const float* fn_g = (const float*)d_in[34];
  const float* fn_b = (const float*)d_in[35];
  float* out = (float*)d_out;

  const size_t NBL = (size_t)Bz * Cz * Lz;  // 8388608 elems
  char* p = (char*)d_ws;
  u16* xbf = (u16*)p; p += NBL * 2;          // 16MB; reused as oproj later
  u16* xpw = (u16*)p; p += NBL * 2;          // 16MB
  u16* ybuf = (u16*)p; p += 4 * NBL * 2;     // 64MB
  u16* ebuf = (u16*)p; p += 4 * NBL * 2;     // 64MB
  u16* pwwbf = (u16*)p; p += (size_t)Cz * Cz * 2;    // 512KB
  u16* wvbf = (u16*)p; p += (size_t)DHz * Cz * 2;    // 256KB
  u16* opwbf = (u16*)p; p += (size_t)Cz * Cz * 2;    // 512KB
  float* fbuf = (float*)p;
  float* ysum = fbuf;                  // 16384
  float* scv = fbuf + 16384;           // 16384
  float* scores = fbuf + 32768;        // 65536
  float* pwA = fbuf + 98304;           // 512
  float* pwB = pwA + 512;              // 512
  float* dwA = pwB + 512;              // 2048
  float* dwB = dwA + 2048;             // 2048
  float* qc = dwB + 2048;              // 256
  u16* oproj = xbf;                    // alias (xbf dead after pw_mfma)

  cvt_bf16_kernel<<<(int)(NBL / 8 / 256), 256, 0, stream>>>(x, xbf,
                                                            (int)(NBL / 8));
  cvt_bf16_kernel<<<Cz * Cz / 8 / 256, 256, 0, stream>>>(pw_w, pwwbf,
                                                         Cz * Cz / 8);
  cvt_bf16_kernel<<<DHz * Cz / 8 / 256, 256, 0, stream>>>(wv, wvbf,
                                                          DHz * Cz / 8);
  cvt_bf16_kernel<<<Cz * Cz / 8 / 256, 256, 0, stream>>>(op_w, opwbf,
                                                         Cz * Cz / 8);

  prep_kernel<<<6, 256, 0, stream>>>(pw_b, pw_bn_g, pw_bn_b, pw_bn_m, pw_bn_v,
                                     dw_b, dw_bn_g, dw_bn_b, dw_bn_m, dw_bn_v,
                                     df_ln_b, wq, bq, pwA, pwB, dwA, dwB, qc);

  pw_mfma_kernel<<<dim3(Lz / 64, Cz / 64, Bz), 256, 0, stream>>>(
      pwwbf, xbf, pwA, pwB, xpw);

  dw_conv_kernel<<<4 * Bz * Cz, 256, 0, stream>>>(xpw, dw_w0, dw_w1, dw_w2,
                                                  dw_w3, dwA, dwB, ybuf, ysum);

  se_kernel<<<32, 128, 0, stream>>>(ysum, se_w1, se_b1, se_w2, se_b2, scv);

  ln_transpose_kernel<<<dim3(Lz / 32, 4 * Bz), 256, 0, stream>>>(
      ybuf, scv, se_ln_g, se_ln_b, ebuf);

  score_mfma_kernel<<<dim3(MT / 64, 4), 256, 0, stream>>>(
      ebuf, ebuf + NBL, ebuf + 2 * NBL, ebuf + 3 * NBL, wvbf, bv, qc, wg, bg,
      scores);

  op_mfma_kernel<<<dim3(Cz / 64, MT / 64), 256, 0, stream>>>(
      ebuf, ebuf + NBL, ebuf + 2 * NBL, ebuf + 3 * NBL, scores, opwbf, op_b,
      oproj);

  final_ln_kernel<<<MT / 4, 256, 0, stream>>>(oproj, op_ln_g, op_ln_b, x, fn_g,
                                              fn_b, out);
}

// Round 6
// 251.955 us; speedup vs baseline: 2.9497x; 1.2503x over previous
//
#include <hip/hip_runtime.h>
#include <math.h>

static constexpr int Bz = 8;
static constexpr int Lz = 2048;
static constexpr int Cz = 512;
static constexpr int CRz = 128;
static constexpr int DHz = 256;
static constexpr int MT = Bz * Lz;           // 16384 rows
static constexpr float EPSz = 1e-5f;

typedef unsigned short u16;
typedef __bf16 bf16x8 __attribute__((ext_vector_type(8)));
typedef float f32x4 __attribute__((ext_vector_type(4)));
typedef unsigned short u16x8 __attribute__((ext_vector_type(8)));

__device__ __forceinline__ float bf2f(u16 u) {
  unsigned int v = ((unsigned int)u) << 16;
  return __builtin_bit_cast(float, v);
}
__device__ __forceinline__ u16 f2bf(float f) {
  unsigned int b = __builtin_bit_cast(unsigned int, f);
  b += 0x7FFFu + ((b >> 16) & 1u);
  return (u16)(b >> 16);
}
__device__ __forceinline__ f32x4 mfma16(bf16x8 a, bf16x8 b, f32x4 c) {
  return __builtin_amdgcn_mfma_f32_16x16x32_bf16(a, b, c, 0, 0, 0);
}

// ---------------------------------------------------------------------------
// cvt: fp32 -> bf16 (8 elems/thread) — weights only now
// ---------------------------------------------------------------------------
__global__ __launch_bounds__(256) void cvt_bf16_kernel(
    const float* __restrict__ src, u16* __restrict__ dst, int n8) {
  int i = blockIdx.x * 256 + threadIdx.x;
  if (i >= n8) return;
  const float4* s = (const float4*)src;
  float4 a = s[i * 2], b = s[i * 2 + 1];
  u16x8 o;
  o[0] = f2bf(a.x); o[1] = f2bf(a.y); o[2] = f2bf(a.z); o[3] = f2bf(a.w);
  o[4] = f2bf(b.x); o[5] = f2bf(b.y); o[6] = f2bf(b.z); o[7] = f2bf(b.w);
  ((u16x8*)dst)[i] = o;
}

// ---------------------------------------------------------------------------
// P: fold BN params; compute Q const vector (diff-path LN collapses to bias)
// ---------------------------------------------------------------------------
__global__ __launch_bounds__(256) void prep_kernel(
    const float* __restrict__ pw_b, const float* __restrict__ pw_g,
    const float* __restrict__ pw_bb, const float* __restrict__ pw_m,
    const float* __restrict__ pw_v,
    const float* __restrict__ dw_b, const float* __restrict__ dw_g,
    const float* __restrict__ dw_bb, const float* __restrict__ dw_m,
    const float* __restrict__ dw_v,
    const float* __restrict__ df_ln_b, const float* __restrict__ wq,
    const float* __restrict__ bq,
    float* __restrict__ pwA, float* __restrict__ pwB,
    float* __restrict__ dwA, float* __restrict__ dwB,
    float* __restrict__ qc) {
  const int blk = blockIdx.x;
  const int t = threadIdx.x;
  if (blk == 0) {
    for (int c = t; c < Cz; c += 256) {
      float inv = rsqrtf(pw_v[c] + EPSz);
      float a = pw_g[c] * inv;
      float bb = pw_bb[c] - pw_m[c] * a;
      pwA[c] = a;
      pwB[c] = pw_b[c] * a + bb;
    }
  } else if (blk <= 4) {
    const int i = blk - 1;
    for (int c = t; c < Cz; c += 256) {
      int idx = i * Cz + c;
      float inv = rsqrtf(dw_v[idx] + EPSz);
      float a = dw_g[idx] * inv;
      float bb = dw_bb[idx] - dw_m[idx] * a;
      dwA[idx] = a;
      dwB[idx] = dw_b[idx] * a + bb;
    }
  } else {
    if (t < DHz) {
      float s = bq[t];
      const float* w = wq + (size_t)t * Cz;
      for (int c = 0; c < Cz; c++) s += df_ln_b[c] * w[c];
      qc[t] = s;
    }
  }
}

// ---------------------------------------------------------------------------
// A: pointwise conv, panel-resident: block owns 32 l-rows, stages x full-K
// once (fp32->bf16 during stage), loops k0 staging ALL 512 W rows per k-slice.
// grid 512 = (bat, l-tile), 256 thr, 4 waves: wave = (m-half, n-frag).
// ---------------------------------------------------------------------------
__global__ __launch_bounds__(256, 2) void pw_mfma_kernel(
    const u16* __restrict__ Wbf, const float* __restrict__ x,
    const float* __restrict__ alpha, const float* __restrict__ beta,
    u16* __restrict__ xpw) {
  __shared__ __align__(16) char lds[74240];
  u16(*sX)[520] = (u16(*)[520])lds;                  // [32][520] = 33,280 B
  u16(*sW)[40] = (u16(*)[40])(lds + 33280);          // [512][40] = 40,960 B
  u16* sC = (u16*)(lds + 33280);                     // [512][40] epilogue alias
  __shared__ float sAl[Cz];
  __shared__ float sBe[Cz];
  const int bat = blockIdx.x >> 6;
  const int l0 = (blockIdx.x & 63) * 32;
  const int t = threadIdx.x;
  const int lane = t & 63, w = t >> 6;
  const int fr = lane & 15, fk = (lane >> 4) * 8;
  const int mh = (w >> 1) * 16;   // m-frag half base (o dimension)
  const int nh = (w & 1) * 16;    // n-frag col base (l dimension)
  // stage x panel: 32 rows x 512 cols, cvt to bf16
#pragma unroll
  for (int rep = 0; rep < 8; rep++) {
    const int idx = rep * 256 + t;
    const int row = idx >> 6;
    const int col = (idx & 63) * 8;
    const float* src = x + ((size_t)bat * Lz + l0 + row) * Cz + col;
    float4 f0 = *(const float4*)src;
    float4 f1 = *(const float4*)(src + 4);
    u16x8 o;
    o[0] = f2bf(f0.x); o[1] = f2bf(f0.y); o[2] = f2bf(f0.z); o[3] = f2bf(f0.w);
    o[4] = f2bf(f1.x); o[5] = f2bf(f1.y); o[6] = f2bf(f1.z); o[7] = f2bf(f1.w);
    *(u16x8*)&sX[row][col] = o;
  }
  for (int c = t; c < Cz; c += 256) { sAl[c] = alpha[c]; sBe[c] = beta[c]; }
  f32x4 acc[16];
#pragma unroll
  for (int mf = 0; mf < 16; mf++)
#pragma unroll
    for (int r = 0; r < 4; r++) acc[mf][r] = 0.f;
  // W k-slice staging: thread handles rows t>>2 + rep*64, chunk (t&3)*8
  const int wrow = t >> 2, wch = (t & 3) * 8;
  const u16* wbase = Wbf + (size_t)wrow * Cz + wch;
  u16x8 breg[8];
#pragma unroll
  for (int rep = 0; rep < 8; rep++)
    breg[rep] = *(const u16x8*)(wbase + (size_t)rep * 64 * Cz);
  for (int k0 = 0; k0 < Cz; k0 += 32) {
    __syncthreads();
#pragma unroll
    for (int rep = 0; rep < 8; rep++)
      *(u16x8*)&sW[rep * 64 + wrow][wch] = breg[rep];
    __syncthreads();
    if (k0 + 32 < Cz) {
#pragma unroll
      for (int rep = 0; rep < 8; rep++)
        breg[rep] = *(const u16x8*)(wbase + (size_t)rep * 64 * Cz + k0 + 32);
    }
    bf16x8 bfrag = *(const bf16x8*)&sX[nh + fr][k0 + fk];
#pragma unroll
    for (int mf = 0; mf < 16; mf++) {
      bf16x8 a = *(const bf16x8*)&sW[(mh + mf) * 16 + fr][fk];
      acc[mf] = mfma16(a, bfrag, acc[mf]);
    }
  }
  __syncthreads();  // sW reads done; reuse as sC[512][40]
#pragma unroll
  for (int mf = 0; mf < 16; mf++) {
#pragma unroll
    for (int r = 0; r < 4; r++) {
      const int o = (mh + mf) * 16 + ((lane >> 4) << 2) + r;
      const int l = nh + fr;
      float v = fmaxf(acc[mf][r] * sAl[o] + sBe[o], 0.f);
      sC[o * 40 + l] = f2bf(v);
    }
  }
  __syncthreads();
#pragma unroll
  for (int rep = 0; rep < 8; rep++) {
    const int o = rep * 64 + (t >> 2);
    const int l8 = (t & 3) * 8;
    u16x8 v = *(const u16x8*)&sC[o * 40 + l8];
    *(u16x8*)(xpw + ((size_t)(bat * Cz + o)) * Lz + l0 + l8) = v;
  }
}

// ---------------------------------------------------------------------------
// B: depthwise conv, register sliding window (unchanged)
// ---------------------------------------------------------------------------
template <int K>
__device__ __forceinline__ void dw_body(const float* __restrict__ row,
                                        const float* __restrict__ w,
                                        float a, float bb, int valid, int t,
                                        u16* __restrict__ dst, float& psum) {
  constexpr int P = (K - 1) / 2;
  constexpr int W = 8 + K - 1;
  float wreg[K];
#pragma unroll
  for (int j = 0; j < K; j++) wreg[j] = w[j];
  const int base = t * 8 - P;
  float win[W];
  if (base >= 0 && base + W <= Lz) {
#pragma unroll
    for (int j = 0; j < W; j++) win[j] = row[base + j];
  } else {
#pragma unroll
    for (int j = 0; j < W; j++) {
      int xi = base + j;
      win[j] = (xi >= 0 && xi < Lz) ? row[xi] : 0.f;
    }
  }
  float acc[8] = {};
#pragma unroll
  for (int jj = 0; jj < K; jj++)
#pragma unroll
    for (int o = 0; o < 8; o++) acc[o] = fmaf(wreg[jj], win[jj + o], acc[o]);
  u16x8 ov;
#pragma unroll
  for (int o = 0; o < 8; o++) {
    float v = fmaxf(acc[o] * a + bb, 0.f);
    if (t * 8 + o >= valid) v = 0.f;
    ov[o] = f2bf(v);
    psum += v;
  }
  *(u16x8*)(dst + t * 8) = ov;
}

__global__ __launch_bounds__(256) void dw_conv_kernel(
    const u16* __restrict__ xpw,
    const float* __restrict__ w0, const float* __restrict__ w1,
    const float* __restrict__ w2, const float* __restrict__ w3,
    const float* __restrict__ dwA, const float* __restrict__ dwB,
    u16* __restrict__ y, float* __restrict__ ysum) {
  __shared__ float row[Lz];
  __shared__ float wsum[4];
  const int bx = blockIdx.x;
  const int i = bx >> 12;
  const int rem = bx & 4095;
  const int b = rem >> 9;
  const int c = rem & 511;
  const int t = threadIdx.x;
  const u16* src = xpw + ((size_t)(b * Cz + c)) * Lz;
  {
    u16x8 v = ((const u16x8*)src)[t];
#pragma unroll
    for (int j = 0; j < 8; j++) row[t * 8 + j] = bf2f(v[j]);
  }
  __syncthreads();
  const float a = dwA[i * Cz + c], bb = dwB[i * Cz + c];
  u16* dst = y + ((size_t)((i * Bz + b) * Cz + c)) * Lz;
  float psum = 0.f;
  if (i == 0) {
    dw_body<3>(row, w0 + c * 3, a, bb, Lz, t, dst, psum);
  } else if (i == 1) {
    dw_body<7>(row, w1 + c * 7, a, bb, Lz, t, dst, psum);
  } else if (i == 2) {
    dw_body<15>(row, w2 + c * 15, a, bb, Lz, t, dst, psum);
  } else {
    dw_body<20>(row, w3 + c * 20, a, bb, Lz - 1, t, dst, psum);
  }
  for (int off = 32; off > 0; off >>= 1) psum += __shfl_down(psum, off, 64);
  if ((t & 63) == 0) wsum[t >> 6] = psum;
  __syncthreads();
  if (t == 0) ysum[(i * Bz + b) * Cz + c] = wsum[0] + wsum[1] + wsum[2] + wsum[3];
}

// ---------------------------------------------------------------------------
// C: squeeze-excite (unchanged)
// ---------------------------------------------------------------------------
__global__ __launch_bounds__(128) void se_kernel(
    const float* __restrict__ ysum,
    const float* __restrict__ se_w1, const float* __restrict__ se_b1,
    const float* __restrict__ se_w2, const float* __restrict__ se_b2,
    float* __restrict__ sc) {
  const int i = blockIdx.x >> 3;
  const int b = blockIdx.x & 7;
  __shared__ float ym[Cz];
  __shared__ float h[CRz];
  const int t = threadIdx.x;
  const float* ys = ysum + (i * Bz + b) * Cz;
  for (int cc = t; cc < Cz; cc += 128) ym[cc] = ys[cc] * (1.f / Lz);
  __syncthreads();
  {
    const float* w1 = se_w1 + (size_t)i * CRz * Cz + (size_t)t * Cz;
    float s = se_b1[i * CRz + t];
    for (int cc = 0; cc < Cz; cc++) s += ym[cc] * w1[cc];
    h[t] = fmaxf(s, 0.f);
  }
  __syncthreads();
  for (int cc = t; cc < Cz; cc += 128) {
    const float* w2 = se_w2 + ((size_t)i * Cz + cc) * CRz;
    float s = se_b2[i * Cz + cc];
    for (int r = 0; r < CRz; r++) s += h[r] * w2[r];
    float wt = 1.f / (1.f + expf(-s));
    sc[(i * Bz + b) * Cz + cc] = 1.f + wt;
  }
}

// ---------------------------------------------------------------------------
// D: enhanced = LN_c( y[b,c,l]*sc[b,c] ), 32-l tiles (unchanged)
// ---------------------------------------------------------------------------
__global__ __launch_bounds__(256) void ln_transpose_kernel(
    const u16* __restrict__ ybuf, const float* __restrict__ scv,
    const float* __restrict__ se_ln_g, const float* __restrict__ se_ln_b,
    u16* __restrict__ ebuf) {
  __shared__ float tile[32][Cz + 1];
  const size_t NBL = (size_t)Bz * Cz * Lz;
  const int i = blockIdx.y >> 3;
  const int b = blockIdx.y & 7;
  const int l0 = blockIdx.x * 32;
  const int t = threadIdx.x;
  const u16* yb = ybuf + (size_t)i * NBL + (size_t)b * Cz * Lz;
  const float* scb = scv + (i * Bz + b) * Cz;
  const float* g = se_ln_g + i * Cz;
  const float* bb = se_ln_b + i * Cz;
#pragma unroll
  for (int rep = 0; rep < 8; rep++) {
    const int idx = rep * 256 + t;
    const int c = idx >> 2;
    const int l8 = (idx & 3) * 8;
    u16x8 v = *(const u16x8*)(yb + (size_t)c * Lz + l0 + l8);
    const float scale = scb[c];
#pragma unroll
    for (int j = 0; j < 8; j++) tile[l8 + j][c] = bf2f(v[j]) * scale;
  }
  __syncthreads();
  const int wave = t >> 6, lane = t & 63;
  u16* eb = ebuf + (size_t)i * NBL + ((size_t)b * Lz + l0) * Cz;
  for (int r = wave; r < 32; r += 4) {
    float vals[8];
    float s1 = 0.f, s2 = 0.f;
#pragma unroll
    for (int j = 0; j < 8; j++) {
      float v = tile[r][lane + j * 64];
      vals[j] = v; s1 += v; s2 += v * v;
    }
    for (int off = 32; off > 0; off >>= 1) {
      s1 += __shfl_xor(s1, off, 64);
      s2 += __shfl_xor(s2, off, 64);
    }
    const float m = s1 * (1.f / Cz);
    const float var = s2 * (1.f / Cz) - m * m;
    const float inv = rsqrtf(var + EPSz);
#pragma unroll
    for (int j = 0; j < 8; j++) {
      const int cc = lane + j * 64;
      eb[(size_t)r * Cz + cc] = f2bf((vals[j] - m) * inv * g[cc] + bb[cc]);
    }
  }
}

// ---------------------------------------------------------------------------
// E: score via MFMA, k0-outer full-B staging (unchanged)
// ---------------------------------------------------------------------------
__global__ __launch_bounds__(256) void score_mfma_kernel(
    const u16* __restrict__ e0, const u16* __restrict__ e1,
    const u16* __restrict__ e2, const u16* __restrict__ e3,
    const u16* __restrict__ wvbf, const float* __restrict__ bv,
    const float* __restrict__ qc, const float* __restrict__ wg,
    const float* __restrict__ bg, float* __restrict__ scores) {
  __shared__ u16 sA[64][40];
  __shared__ u16 sB[256][40];
  __shared__ float sP[4][64];
  const int i = blockIdx.y;
  const u16* E = (i == 0) ? e0 : (i == 1) ? e1 : (i == 2) ? e2 : e3;
  const int r0 = blockIdx.x * 64;
  const int t = threadIdx.x;
  const int lane = t & 63, w = t >> 6;
  const int srow = t >> 2, skoff = (t & 3) * 8;
  const int fr = lane & 15, fk = (lane >> 4) * 8;
  const u16* ap = E + (size_t)(r0 + srow) * Cz + skoff;
  const u16* bp = wvbf + (size_t)srow * Cz + skoff;
  f32x4 acc[4][4];
#pragma unroll
  for (int m = 0; m < 4; m++)
#pragma unroll
    for (int j = 0; j < 4; j++)
#pragma unroll
      for (int r = 0; r < 4; r++) acc[m][j][r] = 0.f;
  for (int k0 = 0; k0 < Cz; k0 += 32) {
    u16x8 av = *(const u16x8*)(ap + k0);
    u16x8 bq0 = *(const u16x8*)(bp + k0);
    u16x8 bq1 = *(const u16x8*)(bp + (size_t)64 * Cz + k0);
    u16x8 bq2 = *(const u16x8*)(bp + (size_t)128 * Cz + k0);
    u16x8 bq3 = *(const u16x8*)(bp + (size_t)192 * Cz + k0);
    __syncthreads();
    *(u16x8*)&sA[srow][skoff] = av;
    *(u16x8*)&sB[srow][skoff] = bq0;
    *(u16x8*)&sB[srow + 64][skoff] = bq1;
    *(u16x8*)&sB[srow + 128][skoff] = bq2;
    *(u16x8*)&sB[srow + 192][skoff] = bq3;
    __syncthreads();
    bf16x8 am[4], bj[4];
#pragma unroll
    for (int m = 0; m < 4; m++) am[m] = *(const bf16x8*)&sA[m * 16 + fr][fk];
#pragma unroll
    for (int j = 0; j < 4; j++)
      bj[j] = *(const bf16x8*)&sB[(w * 4 + j) * 16 + fr][fk];
#pragma unroll
    for (int m = 0; m < 4; m++)
#pragma unroll
      for (int j = 0; j < 4; j++)
        acc[m][j] = mfma16(am[m], bj[j], acc[m][j]);
  }
  float part[4][4];
#pragma unroll
  for (int m = 0; m < 4; m++)
#pragma unroll
    for (int r = 0; r < 4; r++) part[m][r] = 0.f;
#pragma unroll
  for (int j = 0; j < 4; j++) {
    const int dh = (w * 4 + j) * 16 + fr;
    const float bvn = bv[dh], qcn = qc[dh], wgn = wg[dh];
#pragma unroll
    for (int m = 0; m < 4; m++)
#pragma unroll
      for (int r = 0; r < 4; r++)
        part[m][r] += tanhf(qcn * (acc[m][j][r] + bvn)) * wgn;
  }
#pragma unroll
  for (int off = 1; off < 16; off <<= 1) {
#pragma unroll
    for (int m = 0; m < 4; m++)
#pragma unroll
      for (int r = 0; r < 4; r++)
        part[m][r] += __shfl_xor(part[m][r], off, 64);
  }
  if (fr == 0) {
#pragma unroll
    for (int m = 0; m < 4; m++)
#pragma unroll
      for (int r = 0; r < 4; r++)
        sP[w][m * 16 + ((lane >> 4) << 2) + r] = part[m][r];
  }
  __syncthreads();
  if (t < 64) {
    float s = sP[0][t] + sP[1][t] + sP[2][t] + sP[3][t] + bg[0];
    scores[(size_t)i * MT + r0 + t] = s;
  }
}

// ---------------------------------------------------------------------------
// G: fused softmax-combine + op GEMM, panel-resident: block owns 32 rows,
// combines A once, loops k0 staging ALL 512 op_w rows per k-slice.
// grid MT/32 = 512, 256 thr. Output bf16.
// ---------------------------------------------------------------------------
__global__ __launch_bounds__(256, 2) void op_mfma_kernel(
    const u16* __restrict__ e0, const u16* __restrict__ e1,
    const u16* __restrict__ e2, const u16* __restrict__ e3,
    const float* __restrict__ scores, const u16* __restrict__ opwbf,
    const float* __restrict__ opb, u16* __restrict__ oproj) {
  __shared__ u16 sA[32][520];   // combined A panel full-K, 33,280 B
  __shared__ u16 sB[512][40];   // op_w k-slice, 40,960 B
  __shared__ float sw4[4][32];
  const int m0 = blockIdx.x * 32;
  const int t = threadIdx.x;
  const int lane = t & 63, w = t >> 6;
  const int fr = lane & 15, fk = (lane >> 4) * 8;
  const int mh = (w >> 1) * 16;  // m-frag base within 32-row panel (0 or 16)
  const int nh = (w & 1) * 16;   // n-frag half base (0 or 16 -> cols 0/256)
  if (t < 32) {
    const int r = m0 + t;
    float s0 = scores[r], s1 = scores[MT + r], s2 = scores[2 * MT + r],
          s3 = scores[3 * MT + r];
    float mx = fmaxf(fmaxf(s0, s1), fmaxf(s2, s3));
    float x0 = expf(s0 - mx), x1 = expf(s1 - mx), x2 = expf(s2 - mx),
          x3 = expf(s3 - mx);
    float inv = 1.f / (x0 + x1 + x2 + x3);
    sw4[0][t] = x0 * inv; sw4[1][t] = x1 * inv;
    sw4[2][t] = x2 * inv; sw4[3][t] = x3 * inv;
  }
  __syncthreads();
#pragma unroll
  for (int rep = 0; rep < 8; rep++) {
    const int idx = rep * 256 + t;
    const int row = idx >> 6;
    const int col = (idx & 63) * 8;
    const size_t off = (size_t)(m0 + row) * Cz + col;
    u16x8 v0 = *(const u16x8*)(e0 + off);
    u16x8 v1 = *(const u16x8*)(e1 + off);
    u16x8 v2 = *(const u16x8*)(e2 + off);
    u16x8 v3 = *(const u16x8*)(e3 + off);
    const float x0 = sw4[0][row], x1 = sw4[1][row], x2 = sw4[2][row],
                x3 = sw4[3][row];
    u16x8 o;
#pragma unroll
    for (int j = 0; j < 8; j++)
      o[j] = f2bf(x0 * bf2f(v0[j]) + x1 * bf2f(v1[j]) + x2 * bf2f(v2[j]) +
                  x3 * bf2f(v3[j]));
    *(u16x8*)&sA[row][col] = o;
  }
  f32x4 acc[16];
#pragma unroll
  for (int nf = 0; nf < 16; nf++)
#pragma unroll
    for (int r = 0; r < 4; r++) acc[nf][r] = 0.f;
  const int wrow = t >> 2, wch = (t & 3) * 8;
  const u16* wbase = opwbf + (size_t)wrow * Cz + wch;
  u16x8 breg[8];
#pragma unroll
  for (int rep = 0; rep < 8; rep++)
    breg[rep] = *(const u16x8*)(wbase + (size_t)rep * 64 * Cz);
  for (int k0 = 0; k0 < Cz; k0 += 32) {
    __syncthreads();
#pragma unroll
    for (int rep = 0; rep < 8; rep++)
      *(u16x8*)&sB[rep * 64 + wrow][wch] = breg[rep];
    __syncthreads();
    if (k0 + 32 < Cz) {
#pragma unroll
      for (int rep = 0; rep < 8; rep++)
        breg[rep] = *(const u16x8*)(wbase + (size_t)rep * 64 * Cz + k0 + 32);
    }
    bf16x8 a = *(const bf16x8*)&sA[mh + fr][k0 + fk];
#pragma unroll
    for (int nf = 0; nf < 16; nf++) {
      bf16x8 b = *(const bf16x8*)&sB[(nh + nf) * 16 + fr][fk];
      acc[nf] = mfma16(a, b, acc[nf]);
    }
  }
  __syncthreads();  // all sA/sB reads done; reuse sA as sC[32][520]
  u16* sC = (u16*)&sA[0][0];
#pragma unroll
  for (int nf = 0; nf < 16; nf++) {
    const int n = (nh + nf) * 16 + fr;
    const float ob = opb[n];
#pragma unroll
    for (int r = 0; r < 4; r++) {
      const int row = mh + ((lane >> 4) << 2) + r;
      sC[row * 520 + n] = f2bf(acc[nf][r] + ob);
    }
  }
  __syncthreads();
#pragma unroll
  for (int rep = 0; rep < 8; rep++) {
    const int idx = rep * 256 + t;
    const int row = idx >> 6;
    const int col = (idx & 63) * 8;
    u16x8 v = *(const u16x8*)&sC[row * 520 + col];
    *(u16x8*)(oproj + (size_t)(m0 + row) * Cz + col) = v;
  }
}

// ---------------------------------------------------------------------------
// H: out = LN2( LN1(oproj)*g1+b1 + x )  oproj bf16, out fp32 (unchanged)
// ---------------------------------------------------------------------------
__global__ __launch_bounds__(256) void final_ln_kernel(
    const u16* __restrict__ oproj, const float* __restrict__ g1,
    const float* __restrict__ b1, const float* __restrict__ x,
    const float* __restrict__ g2, const float* __restrict__ b2,
    float* __restrict__ out) {
  const int t = threadIdx.x;
  const int row = blockIdx.x * 4 + (t >> 6);
  const int lane = t & 63;
  u16x8 av = ((const u16x8*)(oproj + (size_t)row * Cz))[lane];
  float v[8];
  float s1 = 0.f, s2 = 0.f;
#pragma unroll
  for (int j = 0; j < 8; j++) {
    v[j] = bf2f(av[j]);
    s1 += v[j]; s2 += v[j] * v[j];
  }
  for (int off = 1; off < 64; off <<= 1) {
    s1 += __shfl_xor(s1, off, 64);
    s2 += __shfl_xor(s2, off, 64);
  }
  const float m1 = s1 * (1.f / Cz);
  const float iv1 = rsqrtf(s2 * (1.f / Cz) - m1 * m1 + EPSz);
  float4 g1a = ((const float4*)g1)[lane * 2], g1b = ((const float4*)g1)[lane * 2 + 1];
  float4 b1a = ((const float4*)b1)[lane * 2], b1b = ((const float4*)b1)[lane * 2 + 1];
  const float* xr = x + (size_t)row * Cz;
  float4 xa = ((const float4*)xr)[lane * 2], xb = ((const float4*)xr)[lane * 2 + 1];
  float gv[8] = {g1a.x, g1a.y, g1a.z, g1a.w, g1b.x, g1b.y, g1b.z, g1b.w};
  float bvv[8] = {b1a.x, b1a.y, b1a.z, b1a.w, b1b.x, b1b.y, b1b.z, b1b.w};
  float xv[8] = {xa.x, xa.y, xa.z, xa.w, xb.x, xb.y, xb.z, xb.w};
  float tv[8];
  s1 = 0.f; s2 = 0.f;
#pragma unroll
  for (int j = 0; j < 8; j++) {
    tv[j] = (v[j] - m1) * iv1 * gv[j] + bvv[j] + xv[j];
    s1 += tv[j]; s2 += tv[j] * tv[j];
  }
  for (int off = 1; off < 64; off <<= 1) {
    s1 += __shfl_xor(s1, off, 64);
    s2 += __shfl_xor(s2, off, 64);
  }
  const float m2 = s1 * (1.f / Cz);
  const float iv2 = rsqrtf(s2 * (1.f / Cz) - m2 * m2 + EPSz);
  float4 g2a = ((const float4*)g2)[lane * 2], g2b = ((const float4*)g2)[lane * 2 + 1];
  float4 b2a = ((const float4*)b2)[lane * 2], b2b = ((const float4*)b2)[lane * 2 + 1];
  float g2v[8] = {g2a.x, g2a.y, g2a.z, g2a.w, g2b.x, g2b.y, g2b.z, g2b.w};
  float b2v[8] = {b2a.x, b2a.y, b2a.z, b2a.w, b2b.x, b2b.y, b2b.z, b2b.w};
  float4 oa, ob;
  oa.x = (tv[0] - m2) * iv2 * g2v[0] + b2v[0];
  oa.y = (tv[1] - m2) * iv2 * g2v[1] + b2v[1];
  oa.z = (tv[2] - m2) * iv2 * g2v[2] + b2v[2];
  oa.w = (tv[3] - m2) * iv2 * g2v[3] + b2v[3];
  ob.x = (tv[4] - m2) * iv2 * g2v[4] + b2v[4];
  ob.y = (tv[5] - m2) * iv2 * g2v[5] + b2v[5];
  ob.z = (tv[6] - m2) * iv2 * g2v[6] + b2v[6];
  ob.w = (tv[7] - m2) * iv2 * g2v[7] + b2v[7];
  float* orow = out + (size_t)row * Cz;
  ((float4*)orow)[lane * 2] = oa;
  ((float4*)orow)[lane * 2 + 1] = ob;
}

// ---------------------------------------------------------------------------
extern "C" void kernel_launch(void* const* d_in, const int* in_sizes, int n_in,
                              void* d_out, int out_size, void* d_ws,
                              size_t ws_size, hipStream_t stream) {
  const float* x = (const float*)d_in[0];
  const float* pw_w = (const float*)d_in[1];
  const float* pw_b = (const float*)d_in[2];
  const float* pw_bn_g = (const float*)d_in[3];
  const float* pw_bn_b = (const float*)d_in[4];
  const float* pw_bn_m = (const float*)d_in[5];
  const float* pw_bn_v = (const float*)d_in[6];
  const float* dw_w0 = (const float*)d_in[7];
  const float* dw_w1 = (const float*)d_in[8];
  const float* dw_w2 = (const float*)d_in[9];
  const float* dw_w3 = (const float*)d_in[10];
  const float* dw_b = (const float*)d_in[11];
  const float* dw_bn_g = (const float*)d_in[12];
  const float* dw_bn_b = (const float*)d_in[13];
  const float* dw_bn_m = (const float*)d_in[14];
  const float* dw_bn_v = (const float*)d_in[15];
  const float* se_w1 = (const float*)d_in[16];
  const float* se_b1 = (const float*)d_in[17];
  const float* se_w2 = (const float*)d_in[18];
  const float* se_b2 = (const float*)d_in[19];
  const float* se_ln_g = (const float*)d_in[20];
  const float* se_ln_b = (const float*)d_in[21];
  // d_in[22] = df_ln_g (unused: LN of channel-constant rows -> bias only)
  const float* df_ln_b = (const float*)d_in[23];
  const float* wq = (const float*)d_in[24];
  const float* bq = (const float*)d_in[25];
  const float* wv = (const float*)d_in[26];
  const float* bv = (const float*)d_in[27];
  const float* wg = (const float*)d_in[28];
  const float* bg = (const float*)d_in[29];
  const float* op_w = (const float*)d_in[30];
  const float* op_b = (const float*)d_in[31];
  const float* op_ln_g = (const float*)d_in[32];
  const float* op_ln_b = (const float*)d_in[33];
  const float* fn_g = (const float*)d_in[34];
  const float* fn_b = (const float*)d_in[35];
  float* out = (float*)d_out;

  const size_t NBL = (size_t)Bz * Cz * Lz;  // 8388608 elems
  char* p = (char*)d_ws;
  u16* oproj = (u16*)p; p += NBL * 2;        // 16MB
  u16* xpw = (u16*)p; p += NBL * 2;          // 16MB
  u16* ybuf = (u16*)p; p += 4 * NBL * 2;     // 64MB
  u16* ebuf = (u16*)p; p += 4 * NBL * 2;     // 64MB
  u16* pwwbf = (u16*)p; p += (size_t)Cz * Cz * 2;    // 512KB
  u16* wvbf = (u16*)p; p += (size_t)DHz * Cz * 2;    // 256KB
  u16* opwbf = (u16*)p; p += (size_t)Cz * Cz * 2;    // 512KB
  float* fbuf = (float*)p;
  float* ysum = fbuf;                  // 16384
  float* scv = fbuf + 16384;           // 16384
  float* scores = fbuf + 32768;        // 65536
  float* pwA = fbuf + 98304;           // 512
  float* pwB = pwA + 512;              // 512
  float* dwA = pwB + 512;              // 2048
  float* dwB = dwA + 2048;             // 2048
  float* qc = dwB + 2048;              // 256

  cvt_bf16_kernel<<<Cz * Cz / 8 / 256, 256, 0, stream>>>(pw_w, pwwbf,
                                                         Cz * Cz / 8);
  cvt_bf16_kernel<<<DHz * Cz / 8 / 256, 256, 0, stream>>>(wv, wvbf,
                                                          DHz * Cz / 8);
  cvt_bf16_kernel<<<Cz * Cz / 8 / 256, 256, 0, stream>>>(op_w, opwbf,
                                                         Cz * Cz / 8);

  prep_kernel<<<6, 256, 0, stream>>>(pw_b, pw_bn_g, pw_bn_b, pw_bn_m, pw_bn_v,
                                     dw_b, dw_bn_g, dw_bn_b, dw_bn_m, dw_bn_v,
                                     df_ln_b, wq, bq, pwA, pwB, dwA, dwB, qc);

  pw_mfma_kernel<<<Bz * (Lz / 32), 256, 0, stream>>>(pwwbf, x, pwA, pwB, xpw);

  dw_conv_kernel<<<4 * Bz * Cz, 256, 0, stream>>>(xpw, dw_w0, dw_w1, dw_w2,
                                                  dw_w3, dwA, dwB, ybuf, ysum);

  se_kernel<<<32, 128, 0, stream>>>(ysum, se_w1, se_b1, se_w2, se_b2, scv);

  ln_transpose_kernel<<<dim3(Lz / 32, 4 * Bz), 256, 0, stream>>>(
      ybuf, scv, se_ln_g, se_ln_b, ebuf);

  score_mfma_kernel<<<dim3(MT / 64, 4), 256, 0, stream>>>(
      ebuf, ebuf + NBL, ebuf + 2 * NBL, ebuf + 3 * NBL, wvbf, bv, qc, wg, bg,
      scores);

  op_mfma_kernel<<<MT / 32, 256, 0, stream>>>(
      ebuf, ebuf + NBL, ebuf + 2 * NBL, ebuf + 3 * NBL, scores, opwbf, op_b,
      oproj);

  final_ln_kernel<<<MT / 4, 256, 0, stream>>>(oproj, op_ln_g, op_ln_b, x, fn_g,
                                              fn_b, out);
}

// Round 7
// 236.428 us; speedup vs baseline: 3.1434x; 1.0657x over previous
//
#include <hip/hip_runtime.h>
#include <math.h>

static constexpr int Bz = 8;
static constexpr int Lz = 2048;
static constexpr int Cz = 512;
static constexpr int CRz = 128;
static constexpr int DHz = 256;
static constexpr int MT = Bz * Lz;           // 16384 rows
static constexpr float EPSz = 1e-5f;

typedef unsigned short u16;
typedef __bf16 bf16x8 __attribute__((ext_vector_type(8)));
typedef float f32x4 __attribute__((ext_vector_type(4)));
typedef unsigned short u16x8 __attribute__((ext_vector_type(8)));

__device__ __forceinline__ float bf2f(u16 u) {
  unsigned int v = ((unsigned int)u) << 16;
  return __builtin_bit_cast(float, v);
}
__device__ __forceinline__ u16 f2bf(float f) {
  unsigned int b = __builtin_bit_cast(unsigned int, f);
  b += 0x7FFFu + ((b >> 16) & 1u);
  return (u16)(b >> 16);
}
__device__ __forceinline__ f32x4 mfma16(bf16x8 a, bf16x8 b, f32x4 c) {
  return __builtin_amdgcn_mfma_f32_16x16x32_bf16(a, b, c, 0, 0, 0);
}

// ---------------------------------------------------------------------------
// cvt: fp32 -> bf16 (8 elems/thread) — weights only
// ---------------------------------------------------------------------------
__global__ __launch_bounds__(256) void cvt_bf16_kernel(
    const float* __restrict__ src, u16* __restrict__ dst, int n8) {
  int i = blockIdx.x * 256 + threadIdx.x;
  if (i >= n8) return;
  const float4* s = (const float4*)src;
  float4 a = s[i * 2], b = s[i * 2 + 1];
  u16x8 o;
  o[0] = f2bf(a.x); o[1] = f2bf(a.y); o[2] = f2bf(a.z); o[3] = f2bf(a.w);
  o[4] = f2bf(b.x); o[5] = f2bf(b.y); o[6] = f2bf(b.z); o[7] = f2bf(b.w);
  ((u16x8*)dst)[i] = o;
}

// ---------------------------------------------------------------------------
// P: fold BN params; compute Q const vector (diff-path LN collapses to bias)
// ---------------------------------------------------------------------------
__global__ __launch_bounds__(256) void prep_kernel(
    const float* __restrict__ pw_b, const float* __restrict__ pw_g,
    const float* __restrict__ pw_bb, const float* __restrict__ pw_m,
    const float* __restrict__ pw_v,
    const float* __restrict__ dw_b, const float* __restrict__ dw_g,
    const float* __restrict__ dw_bb, const float* __restrict__ dw_m,
    const float* __restrict__ dw_v,
    const float* __restrict__ df_ln_b, const float* __restrict__ wq,
    const float* __restrict__ bq,
    float* __restrict__ pwA, float* __restrict__ pwB,
    float* __restrict__ dwA, float* __restrict__ dwB,
    float* __restrict__ qc) {
  const int blk = blockIdx.x;
  const int t = threadIdx.x;
  if (blk == 0) {
    for (int c = t; c < Cz; c += 256) {
      float inv = rsqrtf(pw_v[c] + EPSz);
      float a = pw_g[c] * inv;
      float bb = pw_bb[c] - pw_m[c] * a;
      pwA[c] = a;
      pwB[c] = pw_b[c] * a + bb;
    }
  } else if (blk <= 4) {
    const int i = blk - 1;
    for (int c = t; c < Cz; c += 256) {
      int idx = i * Cz + c;
      float inv = rsqrtf(dw_v[idx] + EPSz);
      float a = dw_g[idx] * inv;
      float bb = dw_bb[idx] - dw_m[idx] * a;
      dwA[idx] = a;
      dwB[idx] = dw_b[idx] * a + bb;
    }
  } else {
    if (t < DHz) {
      float s = bq[t];
      const float* w = wq + (size_t)t * Cz;
      for (int c = 0; c < Cz; c++) s += df_ln_b[c] * w[c];
      qc[t] = s;
    }
  }
}

// ---------------------------------------------------------------------------
// A: pointwise conv, panel-resident (unchanged)
// ---------------------------------------------------------------------------
__global__ __launch_bounds__(256, 2) void pw_mfma_kernel(
    const u16* __restrict__ Wbf, const float* __restrict__ x,
    const float* __restrict__ alpha, const float* __restrict__ beta,
    u16* __restrict__ xpw) {
  __shared__ __align__(16) char lds[74240];
  u16(*sX)[520] = (u16(*)[520])lds;                  // [32][520] = 33,280 B
  u16(*sW)[40] = (u16(*)[40])(lds + 33280);          // [512][40] = 40,960 B
  u16* sC = (u16*)(lds + 33280);                     // [512][40] epilogue alias
  __shared__ float sAl[Cz];
  __shared__ float sBe[Cz];
  const int bat = blockIdx.x >> 6;
  const int l0 = (blockIdx.x & 63) * 32;
  const int t = threadIdx.x;
  const int lane = t & 63, w = t >> 6;
  const int fr = lane & 15, fk = (lane >> 4) * 8;
  const int mh = (w >> 1) * 16;   // m-frag half base (o dimension)
  const int nh = (w & 1) * 16;    // n-frag col base (l dimension)
#pragma unroll
  for (int rep = 0; rep < 8; rep++) {
    const int idx = rep * 256 + t;
    const int row = idx >> 6;
    const int col = (idx & 63) * 8;
    const float* src = x + ((size_t)bat * Lz + l0 + row) * Cz + col;
    float4 f0 = *(const float4*)src;
    float4 f1 = *(const float4*)(src + 4);
    u16x8 o;
    o[0] = f2bf(f0.x); o[1] = f2bf(f0.y); o[2] = f2bf(f0.z); o[3] = f2bf(f0.w);
    o[4] = f2bf(f1.x); o[5] = f2bf(f1.y); o[6] = f2bf(f1.z); o[7] = f2bf(f1.w);
    *(u16x8*)&sX[row][col] = o;
  }
  for (int c = t; c < Cz; c += 256) { sAl[c] = alpha[c]; sBe[c] = beta[c]; }
  f32x4 acc[16];
#pragma unroll
  for (int mf = 0; mf < 16; mf++)
#pragma unroll
    for (int r = 0; r < 4; r++) acc[mf][r] = 0.f;
  const int wrow = t >> 2, wch = (t & 3) * 8;
  const u16* wbase = Wbf + (size_t)wrow * Cz + wch;
  u16x8 breg[8];
#pragma unroll
  for (int rep = 0; rep < 8; rep++)
    breg[rep] = *(const u16x8*)(wbase + (size_t)rep * 64 * Cz);
  for (int k0 = 0; k0 < Cz; k0 += 32) {
    __syncthreads();
#pragma unroll
    for (int rep = 0; rep < 8; rep++)
      *(u16x8*)&sW[rep * 64 + wrow][wch] = breg[rep];
    __syncthreads();
    if (k0 + 32 < Cz) {
#pragma unroll
      for (int rep = 0; rep < 8; rep++)
        breg[rep] = *(const u16x8*)(wbase + (size_t)rep * 64 * Cz + k0 + 32);
    }
    bf16x8 bfrag = *(const bf16x8*)&sX[nh + fr][k0 + fk];
#pragma unroll
    for (int mf = 0; mf < 16; mf++) {
      bf16x8 a = *(const bf16x8*)&sW[(mh + mf) * 16 + fr][fk];
      acc[mf] = mfma16(a, bfrag, acc[mf]);
    }
  }
  __syncthreads();  // sW reads done; reuse as sC[512][40]
#pragma unroll
  for (int mf = 0; mf < 16; mf++) {
#pragma unroll
    for (int r = 0; r < 4; r++) {
      const int o = (mh + mf) * 16 + ((lane >> 4) << 2) + r;
      const int l = nh + fr;
      float v = fmaxf(acc[mf][r] * sAl[o] + sBe[o], 0.f);
      sC[o * 40 + l] = f2bf(v);
    }
  }
  __syncthreads();
#pragma unroll
  for (int rep = 0; rep < 8; rep++) {
    const int o = rep * 64 + (t >> 2);
    const int l8 = (t & 3) * 8;
    u16x8 v = *(const u16x8*)&sC[o * 40 + l8];
    *(u16x8*)(xpw + ((size_t)(bat * Cz + o)) * Lz + l0 + l8) = v;
  }
}

// ---------------------------------------------------------------------------
// B: depthwise conv, ALL 4 branches per block; padded LDS (conflict-free).
// phys(l) = l + (l>>5): lane-stride-8 reads spread across all 32 banks.
// grid Bz*Cz = 4096, 256 thr; block = one (b,c) row of length L.
// ---------------------------------------------------------------------------
template <int K>
__device__ __forceinline__ float dw_branch(const float* __restrict__ row,
                                           const float* __restrict__ wts,
                                           float a, float bb, int valid, int t,
                                           u16* __restrict__ dst) {
  constexpr int P = (K - 1) / 2;
  constexpr int W = 8 + K - 1;
  float wreg[K];
#pragma unroll
  for (int j = 0; j < K; j++) wreg[j] = wts[j];
  const int base = t * 8 - P;
  float win[W];
  if (base >= 0 && base + W <= Lz) {
#pragma unroll
    for (int j = 0; j < W; j++) {
      const int idx = base + j;
      win[j] = row[idx + (idx >> 5)];
    }
  } else {
#pragma unroll
    for (int j = 0; j < W; j++) {
      const int idx = base + j;
      win[j] = (idx >= 0 && idx < Lz) ? row[idx + (idx >> 5)] : 0.f;
    }
  }
  float acc[8] = {};
#pragma unroll
  for (int jj = 0; jj < K; jj++)
#pragma unroll
    for (int o = 0; o < 8; o++) acc[o] = fmaf(wreg[jj], win[jj + o], acc[o]);
  u16x8 ov;
  float psum = 0.f;
#pragma unroll
  for (int o = 0; o < 8; o++) {
    float v = fmaxf(acc[o] * a + bb, 0.f);
    if (t * 8 + o >= valid) v = 0.f;
    ov[o] = f2bf(v);
    psum += v;
  }
  *(u16x8*)(dst + t * 8) = ov;
  return psum;
}

__global__ __launch_bounds__(256) void dw_conv_kernel(
    const u16* __restrict__ xpw,
    const float* __restrict__ w0, const float* __restrict__ w1,
    const float* __restrict__ w2, const float* __restrict__ w3,
    const float* __restrict__ dwA, const float* __restrict__ dwB,
    u16* __restrict__ y, float* __restrict__ ysum) {
  __shared__ float row[Lz + Lz / 32];  // padded: phys = l + (l>>5)
  __shared__ float wts[48];
  __shared__ float wsum[4][4];         // [wave][branch]
  const int b = blockIdx.x >> 9;
  const int c = blockIdx.x & 511;
  const int t = threadIdx.x;
  const size_t NBL = (size_t)Bz * Cz * Lz;
  // stage row once (bf16 -> padded f32 LDS)
  {
    u16x8 v = ((const u16x8*)(xpw + ((size_t)(b * Cz + c)) * Lz))[t];
#pragma unroll
    for (int j = 0; j < 8; j++) {
      const int idx = t * 8 + j;
      row[idx + (idx >> 5)] = bf2f(v[j]);
    }
  }
  // stage all 45 taps: [0..2]=w0, [3..9]=w1, [10..24]=w2, [25..44]=w3
  if (t < 45) {
    float wv;
    if (t < 3) wv = w0[c * 3 + t];
    else if (t < 10) wv = w1[c * 7 + (t - 3)];
    else if (t < 25) wv = w2[c * 15 + (t - 10)];
    else wv = w3[c * 20 + (t - 25)];
    wts[t] = wv;
  }
  __syncthreads();
  u16* dstb = y + ((size_t)b * Cz + c) * Lz;
  float ps[4];
  ps[0] = dw_branch<3>(row, wts + 0, dwA[c], dwB[c], Lz, t, dstb);
  ps[1] = dw_branch<7>(row, wts + 3, dwA[Cz + c], dwB[Cz + c], Lz, t,
                       dstb + NBL);
  ps[2] = dw_branch<15>(row, wts + 10, dwA[2 * Cz + c], dwB[2 * Cz + c], Lz, t,
                        dstb + 2 * NBL);
  ps[3] = dw_branch<20>(row, wts + 25, dwA[3 * Cz + c], dwB[3 * Cz + c],
                        Lz - 1, t, dstb + 3 * NBL);
#pragma unroll
  for (int off = 32; off > 0; off >>= 1) {
#pragma unroll
    for (int i = 0; i < 4; i++) ps[i] += __shfl_down(ps[i], off, 64);
  }
  if ((t & 63) == 0) {
#pragma unroll
    for (int i = 0; i < 4; i++) wsum[t >> 6][i] = ps[i];
  }
  __syncthreads();
  if (t < 4)
    ysum[(t * Bz + b) * Cz + c] =
        wsum[0][t] + wsum[1][t] + wsum[2][t] + wsum[3][t];
}

// ---------------------------------------------------------------------------
// C: squeeze-excite (unchanged)
// ---------------------------------------------------------------------------
__global__ __launch_bounds__(128) void se_kernel(
    const float* __restrict__ ysum,
    const float* __restrict__ se_w1, const float* __restrict__ se_b1,
    const float* __restrict__ se_w2, const float* __restrict__ se_b2,
    float* __restrict__ sc) {
  const int i = blockIdx.x >> 3;
  const int b = blockIdx.x & 7;
  __shared__ float ym[Cz];
  __shared__ float h[CRz];
  const int t = threadIdx.x;
  const float* ys = ysum + (i * Bz + b) * Cz;
  for (int cc = t; cc < Cz; cc += 128) ym[cc] = ys[cc] * (1.f / Lz);
  __syncthreads();
  {
    const float* w1 = se_w1 + (size_t)i * CRz * Cz + (size_t)t * Cz;
    float s = se_b1[i * CRz + t];
    for (int cc = 0; cc < Cz; cc++) s += ym[cc] * w1[cc];
    h[t] = fmaxf(s, 0.f);
  }
  __syncthreads();
  for (int cc = t; cc < Cz; cc += 128) {
    const float* w2 = se_w2 + ((size_t)i * Cz + cc) * CRz;
    float s = se_b2[i * Cz + cc];
    for (int r = 0; r < CRz; r++) s += h[r] * w2[r];
    float wt = 1.f / (1.f + expf(-s));
    sc[(i * Bz + b) * Cz + cc] = 1.f + wt;
  }
}

// ---------------------------------------------------------------------------
// D: enhanced = LN_c( y[b,c,l]*sc[b,c] ), 32-l tiles (unchanged)
// ---------------------------------------------------------------------------
__global__ __launch_bounds__(256) void ln_transpose_kernel(
    const u16* __restrict__ ybuf, const float* __restrict__ scv,
    const float* __restrict__ se_ln_g, const float* __restrict__ se_ln_b,
    u16* __restrict__ ebuf) {
  __shared__ float tile[32][Cz + 1];
  const size_t NBL = (size_t)Bz * Cz * Lz;
  const int i = blockIdx.y >> 3;
  const int b = blockIdx.y & 7;
  const int l0 = blockIdx.x * 32;
  const int t = threadIdx.x;
  const u16* yb = ybuf + (size_t)i * NBL + (size_t)b * Cz * Lz;
  const float* scb = scv + (i * Bz + b) * Cz;
  const float* g = se_ln_g + i * Cz;
  const float* bb = se_ln_b + i * Cz;
#pragma unroll
  for (int rep = 0; rep < 8; rep++) {
    const int idx = rep * 256 + t;
    const int c = idx >> 2;
    const int l8 = (idx & 3) * 8;
    u16x8 v = *(const u16x8*)(yb + (size_t)c * Lz + l0 + l8);
    const float scale = scb[c];
#pragma unroll
    for (int j = 0; j < 8; j++) tile[l8 + j][c] = bf2f(v[j]) * scale;
  }
  __syncthreads();
  const int wave = t >> 6, lane = t & 63;
  u16* eb = ebuf + (size_t)i * NBL + ((size_t)b * Lz + l0) * Cz;
  for (int r = wave; r < 32; r += 4) {
    float vals[8];
    float s1 = 0.f, s2 = 0.f;
#pragma unroll
    for (int j = 0; j < 8; j++) {
      float v = tile[r][lane + j * 64];
      vals[j] = v; s1 += v; s2 += v * v;
    }
    for (int off = 32; off > 0; off >>= 1) {
      s1 += __shfl_xor(s1, off, 64);
      s2 += __shfl_xor(s2, off, 64);
    }
    const float m = s1 * (1.f / Cz);
    const float var = s2 * (1.f / Cz) - m * m;
    const float inv = rsqrtf(var + EPSz);
#pragma unroll
    for (int j = 0; j < 8; j++) {
      const int cc = lane + j * 64;
      eb[(size_t)r * Cz + cc] = f2bf((vals[j] - m) * inv * g[cc] + bb[cc]);
    }
  }
}

// ---------------------------------------------------------------------------
// E: score via MFMA, k0-outer full-B staging (unchanged)
// ---------------------------------------------------------------------------
__global__ __launch_bounds__(256) void score_mfma_kernel(
    const u16* __restrict__ e0, const u16* __restrict__ e1,
    const u16* __restrict__ e2, const u16* __restrict__ e3,
    const u16* __restrict__ wvbf, const float* __restrict__ bv,
    const float* __restrict__ qc, const float* __restrict__ wg,
    const float* __restrict__ bg, float* __restrict__ scores) {
  __shared__ u16 sA[64][40];
  __shared__ u16 sB[256][40];
  __shared__ float sP[4][64];
  const int i = blockIdx.y;
  const u16* E = (i == 0) ? e0 : (i == 1) ? e1 : (i == 2) ? e2 : e3;
  const int r0 = blockIdx.x * 64;
  const int t = threadIdx.x;
  const int lane = t & 63, w = t >> 6;
  const int srow = t >> 2, skoff = (t & 3) * 8;
  const int fr = lane & 15, fk = (lane >> 4) * 8;
  const u16* ap = E + (size_t)(r0 + srow) * Cz + skoff;
  const u16* bp = wvbf + (size_t)srow * Cz + skoff;
  f32x4 acc[4][4];
#pragma unroll
  for (int m = 0; m < 4; m++)
#pragma unroll
    for (int j = 0; j < 4; j++)
#pragma unroll
      for (int r = 0; r < 4; r++) acc[m][j][r] = 0.f;
  for (int k0 = 0; k0 < Cz; k0 += 32) {
    u16x8 av = *(const u16x8*)(ap + k0);
    u16x8 bq0 = *(const u16x8*)(bp + k0);
    u16x8 bq1 = *(const u16x8*)(bp + (size_t)64 * Cz + k0);
    u16x8 bq2 = *(const u16x8*)(bp + (size_t)128 * Cz + k0);
    u16x8 bq3 = *(const u16x8*)(bp + (size_t)192 * Cz + k0);
    __syncthreads();
    *(u16x8*)&sA[srow][skoff] = av;
    *(u16x8*)&sB[srow][skoff] = bq0;
    *(u16x8*)&sB[srow + 64][skoff] = bq1;
    *(u16x8*)&sB[srow + 128][skoff] = bq2;
    *(u16x8*)&sB[srow + 192][skoff] = bq3;
    __syncthreads();
    bf16x8 am[4], bj[4];
#pragma unroll
    for (int m = 0; m < 4; m++) am[m] = *(const bf16x8*)&sA[m * 16 + fr][fk];
#pragma unroll
    for (int j = 0; j < 4; j++)
      bj[j] = *(const bf16x8*)&sB[(w * 4 + j) * 16 + fr][fk];
#pragma unroll
    for (int m = 0; m < 4; m++)
#pragma unroll
      for (int j = 0; j < 4; j++)
        acc[m][j] = mfma16(am[m], bj[j], acc[m][j]);
  }
  float part[4][4];
#pragma unroll
  for (int m = 0; m < 4; m++)
#pragma unroll
    for (int r = 0; r < 4; r++) part[m][r] = 0.f;
#pragma unroll
  for (int j = 0; j < 4; j++) {
    const int dh = (w * 4 + j) * 16 + fr;
    const float bvn = bv[dh], qcn = qc[dh], wgn = wg[dh];
#pragma unroll
    for (int m = 0; m < 4; m++)
#pragma unroll
      for (int r = 0; r < 4; r++)
        part[m][r] += tanhf(qcn * (acc[m][j][r] + bvn)) * wgn;
  }
#pragma unroll
  for (int off = 1; off < 16; off <<= 1) {
#pragma unroll
    for (int m = 0; m < 4; m++)
#pragma unroll
      for (int r = 0; r < 4; r++)
        part[m][r] += __shfl_xor(part[m][r], off, 64);
  }
  if (fr == 0) {
#pragma unroll
    for (int m = 0; m < 4; m++)
#pragma unroll
      for (int r = 0; r < 4; r++)
        sP[w][m * 16 + ((lane >> 4) << 2) + r] = part[m][r];
  }
  __syncthreads();
  if (t < 64) {
    float s = sP[0][t] + sP[1][t] + sP[2][t] + sP[3][t] + bg[0];
    scores[(size_t)i * MT + r0 + t] = s;
  }
}

// ---------------------------------------------------------------------------
// G: fused softmax-combine + op GEMM, panel-resident (unchanged)
// ---------------------------------------------------------------------------
__global__ __launch_bounds__(256, 2) void op_mfma_kernel(
    const u16* __restrict__ e0, const u16* __restrict__ e1,
    const u16* __restrict__ e2, const u16* __restrict__ e3,
    const float* __restrict__ scores, const u16* __restrict__ opwbf,
    const float* __restrict__ opb, u16* __restrict__ oproj) {
  __shared__ u16 sA[32][520];   // combined A panel full-K, 33,280 B
  __shared__ u16 sB[512][40];   // op_w k-slice, 40,960 B
  __shared__ float sw4[4][32];
  const int m0 = blockIdx.x * 32;
  const int t = threadIdx.x;
  const int lane = t & 63, w = t >> 6;
  const int fr = lane & 15, fk = (lane >> 4) * 8;
  const int mh = (w >> 1) * 16;  // m-frag base within 32-row panel (0 or 16)
  const int nh = (w & 1) * 16;   // n-frag half base (0 or 16 -> cols 0/256)
  if (t < 32) {
    const int r = m0 + t;
    float s0 = scores[r], s1 = scores[MT + r], s2 = scores[2 * MT + r],
          s3 = scores[3 * MT + r];
    float mx = fmaxf(fmaxf(s0, s1), fmaxf(s2, s3));
    float x0 = expf(s0 - mx), x1 = expf(s1 - mx), x2 = expf(s2 - mx),
          x3 = expf(s3 - mx);
    float inv = 1.f / (x0 + x1 + x2 + x3);
    sw4[0][t] = x0 * inv; sw4[1][t] = x1 * inv;
    sw4[2][t] = x2 * inv; sw4[3][t] = x3 * inv;
  }
  __syncthreads();
#pragma unroll
  for (int rep = 0; rep < 8; rep++) {
    const int idx = rep * 256 + t;
    const int row = idx >> 6;
    const int col = (idx & 63) * 8;
    const size_t off = (size_t)(m0 + row) * Cz + col;
    u16x8 v0 = *(const u16x8*)(e0 + off);
    u16x8 v1 = *(const u16x8*)(e1 + off);
    u16x8 v2 = *(const u16x8*)(e2 + off);
    u16x8 v3 = *(const u16x8*)(e3 + off);
    const float x0 = sw4[0][row], x1 = sw4[1][row], x2 = sw4[2][row],
                x3 = sw4[3][row];
    u16x8 o;
#pragma unroll
    for (int j = 0; j < 8; j++)
      o[j] = f2bf(x0 * bf2f(v0[j]) + x1 * bf2f(v1[j]) + x2 * bf2f(v2[j]) +
                  x3 * bf2f(v3[j]));
    *(u16x8*)&sA[row][col] = o;
  }
  f32x4 acc[16];
#pragma unroll
  for (int nf = 0; nf < 16; nf++)
#pragma unroll
    for (int r = 0; r < 4; r++) acc[nf][r] = 0.f;
  const int wrow = t >> 2, wch = (t & 3) * 8;
  const u16* wbase = opwbf + (size_t)wrow * Cz + wch;
  u16x8 breg[8];
#pragma unroll
  for (int rep = 0; rep < 8; rep++)
    breg[rep] = *(const u16x8*)(wbase + (size_t)rep * 64 * Cz);
  for (int k0 = 0; k0 < Cz; k0 += 32) {
    __syncthreads();
#pragma unroll
    for (int rep = 0; rep < 8; rep++)
      *(u16x8*)&sB[rep * 64 + wrow][wch] = breg[rep];
    __syncthreads();
    if (k0 + 32 < Cz) {
#pragma unroll
      for (int rep = 0; rep < 8; rep++)
        breg[rep] = *(const u16x8*)(wbase + (size_t)rep * 64 * Cz + k0 + 32);
    }
    bf16x8 a = *(const bf16x8*)&sA[mh + fr][k0 + fk];
#pragma unroll
    for (int nf = 0; nf < 16; nf++) {
      bf16x8 b = *(const bf16x8*)&sB[(nh + nf) * 16 + fr][fk];
      acc[nf] = mfma16(a, b, acc[nf]);
    }
  }
  __syncthreads();  // all sA/sB reads done; reuse sA as sC[32][520]
  u16* sC = (u16*)&sA[0][0];
#pragma unroll
  for (int nf = 0; nf < 16; nf++) {
    const int n = (nh + nf) * 16 + fr;
    const float ob = opb[n];
#pragma unroll
    for (int r = 0; r < 4; r++) {
      const int row = mh + ((lane >> 4) << 2) + r;
      sC[row * 520 + n] = f2bf(acc[nf][r] + ob);
    }
  }
  __syncthreads();
#pragma unroll
  for (int rep = 0; rep < 8; rep++) {
    const int idx = rep * 256 + t;
    const int row = idx >> 6;
    const int col = (idx & 63) * 8;
    u16x8 v = *(const u16x8*)&sC[row * 520 + col];
    *(u16x8*)(oproj + (size_t)(m0 + row) * Cz + col) = v;
  }
}

// ---------------------------------------------------------------------------
// H: out = LN2( LN1(oproj)*g1+b1 + x )  oproj bf16, out fp32 (unchanged)
// ---------------------------------------------------------------------------
__global__ __launch_bounds__(256) void final_ln_kernel(
    const u16* __restrict__ oproj, const float* __restrict__ g1,
    const float* __restrict__ b1, const float* __restrict__ x,
    const float* __restrict__ g2, const float* __restrict__ b2,
    float* __restrict__ out) {
  const int t = threadIdx.x;
  const int row = blockIdx.x * 4 + (t >> 6);
  const int lane = t & 63;
  u16x8 av = ((const u16x8*)(oproj + (size_t)row * Cz))[lane];
  float v[8];
  float s1 = 0.f, s2 = 0.f;
#pragma unroll
  for (int j = 0; j < 8; j++) {
    v[j] = bf2f(av[j]);
    s1 += v[j]; s2 += v[j] * v[j];
  }
  for (int off = 1; off < 64; off <<= 1) {
    s1 += __shfl_xor(s1, off, 64);
    s2 += __shfl_xor(s2, off, 64);
  }
  const float m1 = s1 * (1.f / Cz);
  const float iv1 = rsqrtf(s2 * (1.f / Cz) - m1 * m1 + EPSz);
  float4 g1a = ((const float4*)g1)[lane * 2], g1b = ((const float4*)g1)[lane * 2 + 1];
  float4 b1a = ((const float4*)b1)[lane * 2], b1b = ((const float4*)b1)[lane * 2 + 1];
  const float* xr = x + (size_t)row * Cz;
  float4 xa = ((const float4*)xr)[lane * 2], xb = ((const float4*)xr)[lane * 2 + 1];
  float gv[8] = {g1a.x, g1a.y, g1a.z, g1a.w, g1b.x, g1b.y, g1b.z, g1b.w};
  float bvv[8] = {b1a.x, b1a.y, b1a.z, b1a.w, b1b.x, b1b.y, b1b.z, b1b.w};
  float xv[8] = {xa.x, xa.y, xa.z, xa.w, xb.x, xb.y, xb.z, xb.w};
  float tv[8];
  s1 = 0.f; s2 = 0.f;
#pragma unroll
  for (int j = 0; j < 8; j++) {
    tv[j] = (v[j] - m1) * iv1 * gv[j] + bvv[j] + xv[j];
    s1 += tv[j]; s2 += tv[j] * tv[j];
  }
  for (int off = 1; off < 64; off <<= 1) {
    s1 += __shfl_xor(s1, off, 64);
    s2 += __shfl_xor(s2, off, 64);
  }
  const float m2 = s1 * (1.f / Cz);
  const float iv2 = rsqrtf(s2 * (1.f / Cz) - m2 * m2 + EPSz);
  float4 g2a = ((const float4*)g2)[lane * 2], g2b = ((const float4*)g2)[lane * 2 + 1];
  float4 b2a = ((const float4*)b2)[lane * 2], b2b = ((const float4*)b2)[lane * 2 + 1];
  float g2v[8] = {g2a.x, g2a.y, g2a.z, g2a.w, g2b.x, g2b.y, g2b.z, g2b.w};
  float b2v[8] = {b2a.x, b2a.y, b2a.z, b2a.w, b2b.x, b2b.y, b2b.z, b2b.w};
  float4 oa, ob;
  oa.x = (tv[0] - m2) * iv2 * g2v[0] + b2v[0];
  oa.y = (tv[1] - m2) * iv2 * g2v[1] + b2v[1];
  oa.z = (tv[2] - m2) * iv2 * g2v[2] + b2v[2];
  oa.w = (tv[3] - m2) * iv2 * g2v[3] + b2v[3];
  ob.x = (tv[4] - m2) * iv2 * g2v[4] + b2v[4];
  ob.y = (tv[5] - m2) * iv2 * g2v[5] + b2v[5];
  ob.z = (tv[6] - m2) * iv2 * g2v[6] + b2v[6];
  ob.w = (tv[7] - m2) * iv2 * g2v[7] + b2v[7];
  float* orow = out + (size_t)row * Cz;
  ((float4*)orow)[lane * 2] = oa;
  ((float4*)orow)[lane * 2 + 1] = ob;
}

// ---------------------------------------------------------------------------
extern "C" void kernel_launch(void* const* d_in, const int* in_sizes, int n_in,
                              void* d_out, int out_size, void* d_ws,
                              size_t ws_size, hipStream_t stream) {
  const float* x = (const float*)d_in[0];
  const float* pw_w = (const float*)d_in[1];
  const float* pw_b = (const float*)d_in[2];
  const float* pw_bn_g = (const float*)d_in[3];
  const float* pw_bn_b = (const float*)d_in[4];
  const float* pw_bn_m = (const float*)d_in[5];
  const float* pw_bn_v = (const float*)d_in[6];
  const float* dw_w0 = (const float*)d_in[7];
  const float* dw_w1 = (const float*)d_in[8];
  const float* dw_w2 = (const float*)d_in[9];
  const float* dw_w3 = (const float*)d_in[10];
  const float* dw_b = (const float*)d_in[11];
  const float* dw_bn_g = (const float*)d_in[12];
  const float* dw_bn_b = (const float*)d_in[13];
  const float* dw_bn_m = (const float*)d_in[14];
  const float* dw_bn_v = (const float*)d_in[15];
  const float* se_w1 = (const float*)d_in[16];
  const float* se_b1 = (const float*)d_in[17];
  const float* se_w2 = (const float*)d_in[18];
  const float* se_b2 = (const float*)d_in[19];
  const float* se_ln_g = (const float*)d_in[20];
  const float* se_ln_b = (const float*)d_in[21];
  // d_in[22] = df_ln_g (unused: LN of channel-constant rows -> bias only)
  const float* df_ln_b = (const float*)d_in[23];
  const float* wq = (const float*)d_in[24];
  const float* bq = (const float*)d_in[25];
  const float* wv = (const float*)d_in[26];
  const float* bv = (const float*)d_in[27];
  const float* wg = (const float*)d_in[28];
  const float* bg = (const float*)d_in[29];
  const float* op_w = (const float*)d_in[30];
  const float* op_b = (const float*)d_in[31];
  const float* op_ln_g = (const float*)d_in[32];
  const float* op_ln_b = (const float*)d_in[33];
  const float* fn_g = (const float*)d_in[34];
  const float* fn_b = (const float*)d_in[35];
  float* out = (float*)d_out;

  const size_t NBL = (size_t)Bz * Cz * Lz;  // 8388608 elems
  char* p = (char*)d_ws;
  u16* oproj = (u16*)p; p += NBL * 2;        // 16MB
  u16* xpw = (u16*)p; p += NBL * 2;          // 16MB
  u16* ybuf = (u16*)p; p += 4 * NBL * 2;     // 64MB
  u16* ebuf = (u16*)p; p += 4 * NBL * 2;     // 64MB
  u16* pwwbf = (u16*)p; p += (size_t)Cz * Cz * 2;    // 512KB
  u16* wvbf = (u16*)p; p += (size_t)DHz * Cz * 2;    // 256KB
  u16* opwbf = (u16*)p; p += (size_t)Cz * Cz * 2;    // 512KB
  float* fbuf = (float*)p;
  float* ysum = fbuf;                  // 16384
  float* scv = fbuf + 16384;           // 16384
  float* scores = fbuf + 32768;        // 65536
  float* pwA = fbuf + 98304;           // 512
  float* pwB = pwA + 512;              // 512
  float* dwA = pwB + 512;              // 2048
  float* dwB = dwA + 2048;             // 2048
  float* qc = dwB + 2048;              // 256

  cvt_bf16_kernel<<<Cz * Cz / 8 / 256, 256, 0, stream>>>(pw_w, pwwbf,
                                                         Cz * Cz / 8);
  cvt_bf16_kernel<<<DHz * Cz / 8 / 256, 256, 0, stream>>>(wv, wvbf,
                                                          DHz * Cz / 8);
  cvt_bf16_kernel<<<Cz * Cz / 8 / 256, 256, 0, stream>>>(op_w, opwbf,
                                                         Cz * Cz / 8);

  prep_kernel<<<6, 256, 0, stream>>>(pw_b, pw_bn_g, pw_bn_b, pw_bn_m, pw_bn_v,
                                     dw_b, dw_bn_g, dw_bn_b, dw_bn_m, dw_bn_v,
                                     df_ln_b, wq, bq, pwA, pwB, dwA, dwB, qc);

  pw_mfma_kernel<<<Bz * (Lz / 32), 256, 0, stream>>>(pwwbf, x, pwA, pwB, xpw);

  dw_conv_kernel<<<Bz * Cz, 256, 0, stream>>>(xpw, dw_w0, dw_w1, dw_w2, dw_w3,
                                              dwA, dwB, ybuf, ysum);

  se_kernel<<<32, 128, 0, stream>>>(ysum, se_w1, se_b1, se_w2, se_b2, scv);

  ln_transpose_kernel<<<dim3(Lz / 32, 4 * Bz), 256, 0, stream>>>(
      ybuf, scv, se_ln_g, se_ln_b, ebuf);

  score_mfma_kernel<<<dim3(MT / 64, 4), 256, 0, stream>>>(
      ebuf, ebuf + NBL, ebuf + 2 * NBL, ebuf + 3 * NBL, wvbf, bv, qc, wg, bg,
      scores);

  op_mfma_kernel<<<MT / 32, 256, 0, stream>>>(
      ebuf, ebuf + NBL, ebuf + 2 * NBL, ebuf + 3 * NBL, scores, opwbf, op_b,
      oproj);

  final_ln_kernel<<<MT / 4, 256, 0, stream>>>(oproj, op_ln_g, op_ln_b, x, fn_g,
                                              fn_b, out);
}

// Round 8
// 212.212 us; speedup vs baseline: 3.5021x; 1.1141x over previous
//
#include <hip/hip_runtime.h>
#include <math.h>

static constexpr int Bz = 8;
static constexpr int Lz = 2048;
static constexpr int Cz = 512;
static constexpr int CRz = 128;
static constexpr int DHz = 256;
static constexpr int MT = Bz * Lz;           // 16384 rows
static constexpr float EPSz = 1e-5f;

typedef unsigned short u16;
typedef __bf16 bf16x8 __attribute__((ext_vector_type(8)));
typedef float f32x4 __attribute__((ext_vector_type(4)));
typedef unsigned short u16x8 __attribute__((ext_vector_type(8)));

__device__ __forceinline__ float bf2f(u16 u) {
  unsigned int v = ((unsigned int)u) << 16;
  return __builtin_bit_cast(float, v);
}
__device__ __forceinline__ u16 f2bf(float f) {
  unsigned int b = __builtin_bit_cast(unsigned int, f);
  b += 0x7FFFu + ((b >> 16) & 1u);
  return (u16)(b >> 16);
}
__device__ __forceinline__ f32x4 mfma16(bf16x8 a, bf16x8 b, f32x4 c) {
  return __builtin_amdgcn_mfma_f32_16x16x32_bf16(a, b, c, 0, 0, 0);
}

// ---------------------------------------------------------------------------
// cvt: fp32 -> bf16 (8 elems/thread) — weights only
// ---------------------------------------------------------------------------
__global__ __launch_bounds__(256) void cvt_bf16_kernel(
    const float* __restrict__ src, u16* __restrict__ dst, int n8) {
  int i = blockIdx.x * 256 + threadIdx.x;
  if (i >= n8) return;
  const float4* s = (const float4*)src;
  float4 a = s[i * 2], b = s[i * 2 + 1];
  u16x8 o;
  o[0] = f2bf(a.x); o[1] = f2bf(a.y); o[2] = f2bf(a.z); o[3] = f2bf(a.w);
  o[4] = f2bf(b.x); o[5] = f2bf(b.y); o[6] = f2bf(b.z); o[7] = f2bf(b.w);
  ((u16x8*)dst)[i] = o;
}

// ---------------------------------------------------------------------------
// P: fold BN params; compute Q const vector (diff-path LN collapses to bias)
// ---------------------------------------------------------------------------
__global__ __launch_bounds__(256) void prep_kernel(
    const float* __restrict__ pw_b, const float* __restrict__ pw_g,
    const float* __restrict__ pw_bb, const float* __restrict__ pw_m,
    const float* __restrict__ pw_v,
    const float* __restrict__ dw_b, const float* __restrict__ dw_g,
    const float* __restrict__ dw_bb, const float* __restrict__ dw_m,
    const float* __restrict__ dw_v,
    const float* __restrict__ df_ln_b, const float* __restrict__ wq,
    const float* __restrict__ bq,
    float* __restrict__ pwA, float* __restrict__ pwB,
    float* __restrict__ dwA, float* __restrict__ dwB,
    float* __restrict__ qc) {
  const int blk = blockIdx.x;
  const int t = threadIdx.x;
  if (blk == 0) {
    for (int c = t; c < Cz; c += 256) {
      float inv = rsqrtf(pw_v[c] + EPSz);
      float a = pw_g[c] * inv;
      float bb = pw_bb[c] - pw_m[c] * a;
      pwA[c] = a;
      pwB[c] = pw_b[c] * a + bb;
    }
  } else if (blk <= 4) {
    const int i = blk - 1;
    for (int c = t; c < Cz; c += 256) {
      int idx = i * Cz + c;
      float inv = rsqrtf(dw_v[idx] + EPSz);
      float a = dw_g[idx] * inv;
      float bb = dw_bb[idx] - dw_m[idx] * a;
      dwA[idx] = a;
      dwB[idx] = dw_b[idx] * a + bb;
    }
  } else {
    if (t < DHz) {
      float s = bq[t];
      const float* w = wq + (size_t)t * Cz;
      for (int c = 0; c < Cz; c++) s += df_ln_b[c] * w[c];
      qc[t] = s;
    }
  }
}

// ---------------------------------------------------------------------------
// A: pointwise conv, panel-resident (unchanged)
// ---------------------------------------------------------------------------
__global__ __launch_bounds__(256, 2) void pw_mfma_kernel(
    const u16* __restrict__ Wbf, const float* __restrict__ x,
    const float* __restrict__ alpha, const float* __restrict__ beta,
    u16* __restrict__ xpw) {
  __shared__ __align__(16) char lds[74240];
  u16(*sX)[520] = (u16(*)[520])lds;                  // [32][520] = 33,280 B
  u16(*sW)[40] = (u16(*)[40])(lds + 33280);          // [512][40] = 40,960 B
  u16* sC = (u16*)(lds + 33280);                     // [512][40] epilogue alias
  __shared__ float sAl[Cz];
  __shared__ float sBe[Cz];
  const int bat = blockIdx.x >> 6;
  const int l0 = (blockIdx.x & 63) * 32;
  const int t = threadIdx.x;
  const int lane = t & 63, w = t >> 6;
  const int fr = lane & 15, fk = (lane >> 4) * 8;
  const int mh = (w >> 1) * 16;   // m-frag half base (o dimension)
  const int nh = (w & 1) * 16;    // n-frag col base (l dimension)
#pragma unroll
  for (int rep = 0; rep < 8; rep++) {
    const int idx = rep * 256 + t;
    const int row = idx >> 6;
    const int col = (idx & 63) * 8;
    const float* src = x + ((size_t)bat * Lz + l0 + row) * Cz + col;
    float4 f0 = *(const float4*)src;
    float4 f1 = *(const float4*)(src + 4);
    u16x8 o;
    o[0] = f2bf(f0.x); o[1] = f2bf(f0.y); o[2] = f2bf(f0.z); o[3] = f2bf(f0.w);
    o[4] = f2bf(f1.x); o[5] = f2bf(f1.y); o[6] = f2bf(f1.z); o[7] = f2bf(f1.w);
    *(u16x8*)&sX[row][col] = o;
  }
  for (int c = t; c < Cz; c += 256) { sAl[c] = alpha[c]; sBe[c] = beta[c]; }
  f32x4 acc[16];
#pragma unroll
  for (int mf = 0; mf < 16; mf++)
#pragma unroll
    for (int r = 0; r < 4; r++) acc[mf][r] = 0.f;
  const int wrow = t >> 2, wch = (t & 3) * 8;
  const u16* wbase = Wbf + (size_t)wrow * Cz + wch;
  u16x8 breg[8];
#pragma unroll
  for (int rep = 0; rep < 8; rep++)
    breg[rep] = *(const u16x8*)(wbase + (size_t)rep * 64 * Cz);
  for (int k0 = 0; k0 < Cz; k0 += 32) {
    __syncthreads();
#pragma unroll
    for (int rep = 0; rep < 8; rep++)
      *(u16x8*)&sW[rep * 64 + wrow][wch] = breg[rep];
    __syncthreads();
    if (k0 + 32 < Cz) {
#pragma unroll
      for (int rep = 0; rep < 8; rep++)
        breg[rep] = *(const u16x8*)(wbase + (size_t)rep * 64 * Cz + k0 + 32);
    }
    bf16x8 bfrag = *(const bf16x8*)&sX[nh + fr][k0 + fk];
#pragma unroll
    for (int mf = 0; mf < 16; mf++) {
      bf16x8 a = *(const bf16x8*)&sW[(mh + mf) * 16 + fr][fk];
      acc[mf] = mfma16(a, bfrag, acc[mf]);
    }
  }
  __syncthreads();  // sW reads done; reuse as sC[512][40]
#pragma unroll
  for (int mf = 0; mf < 16; mf++) {
#pragma unroll
    for (int r = 0; r < 4; r++) {
      const int o = (mh + mf) * 16 + ((lane >> 4) << 2) + r;
      const int l = nh + fr;
      float v = fmaxf(acc[mf][r] * sAl[o] + sBe[o], 0.f);
      sC[o * 40 + l] = f2bf(v);
    }
  }
  __syncthreads();
#pragma unroll
  for (int rep = 0; rep < 8; rep++) {
    const int o = rep * 64 + (t >> 2);
    const int l8 = (t & 3) * 8;
    u16x8 v = *(const u16x8*)&sC[o * 40 + l8];
    *(u16x8*)(xpw + ((size_t)(bat * Cz + o)) * Lz + l0 + l8) = v;
  }
}

// ---------------------------------------------------------------------------
// B: depthwise conv, ALL 4 branches per block; padded LDS (unchanged)
// ---------------------------------------------------------------------------
template <int K>
__device__ __forceinline__ float dw_branch(const float* __restrict__ row,
                                           const float* __restrict__ wts,
                                           float a, float bb, int valid, int t,
                                           u16* __restrict__ dst) {
  constexpr int P = (K - 1) / 2;
  constexpr int W = 8 + K - 1;
  float wreg[K];
#pragma unroll
  for (int j = 0; j < K; j++) wreg[j] = wts[j];
  const int base = t * 8 - P;
  float win[W];
  if (base >= 0 && base + W <= Lz) {
#pragma unroll
    for (int j = 0; j < W; j++) {
      const int idx = base + j;
      win[j] = row[idx + (idx >> 5)];
    }
  } else {
#pragma unroll
    for (int j = 0; j < W; j++) {
      const int idx = base + j;
      win[j] = (idx >= 0 && idx < Lz) ? row[idx + (idx >> 5)] : 0.f;
    }
  }
  float acc[8] = {};
#pragma unroll
  for (int jj = 0; jj < K; jj++)
#pragma unroll
    for (int o = 0; o < 8; o++) acc[o] = fmaf(wreg[jj], win[jj + o], acc[o]);
  u16x8 ov;
  float psum = 0.f;
#pragma unroll
  for (int o = 0; o < 8; o++) {
    float v = fmaxf(acc[o] * a + bb, 0.f);
    if (t * 8 + o >= valid) v = 0.f;
    ov[o] = f2bf(v);
    psum += v;
  }
  *(u16x8*)(dst + t * 8) = ov;
  return psum;
}

__global__ __launch_bounds__(256) void dw_conv_kernel(
    const u16* __restrict__ xpw,
    const float* __restrict__ w0, const float* __restrict__ w1,
    const float* __restrict__ w2, const float* __restrict__ w3,
    const float* __restrict__ dwA, const float* __restrict__ dwB,
    u16* __restrict__ y, float* __restrict__ ysum) {
  __shared__ float row[Lz + Lz / 32];  // padded: phys = l + (l>>5)
  __shared__ float wts[48];
  __shared__ float wsum[4][4];         // [wave][branch]
  const int b = blockIdx.x >> 9;
  const int c = blockIdx.x & 511;
  const int t = threadIdx.x;
  const size_t NBL = (size_t)Bz * Cz * Lz;
  {
    u16x8 v = ((const u16x8*)(xpw + ((size_t)(b * Cz + c)) * Lz))[t];
#pragma unroll
    for (int j = 0; j < 8; j++) {
      const int idx = t * 8 + j;
      row[idx + (idx >> 5)] = bf2f(v[j]);
    }
  }
  if (t < 45) {
    float wv;
    if (t < 3) wv = w0[c * 3 + t];
    else if (t < 10) wv = w1[c * 7 + (t - 3)];
    else if (t < 25) wv = w2[c * 15 + (t - 10)];
    else wv = w3[c * 20 + (t - 25)];
    wts[t] = wv;
  }
  __syncthreads();
  u16* dstb = y + ((size_t)b * Cz + c) * Lz;
  float ps[4];
  ps[0] = dw_branch<3>(row, wts + 0, dwA[c], dwB[c], Lz, t, dstb);
  ps[1] = dw_branch<7>(row, wts + 3, dwA[Cz + c], dwB[Cz + c], Lz, t,
                       dstb + NBL);
  ps[2] = dw_branch<15>(row, wts + 10, dwA[2 * Cz + c], dwB[2 * Cz + c], Lz, t,
                        dstb + 2 * NBL);
  ps[3] = dw_branch<20>(row, wts + 25, dwA[3 * Cz + c], dwB[3 * Cz + c],
                        Lz - 1, t, dstb + 3 * NBL);
#pragma unroll
  for (int off = 32; off > 0; off >>= 1) {
#pragma unroll
    for (int i = 0; i < 4; i++) ps[i] += __shfl_down(ps[i], off, 64);
  }
  if ((t & 63) == 0) {
#pragma unroll
    for (int i = 0; i < 4; i++) wsum[t >> 6][i] = ps[i];
  }
  __syncthreads();
  if (t < 4)
    ysum[(t * Bz + b) * Cz + c] =
        wsum[0][t] + wsum[1][t] + wsum[2][t] + wsum[3][t];
}

// ---------------------------------------------------------------------------
// C: squeeze-excite (unchanged)
// ---------------------------------------------------------------------------
__global__ __launch_bounds__(128) void se_kernel(
    const float* __restrict__ ysum,
    const float* __restrict__ se_w1, const float* __restrict__ se_b1,
    const float* __restrict__ se_w2, const float* __restrict__ se_b2,
    float* __restrict__ sc) {
  const int i = blockIdx.x >> 3;
  const int b = blockIdx.x & 7;
  __shared__ float ym[Cz];
  __shared__ float h[CRz];
  const int t = threadIdx.x;
  const float* ys = ysum + (i * Bz + b) * Cz;
  for (int cc = t; cc < Cz; cc += 128) ym[cc] = ys[cc] * (1.f / Lz);
  __syncthreads();
  {
    const float* w1 = se_w1 + (size_t)i * CRz * Cz + (size_t)t * Cz;
    float s = se_b1[i * CRz + t];
    for (int cc = 0; cc < Cz; cc++) s += ym[cc] * w1[cc];
    h[t] = fmaxf(s, 0.f);
  }
  __syncthreads();
  for (int cc = t; cc < Cz; cc += 128) {
    const float* w2 = se_w2 + ((size_t)i * Cz + cc) * CRz;
    float s = se_b2[i * Cz + cc];
    for (int r = 0; r < CRz; r++) s += h[r] * w2[r];
    float wt = 1.f / (1.f + expf(-s));
    sc[(i * Bz + b) * Cz + cc] = 1.f + wt;
  }
}

// ---------------------------------------------------------------------------
// D: enhanced = LN_c( y[b,c,l]*sc[b,c] ), bf16 LDS tile (stride 522),
// scale applied at read. ~35 KB LDS -> 4 blocks/CU.
// ---------------------------------------------------------------------------
__global__ __launch_bounds__(256) void ln_transpose_kernel(
    const u16* __restrict__ ybuf, const float* __restrict__ scv,
    const float* __restrict__ se_ln_g, const float* __restrict__ se_ln_b,
    u16* __restrict__ ebuf) {
  __shared__ u16 tile[32][522];   // odd-word stride: conflict-free col writes
  __shared__ float ssc[Cz];
  const size_t NBL = (size_t)Bz * Cz * Lz;
  const int i = blockIdx.y >> 3;
  const int b = blockIdx.y & 7;
  const int l0 = blockIdx.x * 32;
  const int t = threadIdx.x;
  const u16* yb = ybuf + (size_t)i * NBL + (size_t)b * Cz * Lz;
  const float* scb = scv + (i * Bz + b) * Cz;
  for (int cc = t; cc < Cz; cc += 256) ssc[cc] = scb[cc];
#pragma unroll
  for (int rep = 0; rep < 8; rep++) {
    const int idx = rep * 256 + t;
    const int c = idx >> 2;
    const int l8 = (idx & 3) * 8;
    u16x8 v = *(const u16x8*)(yb + (size_t)c * Lz + l0 + l8);
#pragma unroll
    for (int j = 0; j < 8; j++) tile[l8 + j][c] = v[j];
  }
  __syncthreads();
  const int wave = t >> 6, lane = t & 63;
  const float* g = se_ln_g + i * Cz;
  const float* bb = se_ln_b + i * Cz;
  float sc8[8], g8[8], b8[8];
#pragma unroll
  for (int j = 0; j < 8; j++) {
    const int cc = lane + j * 64;
    sc8[j] = ssc[cc];
    g8[j] = g[cc];
    b8[j] = bb[cc];
  }
  u16* eb = ebuf + (size_t)i * NBL + ((size_t)b * Lz + l0) * Cz;
  for (int r = wave; r < 32; r += 4) {
    float vals[8];
    float s1 = 0.f, s2 = 0.f;
#pragma unroll
    for (int j = 0; j < 8; j++) {
      float v = bf2f(tile[r][lane + j * 64]) * sc8[j];
      vals[j] = v; s1 += v; s2 += v * v;
    }
    for (int off = 32; off > 0; off >>= 1) {
      s1 += __shfl_xor(s1, off, 64);
      s2 += __shfl_xor(s2, off, 64);
    }
    const float m = s1 * (1.f / Cz);
    const float var = s2 * (1.f / Cz) - m * m;
    const float inv = rsqrtf(var + EPSz);
#pragma unroll
    for (int j = 0; j < 8; j++) {
      const int cc = lane + j * 64;
      eb[(size_t)r * Cz + cc] = f2bf((vals[j] - m) * inv * g8[j] + b8[j]);
    }
  }
}

// ---------------------------------------------------------------------------
// E: score via MFMA, BK=64 + register prefetch. Block = 64 rows, one branch.
// 32 MFMA/wave per barrier pair, 8 K-iterations. LDS ~47KB -> 3 blocks/CU.
// ---------------------------------------------------------------------------
__global__ __launch_bounds__(256) void score_mfma_kernel(
    const u16* __restrict__ e0, const u16* __restrict__ e1,
    const u16* __restrict__ e2, const u16* __restrict__ e3,
    const u16* __restrict__ wvbf, const float* __restrict__ bv,
    const float* __restrict__ qc, const float* __restrict__ wg,
    const float* __restrict__ bg, float* __restrict__ scores) {
  __shared__ u16 sA[64][72];    // 9,216 B  (64 rows x BK=64)
  __shared__ u16 sB[256][72];   // 36,864 B (256 dh rows x BK=64)
  __shared__ float sP[4][64];
  const int i = blockIdx.y;
  const u16* E = (i == 0) ? e0 : (i == 1) ? e1 : (i == 2) ? e2 : e3;
  const int r0 = blockIdx.x * 64;
  const int t = threadIdx.x;
  const int lane = t & 63, w = t >> 6;
  const int fr = lane & 15, fk = (lane >> 4) * 8;
  const int srow = t >> 3;        // 0..31 per rep
  const int kc = (t & 7) * 8;     // k-chunk within BK=64
  u16x8 areg[2], breg[8];
#pragma unroll
  for (int rep = 0; rep < 2; rep++)
    areg[rep] = *(const u16x8*)(E + (size_t)(r0 + rep * 32 + srow) * Cz + kc);
#pragma unroll
  for (int rep = 0; rep < 8; rep++)
    breg[rep] = *(const u16x8*)(wvbf + (size_t)(rep * 32 + srow) * Cz + kc);
  f32x4 acc[4][4];
#pragma unroll
  for (int m = 0; m < 4; m++)
#pragma unroll
    for (int j = 0; j < 4; j++)
#pragma unroll
      for (int r = 0; r < 4; r++) acc[m][j][r] = 0.f;
  for (int k0 = 0; k0 < Cz; k0 += 64) {
    __syncthreads();
#pragma unroll
    for (int rep = 0; rep < 2; rep++)
      *(u16x8*)&sA[rep * 32 + srow][kc] = areg[rep];
#pragma unroll
    for (int rep = 0; rep < 8; rep++)
      *(u16x8*)&sB[rep * 32 + srow][kc] = breg[rep];
    __syncthreads();
    if (k0 + 64 < Cz) {
#pragma unroll
      for (int rep = 0; rep < 2; rep++)
        areg[rep] = *(const u16x8*)(E + (size_t)(r0 + rep * 32 + srow) * Cz +
                                    k0 + 64 + kc);
#pragma unroll
      for (int rep = 0; rep < 8; rep++)
        breg[rep] = *(const u16x8*)(wvbf + (size_t)(rep * 32 + srow) * Cz +
                                    k0 + 64 + kc);
    }
#pragma unroll
    for (int ks = 0; ks < 2; ks++) {
      bf16x8 am[4], bj[4];
#pragma unroll
      for (int m = 0; m < 4; m++)
        am[m] = *(const bf16x8*)&sA[m * 16 + fr][ks * 32 + fk];
#pragma unroll
      for (int j = 0; j < 4; j++)
        bj[j] = *(const bf16x8*)&sB[(w * 4 + j) * 16 + fr][ks * 32 + fk];
#pragma unroll
      for (int m = 0; m < 4; m++)
#pragma unroll
        for (int j = 0; j < 4; j++)
          acc[m][j] = mfma16(am[m], bj[j], acc[m][j]);
    }
  }
  float part[4][4];
#pragma unroll
  for (int m = 0; m < 4; m++)
#pragma unroll
    for (int r = 0; r < 4; r++) part[m][r] = 0.f;
#pragma unroll
  for (int j = 0; j < 4; j++) {
    const int dh = (w * 4 + j) * 16 + fr;
    const float bvn = bv[dh], qcn = qc[dh], wgn = wg[dh];
#pragma unroll
    for (int m = 0; m < 4; m++)
#pragma unroll
      for (int r = 0; r < 4; r++)
        part[m][r] += tanhf(qcn * (acc[m][j][r] + bvn)) * wgn;
  }
#pragma unroll
  for (int off = 1; off < 16; off <<= 1) {
#pragma unroll
    for (int m = 0; m < 4; m++)
#pragma unroll
      for (int r = 0; r < 4; r++)
        part[m][r] += __shfl_xor(part[m][r], off, 64);
  }
  if (fr == 0) {
#pragma unroll
    for (int m = 0; m < 4; m++)
#pragma unroll
      for (int r = 0; r < 4; r++)
        sP[w][m * 16 + ((lane >> 4) << 2) + r] = part[m][r];
  }
  __syncthreads();
  if (t < 64) {
    float s = sP[0][t] + sP[1][t] + sP[2][t] + sP[3][t] + bg[0];
    scores[(size_t)i * MT + r0 + t] = s;
  }
}

// ---------------------------------------------------------------------------
// G: fused softmax-combine + op GEMM + DOUBLE-LN epilogue (absorbs final_ln).
// Block = 32 rows; out = LN2(LN1(fused@op_w^T+op_b)*g1+b1 + x) written fp32.
// ---------------------------------------------------------------------------
__global__ __launch_bounds__(256, 2) void op_mfma_kernel(
    const u16* __restrict__ e0, const u16* __restrict__ e1,
    const u16* __restrict__ e2, const u16* __restrict__ e3,
    const float* __restrict__ scores, const u16* __restrict__ opwbf,
    const float* __restrict__ opb,
    const float* __restrict__ g1, const float* __restrict__ b1,
    const float* __restrict__ x,
    const float* __restrict__ g2, const float* __restrict__ b2,
    float* __restrict__ out) {
  __shared__ u16 sA[32][520];   // combined A panel full-K, 33,280 B
  __shared__ u16 sB[512][40];   // op_w k-slice, 40,960 B
  __shared__ float sw4[4][32];
  const int m0 = blockIdx.x * 32;
  const int t = threadIdx.x;
  const int lane = t & 63, w = t >> 6;
  const int fr = lane & 15, fk = (lane >> 4) * 8;
  const int mh = (w >> 1) * 16;  // m-frag base within 32-row panel (0 or 16)
  const int nh = (w & 1) * 16;   // n-frag half base (0 or 16 -> cols 0/256)
  if (t < 32) {
    const int r = m0 + t;
    float s0 = scores[r], s1 = scores[MT + r], s2 = scores[2 * MT + r],
          s3 = scores[3 * MT + r];
    float mx = fmaxf(fmaxf(s0, s1), fmaxf(s2, s3));
    float x0 = expf(s0 - mx), x1 = expf(s1 - mx), x2 = expf(s2 - mx),
          x3 = expf(s3 - mx);
    float inv = 1.f / (x0 + x1 + x2 + x3);
    sw4[0][t] = x0 * inv; sw4[1][t] = x1 * inv;
    sw4[2][t] = x2 * inv; sw4[3][t] = x3 * inv;
  }
  __syncthreads();
#pragma unroll
  for (int rep = 0; rep < 8; rep++) {
    const int idx = rep * 256 + t;
    const int row = idx >> 6;
    const int col = (idx & 63) * 8;
    const size_t off = (size_t)(m0 + row) * Cz + col;
    u16x8 v0 = *(const u16x8*)(e0 + off);
    u16x8 v1 = *(const u16x8*)(e1 + off);
    u16x8 v2 = *(const u16x8*)(e2 + off);
    u16x8 v3 = *(const u16x8*)(e3 + off);
    const float x0 = sw4[0][row], x1 = sw4[1][row], x2 = sw4[2][row],
                x3 = sw4[3][row];
    u16x8 o;
#pragma unroll
    for (int j = 0; j < 8; j++)
      o[j] = f2bf(x0 * bf2f(v0[j]) + x1 * bf2f(v1[j]) + x2 * bf2f(v2[j]) +
                  x3 * bf2f(v3[j]));
    *(u16x8*)&sA[row][col] = o;
  }
  f32x4 acc[16];
#pragma unroll
  for (int nf = 0; nf < 16; nf++)
#pragma unroll
    for (int r = 0; r < 4; r++) acc[nf][r] = 0.f;
  const int wrow = t >> 2, wch = (t & 3) * 8;
  const u16* wbase = opwbf + (size_t)wrow * Cz + wch;
  u16x8 breg[8];
#pragma unroll
  for (int rep = 0; rep < 8; rep++)
    breg[rep] = *(const u16x8*)(wbase + (size_t)rep * 64 * Cz);
  for (int k0 = 0; k0 < Cz; k0 += 32) {
    __syncthreads();
#pragma unroll
    for (int rep = 0; rep < 8; rep++)
      *(u16x8*)&sB[rep * 64 + wrow][wch] = breg[rep];
    __syncthreads();
    if (k0 + 32 < Cz) {
#pragma unroll
      for (int rep = 0; rep < 8; rep++)
        breg[rep] = *(const u16x8*)(wbase + (size_t)rep * 64 * Cz + k0 + 32);
    }
    bf16x8 a = *(const bf16x8*)&sA[mh + fr][k0 + fk];
#pragma unroll
    for (int nf = 0; nf < 16; nf++) {
      bf16x8 b = *(const bf16x8*)&sB[(nh + nf) * 16 + fr][fk];
      acc[nf] = mfma16(a, b, acc[nf]);
    }
  }
  __syncthreads();  // all sA/sB reads done; reuse sA as sC[32][520]
  u16* sC = (u16*)&sA[0][0];
#pragma unroll
  for (int nf = 0; nf < 16; nf++) {
    const int n = (nh + nf) * 16 + fr;
    const float ob = opb[n];
#pragma unroll
    for (int r = 0; r < 4; r++) {
      const int row = mh + ((lane >> 4) << 2) + r;
      sC[row * 520 + n] = f2bf(acc[nf][r] + ob);
    }
  }
  __syncthreads();
  // ---- fused double-LN epilogue: wave handles rows w*8 .. w*8+7 ----
  float g1v[8], b1v[8], g2v[8], b2v[8];
  {
    float4 a0 = ((const float4*)g1)[lane * 2], a1 = ((const float4*)g1)[lane * 2 + 1];
    float4 c0 = ((const float4*)b1)[lane * 2], c1 = ((const float4*)b1)[lane * 2 + 1];
    float4 d0 = ((const float4*)g2)[lane * 2], d1 = ((const float4*)g2)[lane * 2 + 1];
    float4 e0v = ((const float4*)b2)[lane * 2], e1v = ((const float4*)b2)[lane * 2 + 1];
    g1v[0]=a0.x; g1v[1]=a0.y; g1v[2]=a0.z; g1v[3]=a0.w;
    g1v[4]=a1.x; g1v[5]=a1.y; g1v[6]=a1.z; g1v[7]=a1.w;
    b1v[0]=c0.x; b1v[1]=c0.y; b1v[2]=c0.z; b1v[3]=c0.w;
    b1v[4]=c1.x; b1v[5]=c1.y; b1v[6]=c1.z; b1v[7]=c1.w;
    g2v[0]=d0.x; g2v[1]=d0.y; g2v[2]=d0.z; g2v[3]=d0.w;
    g2v[4]=d1.x; g2v[5]=d1.y; g2v[6]=d1.z; g2v[7]=d1.w;
    b2v[0]=e0v.x; b2v[1]=e0v.y; b2v[2]=e0v.z; b2v[3]=e0v.w;
    b2v[4]=e1v.x; b2v[5]=e1v.y; b2v[6]=e1v.z; b2v[7]=e1v.w;
  }
  for (int rr = 0; rr < 8; rr++) {
    const int row = w * 8 + rr;
    u16x8 av = *(const u16x8*)&sC[row * 520 + lane * 8];
    float v[8];
    float s1 = 0.f, s2 = 0.f;
#pragma unroll
    for (int j = 0; j < 8; j++) {
      v[j] = bf2f(av[j]);
      s1 += v[j]; s2 += v[j] * v[j];
    }
    for (int off = 1; off < 64; off <<= 1) {
      s1 += __shfl_xor(s1, off, 64);
      s2 += __shfl_xor(s2, off, 64);
    }
    const float m1 = s1 * (1.f / Cz);
    const float iv1 = rsqrtf(s2 * (1.f / Cz) - m1 * m1 + EPSz);
    const float* xr = x + (size_t)(m0 + row) * Cz;
    float4 xa = ((const float4*)xr)[lane * 2], xb = ((const float4*)xr)[lane * 2 + 1];
    float xv[8] = {xa.x, xa.y, xa.z, xa.w, xb.x, xb.y, xb.z, xb.w};
    float tv[8];
    s1 = 0.f; s2 = 0.f;
#pragma unroll
    for (int j = 0; j < 8; j++) {
      tv[j] = (v[j] - m1) * iv1 * g1v[j] + b1v[j] + xv[j];
      s1 += tv[j]; s2 += tv[j] * tv[j];
    }
    for (int off = 1; off < 64; off <<= 1) {
      s1 += __shfl_xor(s1, off, 64);
      s2 += __shfl_xor(s2, off, 64);
    }
    const float m2 = s1 * (1.f / Cz);
    const float iv2 = rsqrtf(s2 * (1.f / Cz) - m2 * m2 + EPSz);
    float4 oa, ob;
    oa.x = (tv[0] - m2) * iv2 * g2v[0] + b2v[0];
    oa.y = (tv[1] - m2) * iv2 * g2v[1] + b2v[1];
    oa.z = (tv[2] - m2) * iv2 * g2v[2] + b2v[2];
    oa.w = (tv[3] - m2) * iv2 * g2v[3] + b2v[3];
    ob.x = (tv[4] - m2) * iv2 * g2v[4] + b2v[4];
    ob.y = (tv[5] - m2) * iv2 * g2v[5] + b2v[5];
    ob.z = (tv[6] - m2) * iv2 * g2v[6] + b2v[6];
    ob.w = (tv[7] - m2) * iv2 * g2v[7] + b2v[7];
    float* orow = out + (size_t)(m0 + row) * Cz;
    ((float4*)orow)[lane * 2] = oa;
    ((float4*)orow)[lane * 2 + 1] = ob;
  }
}

// ---------------------------------------------------------------------------
extern "C" void kernel_launch(void* const* d_in, const int* in_sizes, int n_in,
                              void* d_out, int out_size, void* d_ws,
                              size_t ws_size, hipStream_t stream) {
  const float* x = (const float*)d_in[0];
  const float* pw_w = (const float*)d_in[1];
  const float* pw_b = (const float*)d_in[2];
  const float* pw_bn_g = (const float*)d_in[3];
  const float* pw_bn_b = (const float*)d_in[4];
  const float* pw_bn_m = (const float*)d_in[5];
  const float* pw_bn_v = (const float*)d_in[6];
  const float* dw_w0 = (const float*)d_in[7];
  const float* dw_w1 = (const float*)d_in[8];
  const float* dw_w2 = (const float*)d_in[9];
  const float* dw_w3 = (const float*)d_in[10];
  const float* dw_b = (const float*)d_in[11];
  const float* dw_bn_g = (const float*)d_in[12];
  const float* dw_bn_b = (const float*)d_in[13];
  const float* dw_bn_m = (const float*)d_in[14];
  const float* dw_bn_v = (const float*)d_in[15];
  const float* se_w1 = (const float*)d_in[16];
  const float* se_b1 = (const float*)d_in[17];
  const float* se_w2 = (const float*)d_in[18];
  const float* se_b2 = (const float*)d_in[19];
  const float* se_ln_g = (const float*)d_in[20];
  const float* se_ln_b = (const float*)d_in[21];
  // d_in[22] = df_ln_g (unused: LN of channel-constant rows -> bias only)
  const float* df_ln_b = (const float*)d_in[23];
  const float* wq = (const float*)d_in[24];
  const float* bq = (const float*)d_in[25];
  const float* wv = (const float*)d_in[26];
  const float* bv = (const float*)d_in[27];
  const float* wg = (const float*)d_in[28];
  const float* bg = (const float*)d_in[29];
  const float* op_w = (const float*)d_in[30];
  const float* op_b = (const float*)d_in[31];
  const float* op_ln_g = (const float*)d_in[32];
  const float* op_ln_b = (const float*)d_in[33];
  const float* fn_g = (const float*)d_in[34];
  const float* fn_b = (const float*)d_in[35];
  float* out = (float*)d_out;

  const size_t NBL = (size_t)Bz * Cz * Lz;  // 8388608 elems
  char* p = (char*)d_ws;
  p += NBL * 2;                              // (spare, was oproj)
  u16* xpw = (u16*)p; p += NBL * 2;          // 16MB
  u16* ybuf = (u16*)p; p += 4 * NBL * 2;     // 64MB
  u16* ebuf = (u16*)p; p += 4 * NBL * 2;     // 64MB
  u16* pwwbf = (u16*)p; p += (size_t)Cz * Cz * 2;    // 512KB
  u16* wvbf = (u16*)p; p += (size_t)DHz * Cz * 2;    // 256KB
  u16* opwbf = (u16*)p; p += (size_t)Cz * Cz * 2;    // 512KB
  float* fbuf = (float*)p;
  float* ysum = fbuf;                  // 16384
  float* scv = fbuf + 16384;           // 16384
  float* scores = fbuf + 32768;        // 65536
  float* pwA = fbuf + 98304;           // 512
  float* pwB = pwA + 512;              // 512
  float* dwA = pwB + 512;              // 2048
  float* dwB = dwA + 2048;             // 2048
  float* qc = dwB + 2048;              // 256

  cvt_bf16_kernel<<<Cz * Cz / 8 / 256, 256, 0, stream>>>(pw_w, pwwbf,
                                                         Cz * Cz / 8);
  cvt_bf16_kernel<<<DHz * Cz / 8 / 256, 256, 0, stream>>>(wv, wvbf,
                                                          DHz * Cz / 8);
  cvt_bf16_kernel<<<Cz * Cz / 8 / 256, 256, 0, stream>>>(op_w, opwbf,
                                                         Cz * Cz / 8);

  prep_kernel<<<6, 256, 0, stream>>>(pw_b, pw_bn_g, pw_bn_b, pw_bn_m, pw_bn_v,
                                     dw_b, dw_bn_g, dw_bn_b, dw_bn_m, dw_bn_v,
                                     df_ln_b, wq, bq, pwA, pwB, dwA, dwB, qc);

  pw_mfma_kernel<<<Bz * (Lz / 32), 256, 0, stream>>>(pwwbf, x, pwA, pwB, xpw);

  dw_conv_kernel<<<Bz * Cz, 256, 0, stream>>>(xpw, dw_w0, dw_w1, dw_w2, dw_w3,
                                              dwA, dwB, ybuf, ysum);

  se_kernel<<<32, 128, 0, stream>>>(ysum, se_w1, se_b1, se_w2, se_b2, scv);

  ln_transpose_kernel<<<dim3(Lz / 32, 4 * Bz), 256, 0, stream>>>(
      ybuf, scv, se_ln_g, se_ln_b, ebuf);

  score_mfma_kernel<<<dim3(MT / 64, 4), 256, 0, stream>>>(
      ebuf, ebuf + NBL, ebuf + 2 * NBL, ebuf + 3 * NBL, wvbf, bv, qc, wg, bg,
      scores);

  op_mfma_kernel<<<MT / 32, 256, 0, stream>>>(
      ebuf, ebuf + NBL, ebuf + 2 * NBL, ebuf + 3 * NBL, scores, opwbf, op_b,
      op_ln_g, op_ln_b, x, fn_g, fn_b, out);
}